// Round 3
// baseline (586.994 us; speedup 1.0000x reference)
//
#include <hip/hip_runtime.h>
#include <hip/hip_bf16.h>

// B=4, S=2048, E=1024, H=16, HD=64.
// d_in / d_out are FLOAT32 (per reference dtypes; npz sizes confirm).
// Internal compute: bf16 MFMA with f32 accumulate.
typedef unsigned short u16;
typedef __attribute__((ext_vector_type(8))) short short8;   // 8 bf16 (MFMA A/B frag)
typedef __attribute__((ext_vector_type(4))) float f32x4;    // MFMA C/D frag

__device__ __forceinline__ float b2f(u16 u){
    unsigned v = ((unsigned)u) << 16; float f; __builtin_memcpy(&f, &v, 4); return f;
}
__device__ __forceinline__ u16 f2b(float f){
    unsigned v; __builtin_memcpy(&v, &f, 4);
    v += 0x7fffu + ((v >> 16) & 1u);   // round-to-nearest-even
    return (u16)(v >> 16);
}

__device__ __forceinline__ void gload16(const void* g, void* l){
    __builtin_amdgcn_global_load_lds((const __attribute__((address_space(1))) unsigned int*)g,
                                     (__attribute__((address_space(3))) unsigned int*)l, 16, 0, 0);
}

// ---------------------------------------------------------------------------
// f32 -> bf16 convert (weights). n must be multiple of 1024; grid = n/1024.
// ---------------------------------------------------------------------------
__global__ void cvt_k(const float* __restrict__ src, u16* __restrict__ dst)
{
    const int i = (blockIdx.x * 256 + threadIdx.x) * 4;
    float4 v = *(const float4*)&src[i];
    ushort4 o;
    o.x = f2b(v.x); o.y = f2b(v.y); o.z = f2b(v.z); o.w = f2b(v.w);
    *(ushort4*)&dst[i] = o;
}

// ---------------------------------------------------------------------------
// GEMM: C[M][N] = A[M][K] @ W[N][K]^T + bias[N]
// A: f32 (AF32=1, staged f32 + cvt in frag build) or bf16 (AF32=0).
// W: bf16. bias: f32. C: f32 (OF32=1) or bf16.
// m97 structure: 128x128 tile, BK=32, 4 waves (2x2), global_load_lds staging.
// ---------------------------------------------------------------------------
template<bool AF32, bool OF32>
__global__ __launch_bounds__(256, 2)
void gemm_k(const void* __restrict__ Ap, const u16* __restrict__ W,
            const float* __restrict__ bias, void* __restrict__ Cp,
            int M, int N, int K)
{
    __shared__ float Asf[128 * 32];   // 16 KB (used when AF32)
    __shared__ u16   Asb[128 * 32];   // 8 KB  (used when !AF32) — union-by-alias not allowed; keep both (24+8=32KB total w/ Bs)
    __shared__ u16   Bs [128 * 32];   // 8 KB
    const int tid  = threadIdx.x;
    const int wave = tid >> 6;
    const int lane = tid & 63;
    const int lg = lane >> 4, lr = lane & 15;
    const int m0 = blockIdx.x * 128, n0 = blockIdx.y * 128;
    const int wm = (wave >> 1) * 64, wn = (wave & 1) * 64;

    // B staging: thread t -> row t>>2 (0..63), 16B chunk t&3; 2 issues (+64 rows)
    const u16* bG = W + (size_t)(n0 + (tid >> 2)) * K + (tid & 3) * 8;
    char* bsBase = (char*)Bs + wave * 1024;
    const size_t brstep = (size_t)64 * K;

    // A staging (f32): thread t -> row t>>3 (0..31), 16B chunk t&7; 4 issues (+32 rows)
    const float* aGf = (const float*)Ap + (size_t)(m0 + (tid >> 3)) * K + (tid & 7) * 4;
    const size_t arstepf = (size_t)32 * K;
    // A staging (bf16): like B
    const u16* aGb = (const u16*)Ap + (size_t)(m0 + (tid >> 2)) * K + (tid & 3) * 8;
    char* aBase = AF32 ? (char*)Asf : (char*)Asb;
    char* asBase = aBase + wave * 1024;

    f32x4 acc[4][4] = {};

    for (int kt = 0; kt < K; kt += 32) {
        if (AF32) {
#pragma unroll
            for (int i = 0; i < 4; ++i)
                gload16(aGf + kt + i * arstepf, asBase + i * 4096);
        } else {
            gload16(aGb + kt,          asBase);
            gload16(aGb + kt + brstep, asBase + 4096);
        }
        gload16(bG + kt,          bsBase);
        gload16(bG + kt + brstep, bsBase + 4096);
        __syncthreads();

        short8 a[4], b[4];
#pragma unroll
        for (int i = 0; i < 4; ++i) {
            const int row = wm + i * 16 + lr;
            if (AF32) {
                float4 f0 = *(const float4*)&Asf[row * 32 + lg * 8];
                float4 f1 = *(const float4*)&Asf[row * 32 + lg * 8 + 4];
                u16* ap = (u16*)&a[i];
                ap[0] = f2b(f0.x); ap[1] = f2b(f0.y); ap[2] = f2b(f0.z); ap[3] = f2b(f0.w);
                ap[4] = f2b(f1.x); ap[5] = f2b(f1.y); ap[6] = f2b(f1.z); ap[7] = f2b(f1.w);
            } else {
                a[i] = *(const short8*)&Asb[row * 32 + lg * 8];
            }
        }
#pragma unroll
        for (int j = 0; j < 4; ++j) b[j] = *(const short8*)&Bs[(wn + j*16 + lr)*32 + lg*8];
#pragma unroll
        for (int i = 0; i < 4; ++i)
#pragma unroll
            for (int j = 0; j < 4; ++j)
                acc[i][j] = __builtin_amdgcn_mfma_f32_16x16x32_bf16(a[i], b[j], acc[i][j], 0, 0, 0);
        __syncthreads();
    }

    // C/D layout: col=lane&15, row=(lane>>4)*4+reg
#pragma unroll
    for (int j = 0; j < 4; ++j) {
        const int cn = n0 + wn + j*16 + lr;
        const float bv = bias[cn];
#pragma unroll
        for (int i = 0; i < 4; ++i) {
            const int cm = m0 + wm + i*16 + lg*4;
#pragma unroll
            for (int r = 0; r < 4; ++r) {
                const float val = acc[i][j][r] + bv;
                if (OF32) ((float*)Cp)[(size_t)(cm + r) * N + cn] = val;
                else      ((u16*)Cp) [(size_t)(cm + r) * N + cn] = f2b(val);
            }
        }
    }
}

// ---------------------------------------------------------------------------
// LayerNorm over E=1024 per row. One block per row, 256 threads x 4 elems.
// INF32: src is f32 else bf16. OUTMODE: 0 = bf16 flat (in-place ok),
// 1 = f32 head-layout scatter [B,H,S,HD], 2 = f32 flat (in-place ok).
// g/be are f32.
// ---------------------------------------------------------------------------
template<int INF32, int OUTMODE>
__global__ void ln_k(const void* src, const float* __restrict__ g,
                     const float* __restrict__ be, void* dst)
{
    __shared__ float red[8];
    const int row = blockIdx.x;           // b*2048 + s
    const int tid = threadIdx.x;
    const int lane = tid & 63, wave = tid >> 6;
    float f[4];
    if (INF32) {
        float4 v = *(const float4*)&((const float*)src)[(size_t)row * 1024 + tid * 4];
        f[0] = v.x; f[1] = v.y; f[2] = v.z; f[3] = v.w;
    } else {
        ushort4 v = *(const ushort4*)&((const u16*)src)[(size_t)row * 1024 + tid * 4];
        f[0] = b2f(v.x); f[1] = b2f(v.y); f[2] = b2f(v.z); f[3] = b2f(v.w);
    }
    float s  = f[0] + f[1] + f[2] + f[3];
    float ss = f[0]*f[0] + f[1]*f[1] + f[2]*f[2] + f[3]*f[3];
#pragma unroll
    for (int off = 32; off; off >>= 1) { s += __shfl_down(s, off); ss += __shfl_down(ss, off); }
    if (lane == 0) { red[wave] = s; red[4 + wave] = ss; }
    __syncthreads();
    s  = red[0] + red[1] + red[2] + red[3];
    ss = red[4] + red[5] + red[6] + red[7];
    const float mean = s * (1.0f / 1024.0f);
    const float var  = fmaxf(ss * (1.0f / 1024.0f) - mean * mean, 0.0f);
    const float rs   = rsqrtf(var + 1e-5f);
    float o[4];
#pragma unroll
    for (int k = 0; k < 4; ++k) {
        const int e = tid * 4 + k;
        o[k] = (f[k] - mean) * rs * g[e] + be[e];
    }
    if (OUTMODE == 0) {
        ushort4 ov; ov.x = f2b(o[0]); ov.y = f2b(o[1]); ov.z = f2b(o[2]); ov.w = f2b(o[3]);
        *(ushort4*)&((u16*)dst)[(size_t)row * 1024 + tid * 4] = ov;
    } else if (OUTMODE == 1) {
        const int b = row >> 11, sIdx = row & 2047;
        const int h = tid >> 4, hd = (tid * 4) & 63;
        float4 ov = { o[0], o[1], o[2], o[3] };
        *(float4*)&((float*)dst)[(((size_t)(b * 16 + h) * 2048 + sIdx) << 6) + hd] = ov;
    } else {
        float4 ov = { o[0], o[1], o[2], o[3] };
        *(float4*)&((float*)dst)[(size_t)row * 1024 + tid * 4] = ov;
    }
}

// ---------------------------------------------------------------------------
// Causal flash attention. Grid (S/64=32, B*H=64), 4 waves x 16 q-rows.
// Q,K: bf16 FLAT [B,S,E] (offset h*64, row stride 1024).
// V: f32 head layout [B,H,S,HD] (the final V output buffer).
// O: bf16 flat [B,S,E].
// ---------------------------------------------------------------------------
__global__ __launch_bounds__(256, 2)
void attn_k(const u16* __restrict__ Qf, const u16* __restrict__ Kf,
            const float* __restrict__ Vf, u16* __restrict__ O)
{
    __shared__ u16 Ks [64 * 64];      // [kv][hd]
    __shared__ u16 Vts[64 * 64];      // [hd][kv] (transposed for PV B-frags)
    __shared__ u16 Ps [4][16 * 64];   // per-wave P tile [qrow][kv]
    const int qt = blockIdx.x, bh = blockIdx.y;
    const int b = bh >> 4, h = bh & 15;
    const int tid = threadIdx.x, wave = tid >> 6, lane = tid & 63;
    const int lg = lane >> 4, lr = lane & 15;
    const int q0 = qt * 64;
    const u16* Qbh = Qf + ((size_t)b * 2048) * 1024 + h * 64;
    const u16* Kbh = Kf + ((size_t)b * 2048) * 1024 + h * 64;
    const float* Vb = Vf + (size_t)bh * 2048 * 64;

    // Q frags in registers (A-frag: row=lane&15, k=8*(lane>>4)+j)
    const int qrow = q0 + wave * 16 + lr;
    const short8 qf0 = *(const short8*)&Qbh[(size_t)qrow * 1024 + lg * 8];
    const short8 qf1 = *(const short8*)&Qbh[(size_t)qrow * 1024 + 32 + lg * 8];

    f32x4 oacc[4] = {};
    float m_r[4] = { -1e30f, -1e30f, -1e30f, -1e30f };
    float l_r[4] = { 0.f, 0.f, 0.f, 0.f };
    const int myrow0 = q0 + wave * 16 + lg * 4;

    for (int kv = 0; kv <= qt; ++kv) {
        const int kv0 = kv * 64;
#pragma unroll
        for (int it = 0; it < 2; ++it) {
            const int id = tid + it * 256;
            const int r = id >> 3, c = id & 7;
            *(uint4*)&Ks[r * 64 + c * 8] = *(const uint4*)&Kbh[(size_t)(kv0 + r) * 1024 + c * 8];
            float4 v0 = *(const float4*)&Vb[(size_t)(kv0 + r) * 64 + c * 8];
            float4 v1 = *(const float4*)&Vb[(size_t)(kv0 + r) * 64 + c * 8 + 4];
            Vts[(c*8 + 0) * 64 + r] = f2b(v0.x);
            Vts[(c*8 + 1) * 64 + r] = f2b(v0.y);
            Vts[(c*8 + 2) * 64 + r] = f2b(v0.z);
            Vts[(c*8 + 3) * 64 + r] = f2b(v0.w);
            Vts[(c*8 + 4) * 64 + r] = f2b(v1.x);
            Vts[(c*8 + 5) * 64 + r] = f2b(v1.y);
            Vts[(c*8 + 6) * 64 + r] = f2b(v1.z);
            Vts[(c*8 + 7) * 64 + r] = f2b(v1.w);
        }
        __syncthreads();

        // S = Q K^T (16x64 per wave)
        f32x4 sacc[4];
#pragma unroll
        for (int c = 0; c < 4; ++c) {
            const short8 k0 = *(const short8*)&Ks[(c*16 + lr)*64 + lg*8];
            const short8 k1 = *(const short8*)&Ks[(c*16 + lr)*64 + 32 + lg*8];
            f32x4 z = { 0.f, 0.f, 0.f, 0.f };
            z = __builtin_amdgcn_mfma_f32_16x16x32_bf16(qf0, k0, z, 0, 0, 0);
            z = __builtin_amdgcn_mfma_f32_16x16x32_bf16(qf1, k1, z, 0, 0, 0);
            sacc[c] = z;
        }

        // scale + causal mask + wave-parallel online softmax (16-lane row groups)
#pragma unroll
        for (int r = 0; r < 4; ++r) {
            const int rowg = myrow0 + r;
            float mx = -1e30f;
#pragma unroll
            for (int c = 0; c < 4; ++c) {
                float sv = sacc[c][r] * 0.125f;
                const int col = kv0 + c * 16 + lr;
                if (col > rowg) sv = -1e30f;
                sacc[c][r] = sv;
                mx = fmaxf(mx, sv);
            }
#pragma unroll
            for (int d = 1; d < 16; d <<= 1) mx = fmaxf(mx, __shfl_xor(mx, d));
            const float mnew = fmaxf(m_r[r], mx);
            const float al = __expf(m_r[r] - mnew);
            m_r[r] = mnew;
            float rsum = 0.f;
#pragma unroll
            for (int c = 0; c < 4; ++c) {
                const float p = __expf(sacc[c][r] - mnew);
                sacc[c][r] = p;
                rsum += p;
            }
#pragma unroll
            for (int d = 1; d < 16; d <<= 1) rsum += __shfl_xor(rsum, d);
            l_r[r] = l_r[r] * al + rsum;
#pragma unroll
            for (int c2 = 0; c2 < 4; ++c2) oacc[c2][r] *= al;
        }

        // P -> LDS (wave-local), then PV MFMA
#pragma unroll
        for (int r = 0; r < 4; ++r)
#pragma unroll
            for (int c = 0; c < 4; ++c)
                Ps[wave][(lg * 4 + r) * 64 + c * 16 + lr] = f2b(sacc[c][r]);
#pragma unroll
        for (int s2 = 0; s2 < 2; ++s2) {
            const short8 pa = *(const short8*)&Ps[wave][lr * 64 + s2 * 32 + lg * 8];
#pragma unroll
            for (int c2 = 0; c2 < 4; ++c2) {
                const short8 vb = *(const short8*)&Vts[(c2*16 + lr)*64 + s2*32 + lg*8];
                oacc[c2] = __builtin_amdgcn_mfma_f32_16x16x32_bf16(pa, vb, oacc[c2], 0, 0, 0);
            }
        }
        __syncthreads();
    }

#pragma unroll
    for (int c2 = 0; c2 < 4; ++c2)
#pragma unroll
        for (int r = 0; r < 4; ++r) {
            const float ov = oacc[c2][r] / l_r[r];
            O[((size_t)b * 2048 + myrow0 + r) * 1024 + h * 64 + c2 * 16 + lr] = f2b(ov);
        }
}

// ---------------------------------------------------------------------------
// Memory plan (all f32 I/O):
//   d_out f32: out [0, 8388608), V [8388608, 16777216)   (67.1 MB total)
//   scratch-in-d_out (bf16 views, dead before final writes):
//     D0 = bytes [0, 16.78M)      : Q bf16 flat
//     D1 = bytes [16.78M, 33.55M) : K bf16 flat
//   ws (peak 25.2 MB): S0 [16.78 MB] = V-preLN bf16 -> attnout bf16
//                      S1 [8.39 MB]  = 4 bf16 weight matrices
// ---------------------------------------------------------------------------
extern "C" void kernel_launch(void* const* d_in, const int* in_sizes, int n_in,
                              void* d_out, int out_size, void* d_ws, size_t ws_size,
                              hipStream_t stream)
{
    (void)in_sizes; (void)n_in; (void)out_size; (void)ws_size;
    const float* x   = (const float*)d_in[0];
    const float* wq  = (const float*)d_in[1];  const float* bq   = (const float*)d_in[2];
    const float* wk  = (const float*)d_in[3];  const float* bk   = (const float*)d_in[4];
    const float* wv  = (const float*)d_in[5];  const float* bv   = (const float*)d_in[6];
    const float* wp  = (const float*)d_in[7];  const float* bp   = (const float*)d_in[8];
    const float* g_q = (const float*)d_in[9];  const float* be_q = (const float*)d_in[10];
    const float* g_k = (const float*)d_in[11]; const float* be_k = (const float*)d_in[12];
    const float* g_v = (const float*)d_in[13]; const float* be_v = (const float*)d_in[14];
    const float* g_p = (const float*)d_in[15]; const float* be_p = (const float*)d_in[16];

    float* outF = (float*)d_out;            // final out f32 [B,S,E]
    float* Vf   = outF + 8388608;           // final V f32 [B,H,S,HD]
    u16* D0 = (u16*)d_out;                  // bf16 scratch over out-region bytes [0,16.78M)
    u16* D1 = (u16*)d_out + 8388608;        // bytes [16.78M, 33.55M)
    char* ws = (char*)d_ws;
    u16* S0  = (u16*)ws;                    // 16.78 MB
    u16* wqb = (u16*)(ws + 16777216);
    u16* wkb = wqb + 1048576;
    u16* wvb = wkb + 1048576;
    u16* wpb = wvb + 1048576;

    const dim3 gg(64, 8), bb(256), cg(1024);
    cvt_k<<<cg, bb, 0, stream>>>(wq, wqb);
    cvt_k<<<cg, bb, 0, stream>>>(wk, wkb);
    cvt_k<<<cg, bb, 0, stream>>>(wv, wvb);
    cvt_k<<<cg, bb, 0, stream>>>(wp, wpb);

    // Q: x(f32) @ wq^T -> D0 bf16, LN in place
    gemm_k<true, false><<<gg, bb, 0, stream>>>(x, wqb, bq, D0, 8192, 1024, 1024);
    ln_k<0, 0><<<dim3(8192), bb, 0, stream>>>(D0, g_q, be_q, D0);
    // K -> D1 bf16, LN in place
    gemm_k<true, false><<<gg, bb, 0, stream>>>(x, wkb, bk, D1, 8192, 1024, 1024);
    ln_k<0, 0><<<dim3(8192), bb, 0, stream>>>(D1, g_k, be_k, D1);
    // V -> S0 bf16; LN writes final V f32 (head layout)
    gemm_k<true, false><<<gg, bb, 0, stream>>>(x, wvb, bv, S0, 8192, 1024, 1024);
    ln_k<0, 1><<<dim3(8192), bb, 0, stream>>>(S0, g_v, be_v, Vf);
    // attention: Q@D0, K@D1 (bf16 flat), V@Vf (f32 head) -> attnout bf16 @ S0
    attn_k<<<dim3(32, 64), bb, 0, stream>>>(D0, D1, Vf, S0);
    // out-proj: attnout(bf16) @ wp^T -> outF f32; final LN in place f32
    gemm_k<false, true><<<gg, bb, 0, stream>>>(S0, wpb, bp, outF, 8192, 1024, 1024);
    ln_k<1, 2><<<dim3(8192), bb, 0, stream>>>(outF, g_p, be_p, outF);
}

// Round 4
// 451.708 us; speedup vs baseline: 1.2995x; 1.2995x over previous
//
#include <hip/hip_runtime.h>
#include <hip/hip_bf16.h>

// B=4, S=2048, E=1024, H=16, HD=64. d_in/d_out are FLOAT32; compute in bf16 MFMA.
typedef unsigned short u16;
typedef __attribute__((ext_vector_type(8))) short short8;   // 8 bf16 (MFMA A/B frag)
typedef __attribute__((ext_vector_type(4))) float f32x4;    // MFMA C/D frag

__device__ __forceinline__ float b2f(u16 u){
    unsigned v = ((unsigned)u) << 16; float f; __builtin_memcpy(&f, &v, 4); return f;
}
__device__ __forceinline__ u16 f2b(float f){
    unsigned v; __builtin_memcpy(&v, &f, 4);
    v += 0x7fffu + ((v >> 16) & 1u);   // round-to-nearest-even
    return (u16)(v >> 16);
}

__device__ __forceinline__ void gload16(const void* g, void* l){
    __builtin_amdgcn_global_load_lds((const __attribute__((address_space(1))) unsigned int*)g,
                                     (__attribute__((address_space(3))) unsigned int*)l, 16, 0, 0);
}

// XOR bank swizzle for 64-u16-wide LDS rows (G4: row stride 128B => all rows same
// bank without this). u16-index form; preserves 16B alignment of 8-elem groups.
__device__ __forceinline__ int swz(int row, int col){
    return row * 64 + (col ^ ((row & 7) << 3));
}

// ---------------------------------------------------------------------------
__global__ void cvt_k(const float* __restrict__ src, u16* __restrict__ dst)
{
    const int i = (blockIdx.x * 256 + threadIdx.x) * 4;
    float4 v = *(const float4*)&src[i];
    ushort4 o;
    o.x = f2b(v.x); o.y = f2b(v.y); o.z = f2b(v.z); o.w = f2b(v.w);
    *(ushort4*)&dst[i] = o;
}

// ---------------------------------------------------------------------------
// GEMM: C[M][N] = A[M][K] @ W[N][K]^T + bias[N]
// ---------------------------------------------------------------------------
template<bool AF32, bool OF32>
__global__ __launch_bounds__(256, 2)
void gemm_k(const void* __restrict__ Ap, const u16* __restrict__ W,
            const float* __restrict__ bias, void* __restrict__ Cp,
            int M, int N, int K)
{
    __shared__ char AsRaw[AF32 ? 16384 : 8192];   // f32 or bf16 A tile (union)
    __shared__ u16  Bs[128 * 32];                 // 8 KB
    float* Asf = (float*)AsRaw;
    u16*   Asb = (u16*)AsRaw;
    const int tid  = threadIdx.x;
    const int wave = tid >> 6;
    const int lane = tid & 63;
    const int lg = lane >> 4, lr = lane & 15;
    const int m0 = blockIdx.x * 128, n0 = blockIdx.y * 128;
    const int wm = (wave >> 1) * 64, wn = (wave & 1) * 64;

    const u16* bG = W + (size_t)(n0 + (tid >> 2)) * K + (tid & 3) * 8;
    char* bsBase = (char*)Bs + wave * 1024;
    const size_t brstep = (size_t)64 * K;

    const float* aGf = (const float*)Ap + (size_t)(m0 + (tid >> 3)) * K + (tid & 7) * 4;
    const size_t arstepf = (size_t)32 * K;
    const u16* aGb = (const u16*)Ap + (size_t)(m0 + (tid >> 2)) * K + (tid & 3) * 8;
    char* asBase = (char*)AsRaw + wave * 1024;

    f32x4 acc[4][4] = {};

    for (int kt = 0; kt < K; kt += 32) {
        if (AF32) {
#pragma unroll
            for (int i = 0; i < 4; ++i)
                gload16(aGf + kt + i * arstepf, asBase + i * 4096);
        } else {
            gload16(aGb + kt,          asBase);
            gload16(aGb + kt + brstep, asBase + 4096);
        }
        gload16(bG + kt,          bsBase);
        gload16(bG + kt + brstep, bsBase + 4096);
        __syncthreads();

        short8 a[4], b[4];
#pragma unroll
        for (int i = 0; i < 4; ++i) {
            const int row = wm + i * 16 + lr;
            if (AF32) {
                float4 f0 = *(const float4*)&Asf[row * 32 + lg * 8];
                float4 f1 = *(const float4*)&Asf[row * 32 + lg * 8 + 4];
                u16* ap = (u16*)&a[i];
                ap[0] = f2b(f0.x); ap[1] = f2b(f0.y); ap[2] = f2b(f0.z); ap[3] = f2b(f0.w);
                ap[4] = f2b(f1.x); ap[5] = f2b(f1.y); ap[6] = f2b(f1.z); ap[7] = f2b(f1.w);
            } else {
                a[i] = *(const short8*)&Asb[row * 32 + lg * 8];
            }
        }
#pragma unroll
        for (int j = 0; j < 4; ++j) b[j] = *(const short8*)&Bs[(wn + j*16 + lr)*32 + lg*8];
        __builtin_amdgcn_s_setprio(1);
#pragma unroll
        for (int i = 0; i < 4; ++i)
#pragma unroll
            for (int j = 0; j < 4; ++j)
                acc[i][j] = __builtin_amdgcn_mfma_f32_16x16x32_bf16(a[i], b[j], acc[i][j], 0, 0, 0);
        __builtin_amdgcn_s_setprio(0);
        __syncthreads();
    }

    // C/D layout: col=lane&15, row=(lane>>4)*4+reg
#pragma unroll
    for (int j = 0; j < 4; ++j) {
        const int cn = n0 + wn + j*16 + lr;
        const float bv = bias[cn];
#pragma unroll
        for (int i = 0; i < 4; ++i) {
            const int cm = m0 + wm + i*16 + lg*4;
#pragma unroll
            for (int r = 0; r < 4; ++r) {
                const float val = acc[i][j][r] + bv;
                if (OF32) ((float*)Cp)[(size_t)(cm + r) * N + cn] = val;
                else      ((u16*)Cp) [(size_t)(cm + r) * N + cn] = f2b(val);
            }
        }
    }
}

// ---------------------------------------------------------------------------
// LayerNorm over E=1024 per row. OUTMODE: 0=bf16 flat, 1=f32 head scatter, 2=f32 flat.
// ---------------------------------------------------------------------------
template<int INF32, int OUTMODE>
__global__ void ln_k(const void* src, const float* __restrict__ g,
                     const float* __restrict__ be, void* dst)
{
    __shared__ float red[8];
    const int row = blockIdx.x;
    const int tid = threadIdx.x;
    const int lane = tid & 63, wave = tid >> 6;
    float f[4];
    if (INF32) {
        float4 v = *(const float4*)&((const float*)src)[(size_t)row * 1024 + tid * 4];
        f[0] = v.x; f[1] = v.y; f[2] = v.z; f[3] = v.w;
    } else {
        ushort4 v = *(const ushort4*)&((const u16*)src)[(size_t)row * 1024 + tid * 4];
        f[0] = b2f(v.x); f[1] = b2f(v.y); f[2] = b2f(v.z); f[3] = b2f(v.w);
    }
    float s  = f[0] + f[1] + f[2] + f[3];
    float ss = f[0]*f[0] + f[1]*f[1] + f[2]*f[2] + f[3]*f[3];
#pragma unroll
    for (int off = 32; off; off >>= 1) { s += __shfl_down(s, off); ss += __shfl_down(ss, off); }
    if (lane == 0) { red[wave] = s; red[4 + wave] = ss; }
    __syncthreads();
    s  = red[0] + red[1] + red[2] + red[3];
    ss = red[4] + red[5] + red[6] + red[7];
    const float mean = s * (1.0f / 1024.0f);
    const float var  = fmaxf(ss * (1.0f / 1024.0f) - mean * mean, 0.0f);
    const float rs   = rsqrtf(var + 1e-5f);
    float o[4];
#pragma unroll
    for (int k = 0; k < 4; ++k) {
        const int e = tid * 4 + k;
        o[k] = (f[k] - mean) * rs * g[e] + be[e];
    }
    if (OUTMODE == 0) {
        ushort4 ov; ov.x = f2b(o[0]); ov.y = f2b(o[1]); ov.z = f2b(o[2]); ov.w = f2b(o[3]);
        *(ushort4*)&((u16*)dst)[(size_t)row * 1024 + tid * 4] = ov;
    } else if (OUTMODE == 1) {
        const int b = row >> 11, sIdx = row & 2047;
        const int h = tid >> 4, hd = (tid * 4) & 63;
        float4 ov = { o[0], o[1], o[2], o[3] };
        *(float4*)&((float*)dst)[(((size_t)(b * 16 + h) * 2048 + sIdx) << 6) + hd] = ov;
    } else {
        float4 ov = { o[0], o[1], o[2], o[3] };
        *(float4*)&((float*)dst)[(size_t)row * 1024 + tid * 4] = ov;
    }
}

// ---------------------------------------------------------------------------
// Causal flash attention. Grid (32, 64), 4 waves x 16 q-rows, KVBLK=64.
// All LDS tiles XOR-swizzled (swz) to kill 16-way bank conflicts.
// ---------------------------------------------------------------------------
__global__ __launch_bounds__(256, 4)
void attn_k(const u16* __restrict__ Qf, const u16* __restrict__ Kf,
            const float* __restrict__ Vf, u16* __restrict__ O)
{
    __shared__ u16 Ks [64 * 64];      // [kv][hd], swizzled
    __shared__ u16 Vts[64 * 64];      // [hd][kv], swizzled (transposed)
    __shared__ u16 Ps [4][16 * 64];   // per-wave [qrow][kv], swizzled
    const int qt = blockIdx.x, bh = blockIdx.y;
    const int b = bh >> 4, h = bh & 15;
    const int tid = threadIdx.x, wave = tid >> 6, lane = tid & 63;
    const int lg = lane >> 4, lr = lane & 15;
    const int q0 = qt * 64;
    const u16* Qbh = Qf + ((size_t)b * 2048) * 1024 + h * 64;
    const u16* Kbh = Kf + ((size_t)b * 2048) * 1024 + h * 64;
    const float* Vb = Vf + (size_t)bh * 2048 * 64;

    // Q frags in registers (A-frag: row=lane&15, k=8*(lane>>4)+j)
    const int qrow = q0 + wave * 16 + lr;
    const short8 qf0 = *(const short8*)&Qbh[(size_t)qrow * 1024 + lg * 8];
    const short8 qf1 = *(const short8*)&Qbh[(size_t)qrow * 1024 + 32 + lg * 8];

    f32x4 oacc[4] = {};
    float m_r[4] = { -1e30f, -1e30f, -1e30f, -1e30f };
    float l_r[4] = { 0.f, 0.f, 0.f, 0.f };
    const int myrow0 = q0 + wave * 16 + lg * 4;
    const int vr = lane;               // V staging: this lane's kv row

    for (int kv = 0; kv <= qt; ++kv) {
        const int kv0 = kv * 64;
        // K: thread -> (row id>>3, 16B chunk id&7), swizzled b128 writes
#pragma unroll
        for (int it = 0; it < 2; ++it) {
            const int id = tid + it * 256;
            const int r = id >> 3, c8 = (id & 7) * 8;
            *(uint4*)&Ks[swz(r, c8)] = *(const uint4*)&Kbh[(size_t)(kv0 + r) * 1024 + c8];
        }
        // V: lane-per-kv-row, scalar swizzled transposed writes (banks spread by r)
#pragma unroll
        for (int it = 0; it < 2; ++it) {
            const int c = wave * 2 + it;                 // hd chunk 0..7
            float4 v0 = *(const float4*)&Vb[(size_t)(kv0 + vr) * 64 + c * 8];
            float4 v1 = *(const float4*)&Vb[(size_t)(kv0 + vr) * 64 + c * 8 + 4];
            const float vv[8] = { v0.x, v0.y, v0.z, v0.w, v1.x, v1.y, v1.z, v1.w };
#pragma unroll
            for (int j = 0; j < 8; ++j)
                Vts[swz(c * 8 + j, vr)] = f2b(vv[j]);
        }
        __syncthreads();

        // S = Q K^T (16x64 per wave)
        f32x4 sacc[4];
#pragma unroll
        for (int c = 0; c < 4; ++c) {
            const int row = c * 16 + lr;
            const short8 k0 = *(const short8*)&Ks[swz(row, lg * 8)];
            const short8 k1 = *(const short8*)&Ks[swz(row, 32 + lg * 8)];
            f32x4 z = { 0.f, 0.f, 0.f, 0.f };
            __builtin_amdgcn_s_setprio(1);
            z = __builtin_amdgcn_mfma_f32_16x16x32_bf16(qf0, k0, z, 0, 0, 0);
            z = __builtin_amdgcn_mfma_f32_16x16x32_bf16(qf1, k1, z, 0, 0, 0);
            __builtin_amdgcn_s_setprio(0);
            sacc[c] = z;
        }

        // scale + causal mask + wave-parallel online softmax (16-lane row groups)
#pragma unroll
        for (int r = 0; r < 4; ++r) {
            const int rowg = myrow0 + r;
            float mx = -1e30f;
#pragma unroll
            for (int c = 0; c < 4; ++c) {
                float sv = sacc[c][r] * 0.125f;
                const int col = kv0 + c * 16 + lr;
                if (col > rowg) sv = -1e30f;
                sacc[c][r] = sv;
                mx = fmaxf(mx, sv);
            }
#pragma unroll
            for (int d = 1; d < 16; d <<= 1) mx = fmaxf(mx, __shfl_xor(mx, d));
            const float mnew = fmaxf(m_r[r], mx);
            const float al = __expf(m_r[r] - mnew);
            m_r[r] = mnew;
            float rsum = 0.f;
#pragma unroll
            for (int c = 0; c < 4; ++c) {
                const float p = __expf(sacc[c][r] - mnew);
                sacc[c][r] = p;
                rsum += p;
            }
#pragma unroll
            for (int d = 1; d < 16; d <<= 1) rsum += __shfl_xor(rsum, d);
            l_r[r] = l_r[r] * al + rsum;
#pragma unroll
            for (int c2 = 0; c2 < 4; ++c2) oacc[c2][r] *= al;
        }

        // P -> LDS (wave-local, swizzled), then PV MFMA
#pragma unroll
        for (int r = 0; r < 4; ++r)
#pragma unroll
            for (int c = 0; c < 4; ++c)
                Ps[wave][swz(lg * 4 + r, c * 16 + lr)] = f2b(sacc[c][r]);
#pragma unroll
        for (int s2 = 0; s2 < 2; ++s2) {
            const short8 pa = *(const short8*)&Ps[wave][swz(lr, s2 * 32 + lg * 8)];
            __builtin_amdgcn_s_setprio(1);
#pragma unroll
            for (int c2 = 0; c2 < 4; ++c2) {
                const short8 vb = *(const short8*)&Vts[swz(c2 * 16 + lr, s2 * 32 + lg * 8)];
                oacc[c2] = __builtin_amdgcn_mfma_f32_16x16x32_bf16(pa, vb, oacc[c2], 0, 0, 0);
            }
            __builtin_amdgcn_s_setprio(0);
        }
        __syncthreads();
    }

#pragma unroll
    for (int c2 = 0; c2 < 4; ++c2)
#pragma unroll
        for (int r = 0; r < 4; ++r) {
            const float ov = oacc[c2][r] / l_r[r];
            O[((size_t)b * 2048 + myrow0 + r) * 1024 + h * 64 + c2 * 16 + lr] = f2b(ov);
        }
}

// ---------------------------------------------------------------------------
extern "C" void kernel_launch(void* const* d_in, const int* in_sizes, int n_in,
                              void* d_out, int out_size, void* d_ws, size_t ws_size,
                              hipStream_t stream)
{
    (void)in_sizes; (void)n_in; (void)out_size; (void)ws_size;
    const float* x   = (const float*)d_in[0];
    const float* wq  = (const float*)d_in[1];  const float* bq   = (const float*)d_in[2];
    const float* wk  = (const float*)d_in[3];  const float* bk   = (const float*)d_in[4];
    const float* wv  = (const float*)d_in[5];  const float* bv   = (const float*)d_in[6];
    const float* wp  = (const float*)d_in[7];  const float* bp   = (const float*)d_in[8];
    const float* g_q = (const float*)d_in[9];  const float* be_q = (const float*)d_in[10];
    const float* g_k = (const float*)d_in[11]; const float* be_k = (const float*)d_in[12];
    const float* g_v = (const float*)d_in[13]; const float* be_v = (const float*)d_in[14];
    const float* g_p = (const float*)d_in[15]; const float* be_p = (const float*)d_in[16];

    float* outF = (float*)d_out;            // final out f32 [B,S,E]
    float* Vf   = outF + 8388608;           // final V f32 [B,H,S,HD]
    u16* D0 = (u16*)d_out;                  // bf16 scratch: Q flat
    u16* D1 = (u16*)d_out + 8388608;        // bf16 scratch: K flat
    char* ws = (char*)d_ws;
    u16* S0  = (u16*)ws;                    // 16.78 MB: V-preLN bf16 -> attnout bf16
    u16* wqb = (u16*)(ws + 16777216);
    u16* wkb = wqb + 1048576;
    u16* wvb = wkb + 1048576;
    u16* wpb = wvb + 1048576;

    const dim3 gg(64, 8), bb(256), cg(1024);
    cvt_k<<<cg, bb, 0, stream>>>(wq, wqb);
    cvt_k<<<cg, bb, 0, stream>>>(wk, wkb);
    cvt_k<<<cg, bb, 0, stream>>>(wv, wvb);
    cvt_k<<<cg, bb, 0, stream>>>(wp, wpb);

    gemm_k<true, false><<<gg, bb, 0, stream>>>(x, wqb, bq, D0, 8192, 1024, 1024);
    ln_k<0, 0><<<dim3(8192), bb, 0, stream>>>(D0, g_q, be_q, D0);
    gemm_k<true, false><<<gg, bb, 0, stream>>>(x, wkb, bk, D1, 8192, 1024, 1024);
    ln_k<0, 0><<<dim3(8192), bb, 0, stream>>>(D1, g_k, be_k, D1);
    gemm_k<true, false><<<gg, bb, 0, stream>>>(x, wvb, bv, S0, 8192, 1024, 1024);
    ln_k<0, 1><<<dim3(8192), bb, 0, stream>>>(S0, g_v, be_v, Vf);
    attn_k<<<dim3(32, 64), bb, 0, stream>>>(D0, D1, Vf, S0);
    gemm_k<false, true><<<gg, bb, 0, stream>>>(S0, wpb, bp, outF, 8192, 1024, 1024);
    ln_k<1, 2><<<dim3(8192), bb, 0, stream>>>(outF, g_p, be_p, outF);
}

// Round 5
// 349.658 us; speedup vs baseline: 1.6788x; 1.2919x over previous
//
#include <hip/hip_runtime.h>
#include <hip/hip_bf16.h>

// B=4, S=2048, E=1024, H=16, HD=64. d_in/d_out are FLOAT32; compute in bf16 MFMA.
typedef unsigned short u16;
typedef __attribute__((ext_vector_type(8))) short short8;   // 8 bf16 (MFMA A/B frag)
typedef __attribute__((ext_vector_type(4))) float f32x4;    // MFMA C/D frag

__device__ __forceinline__ float b2f(u16 u){
    unsigned v = ((unsigned)u) << 16; float f; __builtin_memcpy(&f, &v, 4); return f;
}
__device__ __forceinline__ u16 f2b(float f){
    unsigned v; __builtin_memcpy(&v, &f, 4);
    v += 0x7fffu + ((v >> 16) & 1u);   // round-to-nearest-even
    return (u16)(v >> 16);
}

__device__ __forceinline__ void gload16(const void* g, void* l){
    __builtin_amdgcn_global_load_lds((const __attribute__((address_space(1))) unsigned int*)g,
                                     (__attribute__((address_space(3))) unsigned int*)l, 16, 0, 0);
}

// XOR bank swizzle for 64-u16-wide LDS rows (row stride 128B). u16-index form;
// preserves 16B alignment of 8-elem groups.
__device__ __forceinline__ int swz(int row, int col){
    return row * 64 + (col ^ ((row & 7) << 3));
}

// ---------------------------------------------------------------------------
// fused f32->bf16 convert for the 4 weight matrices (each 1024x1024)
// grid (1024, 4)
// ---------------------------------------------------------------------------
__global__ void cvt4_k(const float* __restrict__ s0, const float* __restrict__ s1,
                       const float* __restrict__ s2, const float* __restrict__ s3,
                       u16* __restrict__ dst)   // 4 matrices contiguous in dst
{
    const float* src = (blockIdx.y == 0) ? s0 : (blockIdx.y == 1) ? s1 :
                       (blockIdx.y == 2) ? s2 : s3;
    const int i = (blockIdx.x * 256 + threadIdx.x) * 4;
    float4 v = *(const float4*)&src[i];
    ushort4 o;
    o.x = f2b(v.x); o.y = f2b(v.y); o.z = f2b(v.z); o.w = f2b(v.w);
    *(ushort4*)&dst[(size_t)blockIdx.y * 1048576 + i] = o;
}

// ---------------------------------------------------------------------------
// GEMM: C[M][N] = A[M][K] @ W[N][K]^T + bias[N]
// ---------------------------------------------------------------------------
template<bool AF32, bool OF32>
__global__ __launch_bounds__(256, 2)
void gemm_k(const void* __restrict__ Ap, const u16* __restrict__ W,
            const float* __restrict__ bias, void* __restrict__ Cp,
            int M, int N, int K)
{
    __shared__ char AsRaw[AF32 ? 16384 : 8192];   // f32 or bf16 A tile (union)
    __shared__ u16  Bs[128 * 32];                 // 8 KB
    float* Asf = (float*)AsRaw;
    u16*   Asb = (u16*)AsRaw;
    const int tid  = threadIdx.x;
    const int wave = tid >> 6;
    const int lane = tid & 63;
    const int lg = lane >> 4, lr = lane & 15;
    const int m0 = blockIdx.x * 128, n0 = blockIdx.y * 128;
    const int wm = (wave >> 1) * 64, wn = (wave & 1) * 64;

    const u16* bG = W + (size_t)(n0 + (tid >> 2)) * K + (tid & 3) * 8;
    char* bsBase = (char*)Bs + wave * 1024;
    const size_t brstep = (size_t)64 * K;

    const float* aGf = (const float*)Ap + (size_t)(m0 + (tid >> 3)) * K + (tid & 7) * 4;
    const size_t arstepf = (size_t)32 * K;
    const u16* aGb = (const u16*)Ap + (size_t)(m0 + (tid >> 2)) * K + (tid & 3) * 8;
    char* asBase = (char*)AsRaw + wave * 1024;

    f32x4 acc[4][4] = {};

    for (int kt = 0; kt < K; kt += 32) {
        if (AF32) {
#pragma unroll
            for (int i = 0; i < 4; ++i)
                gload16(aGf + kt + i * arstepf, asBase + i * 4096);
        } else {
            gload16(aGb + kt,          asBase);
            gload16(aGb + kt + brstep, asBase + 4096);
        }
        gload16(bG + kt,          bsBase);
        gload16(bG + kt + brstep, bsBase + 4096);
        __syncthreads();

        short8 a[4], b[4];
#pragma unroll
        for (int i = 0; i < 4; ++i) {
            const int row = wm + i * 16 + lr;
            if (AF32) {
                float4 f0 = *(const float4*)&Asf[row * 32 + lg * 8];
                float4 f1 = *(const float4*)&Asf[row * 32 + lg * 8 + 4];
                u16* ap = (u16*)&a[i];
                ap[0] = f2b(f0.x); ap[1] = f2b(f0.y); ap[2] = f2b(f0.z); ap[3] = f2b(f0.w);
                ap[4] = f2b(f1.x); ap[5] = f2b(f1.y); ap[6] = f2b(f1.z); ap[7] = f2b(f1.w);
            } else {
                a[i] = *(const short8*)&Asb[row * 32 + lg * 8];
            }
        }
#pragma unroll
        for (int j = 0; j < 4; ++j) b[j] = *(const short8*)&Bs[(wn + j*16 + lr)*32 + lg*8];
        __builtin_amdgcn_s_setprio(1);
#pragma unroll
        for (int i = 0; i < 4; ++i)
#pragma unroll
            for (int j = 0; j < 4; ++j)
                acc[i][j] = __builtin_amdgcn_mfma_f32_16x16x32_bf16(a[i], b[j], acc[i][j], 0, 0, 0);
        __builtin_amdgcn_s_setprio(0);
        __syncthreads();
    }

    // C/D layout: col=lane&15, row=(lane>>4)*4+reg
#pragma unroll
    for (int j = 0; j < 4; ++j) {
        const int cn = n0 + wn + j*16 + lr;
        const float bv = bias[cn];
#pragma unroll
        for (int i = 0; i < 4; ++i) {
            const int cm = m0 + wm + i*16 + lg*4;
#pragma unroll
            for (int r = 0; r < 4; ++r) {
                const float val = acc[i][j][r] + bv;
                if (OF32) ((float*)Cp)[(size_t)(cm + r) * N + cn] = val;
                else      ((u16*)Cp) [(size_t)(cm + r) * N + cn] = f2b(val);
            }
        }
    }
}

// ---------------------------------------------------------------------------
// LayerNorm over E=1024 per row, output scaled by `scale`.
// OUTMODE: 0=bf16 flat (in-place ok), 1=f32 head scatter [B,H,S,HD], 2=f32 flat.
// ---------------------------------------------------------------------------
template<int INF32, int OUTMODE>
__global__ void ln_k(const void* src, const float* __restrict__ g,
                     const float* __restrict__ be, void* dst, float scale)
{
    __shared__ float red[8];
    const int row = blockIdx.x;
    const int tid = threadIdx.x;
    const int lane = tid & 63, wave = tid >> 6;
    float f[4];
    if (INF32) {
        float4 v = *(const float4*)&((const float*)src)[(size_t)row * 1024 + tid * 4];
        f[0] = v.x; f[1] = v.y; f[2] = v.z; f[3] = v.w;
    } else {
        ushort4 v = *(const ushort4*)&((const u16*)src)[(size_t)row * 1024 + tid * 4];
        f[0] = b2f(v.x); f[1] = b2f(v.y); f[2] = b2f(v.z); f[3] = b2f(v.w);
    }
    float s  = f[0] + f[1] + f[2] + f[3];
    float ss = f[0]*f[0] + f[1]*f[1] + f[2]*f[2] + f[3]*f[3];
#pragma unroll
    for (int off = 32; off; off >>= 1) { s += __shfl_down(s, off); ss += __shfl_down(ss, off); }
    if (lane == 0) { red[wave] = s; red[4 + wave] = ss; }
    __syncthreads();
    s  = red[0] + red[1] + red[2] + red[3];
    ss = red[4] + red[5] + red[6] + red[7];
    const float mean = s * (1.0f / 1024.0f);
    const float var  = fmaxf(ss * (1.0f / 1024.0f) - mean * mean, 0.0f);
    const float rs   = rsqrtf(var + 1e-5f);
    float o[4];
#pragma unroll
    for (int k = 0; k < 4; ++k) {
        const int e = tid * 4 + k;
        o[k] = ((f[k] - mean) * rs * g[e] + be[e]) * scale;
    }
    if (OUTMODE == 0) {
        ushort4 ov; ov.x = f2b(o[0]); ov.y = f2b(o[1]); ov.z = f2b(o[2]); ov.w = f2b(o[3]);
        *(ushort4*)&((u16*)dst)[(size_t)row * 1024 + tid * 4] = ov;
    } else if (OUTMODE == 1) {
        const int b = row >> 11, sIdx = row & 2047;
        const int h = tid >> 4, hd = (tid * 4) & 63;
        float4 ov = { o[0], o[1], o[2], o[3] };
        *(float4*)&((float*)dst)[(((size_t)(b * 16 + h) * 2048 + sIdx) << 6) + hd] = ov;
    } else {
        float4 ov = { o[0], o[1], o[2], o[3] };
        *(float4*)&((float*)dst)[(size_t)row * 1024 + tid * 4] = ov;
    }
}

// ---------------------------------------------------------------------------
// Causal flash attention, balanced + pipelined.
// Grid (16, 64): block handles q-tiles {x, 31-x} -> constant 33 kv-iters/block.
// Per iter: issue next K (global_load_lds, pre-swizzled src) + next V (->regs),
// compute current from LDS double-buffer, write V regs->LDS late, ONE barrier.
// Q is pre-scaled by 1/8 in its LN. Row-sum l rides a ones-column MFMA.
// ---------------------------------------------------------------------------
__global__ __launch_bounds__(256, 4)
void attn_k(const u16* __restrict__ Qf, const u16* __restrict__ Kf,
            const float* __restrict__ Vf, u16* __restrict__ O)
{
    __shared__ u16 Ks [2][64 * 64];   // [buf][kv][hd]  (8 KB each)
    __shared__ u16 Vts[2][64 * 64];   // [buf][hd][kv]  (transposed)
    __shared__ u16 Ps [4][16 * 64];   // per-wave P tile
    const int bh = blockIdx.y;
    const int b = bh >> 4, h = bh & 15;
    const int tid = threadIdx.x, wave = tid >> 6, lane = tid & 63;
    const int lg = lane >> 4, lr = lane & 15;
    const u16* Qbh = Qf + ((size_t)b * 2048) * 1024 + h * 64;
    const u16* Kbh = Kf + ((size_t)b * 2048) * 1024 + h * 64;
    const float* Vb = Vf + (size_t)bh * 2048 * 64;

    const short s1 = (short)0x3F80;   // bf16 1.0
    const short8 ones = { s1,s1,s1,s1,s1,s1,s1,s1 };

    for (int half = 0; half < 2; ++half) {
        const int qt = half ? (31 - (int)blockIdx.x) : (int)blockIdx.x;
        const int q0 = qt * 64;
        const int qrow = q0 + wave * 16 + lr;
        const short8 qf0 = *(const short8*)&Qbh[(size_t)qrow * 1024 + lg * 8];
        const short8 qf1 = *(const short8*)&Qbh[(size_t)qrow * 1024 + 32 + lg * 8];
        const int myrow0 = q0 + wave * 16 + lg * 4;

        f32x4 oacc[4] = {};
        f32x4 lacc = { 0.f, 0.f, 0.f, 0.f };
        float m_r[4] = { -1e30f, -1e30f, -1e30f, -1e30f };
        float vreg[16];

        // ---- prologue: stage tile 0 into buf 0 ----
#pragma unroll
        for (int it = 0; it < 2; ++it) {
            const int id = tid + it * 256;
            const int r = id >> 3, c = (id & 7) ^ (r & 7);   // pre-swizzled source chunk
            gload16(Kbh + (size_t)r * 1024 + c * 8,
                    (char*)Ks[0] + it * 4096 + wave * 1024);
        }
#pragma unroll
        for (int it = 0; it < 2; ++it) {
            const int c = wave * 2 + it;
            *(float4*)&vreg[it*8]     = *(const float4*)&Vb[(size_t)lane * 64 + c * 8];
            *(float4*)&vreg[it*8 + 4] = *(const float4*)&Vb[(size_t)lane * 64 + c * 8 + 4];
        }
#pragma unroll
        for (int it = 0; it < 2; ++it) {
            const int c = wave * 2 + it;
#pragma unroll
            for (int j = 0; j < 8; ++j)
                Vts[0][swz(c * 8 + j, lane)] = f2b(vreg[it*8 + j]);
        }
        __syncthreads();

        for (int kv = 0; kv <= qt; ++kv) {
            const int cur = kv & 1, nxt = cur ^ 1;
            const int kv0 = kv * 64;
            const bool hasNext = (kv < qt);

            // ---- issue next tile's loads (overlap with compute below) ----
            if (hasNext) {
                const int kvn = kv0 + 64;
#pragma unroll
                for (int it = 0; it < 2; ++it) {
                    const int id = tid + it * 256;
                    const int r = id >> 3, c = (id & 7) ^ (r & 7);
                    gload16(Kbh + (size_t)(kvn + r) * 1024 + c * 8,
                            (char*)Ks[nxt] + it * 4096 + wave * 1024);
                }
#pragma unroll
                for (int it = 0; it < 2; ++it) {
                    const int c = wave * 2 + it;
                    *(float4*)&vreg[it*8]     = *(const float4*)&Vb[(size_t)(kvn + lane) * 64 + c * 8];
                    *(float4*)&vreg[it*8 + 4] = *(const float4*)&Vb[(size_t)(kvn + lane) * 64 + c * 8 + 4];
                }
            }

            // ---- QK^T (16x64 per wave) ----
            f32x4 sacc[4];
#pragma unroll
            for (int c = 0; c < 4; ++c) {
                const int row = c * 16 + lr;
                const short8 k0 = *(const short8*)&Ks[cur][swz(row, lg * 8)];
                const short8 k1 = *(const short8*)&Ks[cur][swz(row, 32 + lg * 8)];
                f32x4 z = { 0.f, 0.f, 0.f, 0.f };
                __builtin_amdgcn_s_setprio(1);
                z = __builtin_amdgcn_mfma_f32_16x16x32_bf16(qf0, k0, z, 0, 0, 0);
                z = __builtin_amdgcn_mfma_f32_16x16x32_bf16(qf1, k1, z, 0, 0, 0);
                __builtin_amdgcn_s_setprio(0);
                sacc[c] = z;
            }

            // ---- mask + online softmax (no scale: Q pre-scaled) ----
#pragma unroll
            for (int r = 0; r < 4; ++r) {
                const int rowg = myrow0 + r;
                float mx = -1e30f;
#pragma unroll
                for (int c = 0; c < 4; ++c) {
                    float sv = sacc[c][r];
                    if (kv0 + c * 16 + lr > rowg) sv = -1e30f;
                    sacc[c][r] = sv;
                    mx = fmaxf(mx, sv);
                }
#pragma unroll
                for (int d = 1; d < 16; d <<= 1) mx = fmaxf(mx, __shfl_xor(mx, d));
                const float mnew = fmaxf(m_r[r], mx);
                const float al = __expf(m_r[r] - mnew);
                m_r[r] = mnew;
#pragma unroll
                for (int c = 0; c < 4; ++c) sacc[c][r] = __expf(sacc[c][r] - mnew);
#pragma unroll
                for (int c2 = 0; c2 < 4; ++c2) oacc[c2][r] *= al;
                lacc[r] *= al;
            }

            // ---- P -> LDS (wave-local), PV + ones-MFMA row-sum ----
#pragma unroll
            for (int r = 0; r < 4; ++r)
#pragma unroll
                for (int c = 0; c < 4; ++c)
                    Ps[wave][swz(lg * 4 + r, c * 16 + lr)] = f2b(sacc[c][r]);
#pragma unroll
            for (int s2 = 0; s2 < 2; ++s2) {
                const short8 pa = *(const short8*)&Ps[wave][swz(lr, s2 * 32 + lg * 8)];
                __builtin_amdgcn_s_setprio(1);
                lacc = __builtin_amdgcn_mfma_f32_16x16x32_bf16(pa, ones, lacc, 0, 0, 0);
#pragma unroll
                for (int c2 = 0; c2 < 4; ++c2) {
                    const short8 vb = *(const short8*)&Vts[cur][swz(c2 * 16 + lr, s2 * 32 + lg * 8)];
                    oacc[c2] = __builtin_amdgcn_mfma_f32_16x16x32_bf16(pa, vb, oacc[c2], 0, 0, 0);
                }
                __builtin_amdgcn_s_setprio(0);
            }

            // ---- late V write into next buffer ----
            if (hasNext) {
#pragma unroll
                for (int it = 0; it < 2; ++it) {
                    const int c = wave * 2 + it;
#pragma unroll
                    for (int j = 0; j < 8; ++j)
                        Vts[nxt][swz(c * 8 + j, lane)] = f2b(vreg[it*8 + j]);
                }
            }
            __syncthreads();   // drains K gloads (vmcnt0) + LDS; next tile ready
        }

        // ---- epilogue ----
#pragma unroll
        for (int c2 = 0; c2 < 4; ++c2)
#pragma unroll
            for (int r = 0; r < 4; ++r) {
                const float ov = oacc[c2][r] / lacc[r];
                O[((size_t)b * 2048 + myrow0 + r) * 1024 + h * 64 + c2 * 16 + lr] = f2b(ov);
            }
    }
}

// ---------------------------------------------------------------------------
extern "C" void kernel_launch(void* const* d_in, const int* in_sizes, int n_in,
                              void* d_out, int out_size, void* d_ws, size_t ws_size,
                              hipStream_t stream)
{
    (void)in_sizes; (void)n_in; (void)out_size; (void)ws_size;
    const float* x   = (const float*)d_in[0];
    const float* wq  = (const float*)d_in[1];  const float* bq   = (const float*)d_in[2];
    const float* wk  = (const float*)d_in[3];  const float* bk   = (const float*)d_in[4];
    const float* wv  = (const float*)d_in[5];  const float* bv   = (const float*)d_in[6];
    const float* wp  = (const float*)d_in[7];  const float* bp   = (const float*)d_in[8];
    const float* g_q = (const float*)d_in[9];  const float* be_q = (const float*)d_in[10];
    const float* g_k = (const float*)d_in[11]; const float* be_k = (const float*)d_in[12];
    const float* g_v = (const float*)d_in[13]; const float* be_v = (const float*)d_in[14];
    const float* g_p = (const float*)d_in[15]; const float* be_p = (const float*)d_in[16];

    float* outF = (float*)d_out;            // final out f32 [B,S,E]
    float* Vf   = outF + 8388608;           // final V f32 [B,H,S,HD]
    u16* D0 = (u16*)d_out;                  // bf16 scratch: Q flat (pre-scaled 1/8)
    u16* D1 = (u16*)d_out + 8388608;        // bf16 scratch: K flat
    char* ws = (char*)d_ws;
    u16* S0  = (u16*)ws;                    // 16.78 MB: V-preLN bf16 -> attnout bf16
    u16* wb  = (u16*)(ws + 16777216);       // 4x 1024x1024 bf16 weights contiguous
    u16* wqb = wb;
    u16* wkb = wb + 1048576;
    u16* wvb = wb + 2097152;
    u16* wpb = wb + 3145728;

    const dim3 gg(64, 8), bb(256);
    cvt4_k<<<dim3(1024, 4), bb, 0, stream>>>(wq, wk, wv, wp, wb);

    gemm_k<true, false><<<gg, bb, 0, stream>>>(x, wqb, bq, D0, 8192, 1024, 1024);
    ln_k<0, 0><<<dim3(8192), bb, 0, stream>>>(D0, g_q, be_q, D0, 0.125f);  // Q pre-scaled
    gemm_k<true, false><<<gg, bb, 0, stream>>>(x, wkb, bk, D1, 8192, 1024, 1024);
    ln_k<0, 0><<<dim3(8192), bb, 0, stream>>>(D1, g_k, be_k, D1, 1.0f);
    gemm_k<true, false><<<gg, bb, 0, stream>>>(x, wvb, bv, S0, 8192, 1024, 1024);
    ln_k<0, 1><<<dim3(8192), bb, 0, stream>>>(S0, g_v, be_v, Vf, 1.0f);
    attn_k<<<dim3(16, 64), bb, 0, stream>>>(D0, D1, Vf, S0);
    gemm_k<false, true><<<gg, bb, 0, stream>>>(S0, wpb, bp, outF, 8192, 1024, 1024);
    ln_k<1, 2><<<dim3(8192), bb, 0, stream>>>(outF, g_p, be_p, outF, 1.0f);
}

// Round 6
// 271.340 us; speedup vs baseline: 2.1633x; 1.2886x over previous
//
#include <hip/hip_runtime.h>
#include <hip/hip_bf16.h>

// B=4, S=2048, E=1024, H=16, HD=64. d_in/d_out are FLOAT32; compute in bf16 MFMA.
typedef unsigned short u16;
typedef __attribute__((ext_vector_type(8))) short short8;   // 8 bf16 (MFMA A/B frag)
typedef __attribute__((ext_vector_type(4))) float f32x4;    // MFMA C/D frag

__device__ __forceinline__ float b2f(u16 u){
    unsigned v = ((unsigned)u) << 16; float f; __builtin_memcpy(&f, &v, 4); return f;
}
__device__ __forceinline__ u16 f2b(float f){
    unsigned v; __builtin_memcpy(&v, &f, 4);
    v += 0x7fffu + ((v >> 16) & 1u);   // round-to-nearest-even
    return (u16)(v >> 16);
}

__device__ __forceinline__ void gload16(const void* g, void* l){
    __builtin_amdgcn_global_load_lds((const __attribute__((address_space(1))) unsigned int*)g,
                                     (__attribute__((address_space(3))) unsigned int*)l, 16, 0, 0);
}

// XOR bank swizzle for 64-u16-wide LDS rows (row stride 128B). u16-index form;
// preserves 16B alignment of 8-elem chunks.
__device__ __forceinline__ int swz(int row, int col){
    return row * 64 + (col ^ ((row & 7) << 3));
}

// ---------------------------------------------------------------------------
// f32 -> bf16 converts
// ---------------------------------------------------------------------------
__global__ void cvt_k(const float* __restrict__ src, u16* __restrict__ dst)
{
    const int i = (blockIdx.x * 256 + threadIdx.x) * 4;
    float4 v = *(const float4*)&src[i];
    ushort4 o;
    o.x = f2b(v.x); o.y = f2b(v.y); o.z = f2b(v.z); o.w = f2b(v.w);
    *(ushort4*)&dst[i] = o;
}

__global__ void cvt4_k(const float* __restrict__ s0, const float* __restrict__ s1,
                       const float* __restrict__ s2, const float* __restrict__ s3,
                       u16* __restrict__ dst)   // 4 matrices contiguous
{
    const float* src = (blockIdx.y == 0) ? s0 : (blockIdx.y == 1) ? s1 :
                       (blockIdx.y == 2) ? s2 : s3;
    const int i = (blockIdx.x * 256 + threadIdx.x) * 4;
    float4 v = *(const float4*)&src[i];
    ushort4 o;
    o.x = f2b(v.x); o.y = f2b(v.y); o.z = f2b(v.z); o.w = f2b(v.w);
    *(ushort4*)&dst[(size_t)blockIdx.y * 1048576 + i] = o;
}

// ---------------------------------------------------------------------------
// GEMM: C[M][N] = A[M][K] @ W[N][K]^T + bias[N]   (bf16 in/out, f32 accum)
// m97 structure: 128x128 tile, BK=32, 4 waves (2x2), global_load_lds staging.
// ---------------------------------------------------------------------------
__global__ __launch_bounds__(256, 2)
void gemm_k(const u16* __restrict__ A, const u16* __restrict__ W,
            const float* __restrict__ bias, u16* __restrict__ C,
            int M, int N, int K)
{
    __shared__ u16 As[128 * 32];
    __shared__ u16 Bs[128 * 32];
    const int tid  = threadIdx.x;
    const int wave = tid >> 6, lane = tid & 63;
    const int lg = lane >> 4, lr = lane & 15;
    const int m0 = blockIdx.x * 128, n0 = blockIdx.y * 128;
    const int wm = (wave >> 1) * 64, wn = (wave & 1) * 64;

    const u16* aG = A + (size_t)(m0 + (tid >> 2)) * K + (tid & 3) * 8;
    const u16* bG = W + (size_t)(n0 + (tid >> 2)) * K + (tid & 3) * 8;
    char* asBase = (char*)As + wave * 1024;
    char* bsBase = (char*)Bs + wave * 1024;
    const size_t rstep = (size_t)64 * K;

    f32x4 acc[4][4] = {};

    for (int kt = 0; kt < K; kt += 32) {
        gload16(aG + kt,         asBase);
        gload16(aG + kt + rstep, asBase + 4096);
        gload16(bG + kt,         bsBase);
        gload16(bG + kt + rstep, bsBase + 4096);
        __syncthreads();

        short8 a[4], b[4];
#pragma unroll
        for (int i = 0; i < 4; ++i) a[i] = *(const short8*)&As[(wm + i*16 + lr)*32 + lg*8];
#pragma unroll
        for (int j = 0; j < 4; ++j) b[j] = *(const short8*)&Bs[(wn + j*16 + lr)*32 + lg*8];
        __builtin_amdgcn_s_setprio(1);
#pragma unroll
        for (int i = 0; i < 4; ++i)
#pragma unroll
            for (int j = 0; j < 4; ++j)
                acc[i][j] = __builtin_amdgcn_mfma_f32_16x16x32_bf16(a[i], b[j], acc[i][j], 0, 0, 0);
        __builtin_amdgcn_s_setprio(0);
        __syncthreads();
    }

    // C/D layout: col=lane&15, row=(lane>>4)*4+reg
#pragma unroll
    for (int j = 0; j < 4; ++j) {
        const int cn = n0 + wn + j*16 + lr;
        const float bv = bias[cn];
#pragma unroll
        for (int i = 0; i < 4; ++i) {
            const int cm = m0 + wm + i*16 + lg*4;
#pragma unroll
            for (int r = 0; r < 4; ++r)
                C[(size_t)(cm + r) * N + cn] = f2b(acc[i][j][r] + bv);
        }
    }
}

// ---------------------------------------------------------------------------
// LayerNorm over E=1024 per row (bf16 src), scaled output.
// OUTMODE: 0=bf16 flat (in-place ok), 1=f32 head scatter [B,H,S,HD], 2=f32 flat.
// ---------------------------------------------------------------------------
template<int OUTMODE>
__global__ void ln_k(const u16* src, const float* __restrict__ g,
                     const float* __restrict__ be, void* dst, float scale)
{
    __shared__ float red[8];
    const int row = blockIdx.x;
    const int tid = threadIdx.x;
    const int lane = tid & 63, wave = tid >> 6;
    ushort4 v = *(const ushort4*)&src[(size_t)row * 1024 + tid * 4];
    float f[4] = { b2f(v.x), b2f(v.y), b2f(v.z), b2f(v.w) };
    float s  = f[0] + f[1] + f[2] + f[3];
    float ss = f[0]*f[0] + f[1]*f[1] + f[2]*f[2] + f[3]*f[3];
#pragma unroll
    for (int off = 32; off; off >>= 1) { s += __shfl_down(s, off); ss += __shfl_down(ss, off); }
    if (lane == 0) { red[wave] = s; red[4 + wave] = ss; }
    __syncthreads();
    s  = red[0] + red[1] + red[2] + red[3];
    ss = red[4] + red[5] + red[6] + red[7];
    const float mean = s * (1.0f / 1024.0f);
    const float var  = fmaxf(ss * (1.0f / 1024.0f) - mean * mean, 0.0f);
    const float rs   = rsqrtf(var + 1e-5f);
    float o[4];
#pragma unroll
    for (int k = 0; k < 4; ++k) {
        const int e = tid * 4 + k;
        o[k] = ((f[k] - mean) * rs * g[e] + be[e]) * scale;
    }
    if (OUTMODE == 0) {
        ushort4 ov; ov.x = f2b(o[0]); ov.y = f2b(o[1]); ov.z = f2b(o[2]); ov.w = f2b(o[3]);
        *(ushort4*)&((u16*)dst)[(size_t)row * 1024 + tid * 4] = ov;
    } else if (OUTMODE == 1) {
        const int b = row >> 11, sIdx = row & 2047;
        const int h = tid >> 4, hd = (tid * 4) & 63;
        float4 ov = { o[0], o[1], o[2], o[3] };
        *(float4*)&((float*)dst)[(((size_t)(b * 16 + h) * 2048 + sIdx) << 6) + hd] = ov;
    } else {
        float4 ov = { o[0], o[1], o[2], o[3] };
        *(float4*)&((float*)dst)[(size_t)row * 1024 + tid * 4] = ov;
    }
}

// ---------------------------------------------------------------------------
// V transpose: Vf f32 [bh][s][64] -> Vt bf16 [bh][64(hd)][2048(s)].
// Grid 2048 = 64 bh x 32 s-tiles, 256 threads. LDS 64x65 f32 (conflict-free).
// ---------------------------------------------------------------------------
__global__ void vtr_k(const float* __restrict__ Vf, u16* __restrict__ Vt)
{
    __shared__ float T[64 * 65];
    const int bh = blockIdx.x >> 5, st = blockIdx.x & 31;
    const int tid = threadIdx.x;
    const float* src = Vf + (size_t)bh * 2048 * 64 + (size_t)st * 64 * 64;
#pragma unroll
    for (int it = 0; it < 4; ++it) {
        const int fid = tid + it * 256;            // 0..1023 float4s
        const int r = fid >> 4, c4 = fid & 15;
        float4 v = *(const float4*)&src[r * 64 + c4 * 4];
        T[r * 65 + c4*4 + 0] = v.x;
        T[r * 65 + c4*4 + 1] = v.y;
        T[r * 65 + c4*4 + 2] = v.z;
        T[r * 65 + c4*4 + 3] = v.w;
    }
    __syncthreads();
    u16* dst = Vt + (size_t)bh * 64 * 2048 + (size_t)st * 64;
#pragma unroll
    for (int it = 0; it < 2; ++it) {
        const int oid = tid + it * 256;            // 0..511
        const int hd = oid >> 3, ch = oid & 7;
        u16 tmp[8];
#pragma unroll
        for (int j = 0; j < 8; ++j) tmp[j] = f2b(T[(ch * 8 + j) * 65 + hd]);
        *(uint4*)&dst[(size_t)hd * 2048 + ch * 8] = *(uint4*)tmp;
    }
}

// ---------------------------------------------------------------------------
// Causal flash attention. QBLK=128 (8 waves x 16 rows), KVBLK=64, paired
// q-tiles {x, 15-x} -> 34 kv-iters/block. K and V^T staged via global_load_lds
// (source pre-swizzled). Q pre-scaled by 0.125*log2e; softmax in exp2 domain.
// Output written in-place over Q (block owns exactly its Q rows; Q preloaded).
// XCD remap: 8 blocks sharing one (b,h) K/V panel land on one XCD.
// ---------------------------------------------------------------------------
__global__ __launch_bounds__(512, 4)
void attn_k(const u16* __restrict__ Qf, const u16* __restrict__ Kf,
            const u16* __restrict__ Vt, u16* __restrict__ O)
{
    __shared__ u16 Ks [2][64 * 64];   // [buf][kv][hd] swizzled
    __shared__ u16 Vts[2][64 * 64];   // [buf][hd][kv] swizzled
    __shared__ u16 Ps [8][16 * 64];   // per-wave P tile swizzled
    // XCD-aware remap (dispatch i -> XCD i%8): XCD j gets bh in [8j, 8j+8)
    const int lin = (int)blockIdx.x + (int)blockIdx.y * 8;
    const int j8 = lin & 7, mm = lin >> 3;
    const int bh = 8 * j8 + (mm >> 3), xb_ = mm & 7;
    const int b = bh >> 4, h = bh & 15;
    const int tid = threadIdx.x, wave = tid >> 6, lane = tid & 63;
    const int lg = lane >> 4, lr = lane & 15;
    const u16* Qbh = Qf + ((size_t)b * 2048) * 1024 + h * 64;
    const u16* Kbh = Kf + ((size_t)b * 2048) * 1024 + h * 64;
    const u16* Vbh = Vt + (size_t)bh * 64 * 2048;     // [hd][s]
    u16* Obh = O + ((size_t)b * 2048) * 1024 + h * 64;

    // staging map: thread -> row tid>>3, pre-swizzled 16B chunk
    const int sr = tid >> 3;
    const int sc = (tid & 7) ^ (sr & 7);

    const short s1 = (short)0x3F80;
    const short8 ones = { s1,s1,s1,s1,s1,s1,s1,s1 };

    // preload Q frags for BOTH halves (out overwrites Q rows of this block only)
    const int qts[2] = { xb_, 15 - xb_ };
    short8 qfr[2][2];
#pragma unroll
    for (int hf = 0; hf < 2; ++hf) {
        const int qrow = qts[hf] * 128 + wave * 16 + lr;
        qfr[hf][0] = *(const short8*)&Qbh[(size_t)qrow * 1024 + lg * 8];
        qfr[hf][1] = *(const short8*)&Qbh[(size_t)qrow * 1024 + 32 + lg * 8];
    }

    for (int hf = 0; hf < 2; ++hf) {
        const int qt = qts[hf];
        const int q0w = qt * 128 + wave * 16;
        const int myrow0 = q0w + lg * 4;
        const int nkv = 2 * qt + 2;

        f32x4 oacc[4] = {};
        f32x4 lacc = { 0.f, 0.f, 0.f, 0.f };
        float m_r[4] = { -1e30f, -1e30f, -1e30f, -1e30f };

        // prologue: stage kv tile 0 into buf 0 (one 8KB issue each, 512 thr x 16B)
        gload16(Kbh + (size_t)sr * 1024 + sc * 8, (char*)Ks[0]  + wave * 1024);
        gload16(Vbh + (size_t)sr * 2048 + sc * 8, (char*)Vts[0] + wave * 1024);
        __syncthreads();

        for (int kv = 0; kv < nkv; ++kv) {
            const int cur = kv & 1, nxt = cur ^ 1;
            const int kv0 = kv * 64;
            if (kv + 1 < nkv) {
                const int kvn = kv0 + 64;
                gload16(Kbh + (size_t)(kvn + sr) * 1024 + sc * 8, (char*)Ks[nxt]  + wave * 1024);
                gload16(Vbh + (size_t)sr * 2048 + kvn + sc * 8,   (char*)Vts[nxt] + wave * 1024);
            }

            // QK^T (16x64 per wave)
            f32x4 sacc[4];
#pragma unroll
            for (int c = 0; c < 4; ++c) {
                const int row = c * 16 + lr;
                const short8 k0 = *(const short8*)&Ks[cur][swz(row, lg * 8)];
                const short8 k1 = *(const short8*)&Ks[cur][swz(row, 32 + lg * 8)];
                f32x4 z = { 0.f, 0.f, 0.f, 0.f };
                __builtin_amdgcn_s_setprio(1);
                z = __builtin_amdgcn_mfma_f32_16x16x32_bf16(qfr[hf][0], k0, z, 0, 0, 0);
                z = __builtin_amdgcn_mfma_f32_16x16x32_bf16(qfr[hf][1], k1, z, 0, 0, 0);
                __builtin_amdgcn_s_setprio(0);
                sacc[c] = z;
            }

            // causal mask only on diagonal-overlap tiles (wave-uniform test)
            if (kv0 + 63 > q0w) {
#pragma unroll
                for (int r = 0; r < 4; ++r) {
                    const int rowg = myrow0 + r;
#pragma unroll
                    for (int c = 0; c < 4; ++c)
                        if (kv0 + c * 16 + lr > rowg) sacc[c][r] = -1e30f;
                }
            }

            // online softmax in exp2 domain (Q pre-scaled by 0.125*log2e)
#pragma unroll
            for (int r = 0; r < 4; ++r) {
                float mx = fmaxf(fmaxf(sacc[0][r], sacc[1][r]), fmaxf(sacc[2][r], sacc[3][r]));
#pragma unroll
                for (int d = 1; d < 16; d <<= 1) mx = fmaxf(mx, __shfl_xor(mx, d));
                const float mnew = fmaxf(m_r[r], mx);
                const float al = exp2f(m_r[r] - mnew);
                m_r[r] = mnew;
#pragma unroll
                for (int c = 0; c < 4; ++c) sacc[c][r] = exp2f(sacc[c][r] - mnew);
#pragma unroll
                for (int c2 = 0; c2 < 4; ++c2) oacc[c2][r] *= al;
                lacc[r] *= al;
            }

            // P -> LDS (wave-private), PV + ones-MFMA row-sum
#pragma unroll
            for (int r = 0; r < 4; ++r)
#pragma unroll
                for (int c = 0; c < 4; ++c)
                    Ps[wave][swz(lg * 4 + r, c * 16 + lr)] = f2b(sacc[c][r]);
#pragma unroll
            for (int s2 = 0; s2 < 2; ++s2) {
                const short8 pa = *(const short8*)&Ps[wave][swz(lr, s2 * 32 + lg * 8)];
                __builtin_amdgcn_s_setprio(1);
                lacc = __builtin_amdgcn_mfma_f32_16x16x32_bf16(pa, ones, lacc, 0, 0, 0);
#pragma unroll
                for (int c2 = 0; c2 < 4; ++c2) {
                    const short8 vb = *(const short8*)&Vts[cur][swz(c2 * 16 + lr, s2 * 32 + lg * 8)];
                    oacc[c2] = __builtin_amdgcn_mfma_f32_16x16x32_bf16(pa, vb, oacc[c2], 0, 0, 0);
                }
                __builtin_amdgcn_s_setprio(0);
            }
            __syncthreads();   // drains gloads + LDS; next tile ready
        }

        // epilogue: O rows == this block's Q rows (already in regs) -> safe overwrite
#pragma unroll
        for (int c2 = 0; c2 < 4; ++c2)
#pragma unroll
            for (int r = 0; r < 4; ++r) {
                const float ov = oacc[c2][r] / lacc[r];
                Obh[(size_t)(myrow0 + r) * 1024 + c2 * 16 + lr] = f2b(ov);
            }
    }
}

// ---------------------------------------------------------------------------
// Memory plan (f32 I/O):
//   d_out bytes: [0,16.78M) D0 = Q bf16 -> attnout bf16 (in-place)
//                [16.78,33.55M) D1 = K bf16
//                [33.55,50.33M) xb bf16 (x converted; dead before lnV writes Vf)
//                [33.55,67.1M)  Vf f32 final V output (written by lnV)
//                [0,33.55M)     outF f32 final out (written last)
//   ws (25.2MB): S0 [0,16.78M) = preLN-V bf16 -> Vt bf16 -> gemmP-out bf16
//                weights [16.78,25.17M)
// ---------------------------------------------------------------------------
extern "C" void kernel_launch(void* const* d_in, const int* in_sizes, int n_in,
                              void* d_out, int out_size, void* d_ws, size_t ws_size,
                              hipStream_t stream)
{
    (void)in_sizes; (void)n_in; (void)out_size; (void)ws_size;
    const float* x   = (const float*)d_in[0];
    const float* wq  = (const float*)d_in[1];  const float* bq   = (const float*)d_in[2];
    const float* wk  = (const float*)d_in[3];  const float* bk   = (const float*)d_in[4];
    const float* wv  = (const float*)d_in[5];  const float* bv   = (const float*)d_in[6];
    const float* wp  = (const float*)d_in[7];  const float* bp   = (const float*)d_in[8];
    const float* g_q = (const float*)d_in[9];  const float* be_q = (const float*)d_in[10];
    const float* g_k = (const float*)d_in[11]; const float* be_k = (const float*)d_in[12];
    const float* g_v = (const float*)d_in[13]; const float* be_v = (const float*)d_in[14];
    const float* g_p = (const float*)d_in[15]; const float* be_p = (const float*)d_in[16];

    float* outF = (float*)d_out;
    float* Vf   = outF + 8388608;
    u16* D0 = (u16*)d_out;                  // Q bf16 -> attnout
    u16* D1 = (u16*)d_out + 8388608;        // K bf16
    u16* xb = (u16*)d_out + 16777216;       // x bf16 (in Vf's first half, dead early)
    char* ws = (char*)d_ws;
    u16* S0  = (u16*)ws;                    // preLN-V -> Vt -> gemmP out
    u16* wb  = (u16*)(ws + 16777216);
    u16* wqb = wb;
    u16* wkb = wb + 1048576;
    u16* wvb = wb + 2097152;
    u16* wpb = wb + 3145728;

    const float QSCALE = 0.125f * 1.4426950408889634f;   // 1/sqrt(64) * log2(e)

    const dim3 gg(64, 8), bb(256);
    cvt4_k<<<dim3(1024, 4), bb, 0, stream>>>(wq, wk, wv, wp, wb);
    cvt_k<<<dim3(8192), bb, 0, stream>>>(x, xb);

    gemm_k<<<gg, bb, 0, stream>>>(xb, wqb, bq, D0, 8192, 1024, 1024);
    ln_k<0><<<dim3(8192), bb, 0, stream>>>(D0, g_q, be_q, D0, QSCALE);
    gemm_k<<<gg, bb, 0, stream>>>(xb, wkb, bk, D1, 8192, 1024, 1024);
    ln_k<0><<<dim3(8192), bb, 0, stream>>>(D1, g_k, be_k, D1, 1.0f);
    gemm_k<<<gg, bb, 0, stream>>>(xb, wvb, bv, S0, 8192, 1024, 1024);
    ln_k<1><<<dim3(8192), bb, 0, stream>>>(S0, g_v, be_v, Vf, 1.0f);   // final V f32
    vtr_k<<<dim3(2048), bb, 0, stream>>>(Vf, S0);                      // Vt bf16 over S0
    attn_k<<<dim3(8, 64), dim3(512), 0, stream>>>(D0, D1, S0, D0);     // out over Q
    gemm_k<<<gg, bb, 0, stream>>>(D0, wpb, bp, S0, 8192, 1024, 1024);  // over Vt
    ln_k<2><<<dim3(8192), bb, 0, stream>>>(S0, g_p, be_p, outF, 1.0f);
}

// Round 7
// 257.558 us; speedup vs baseline: 2.2791x; 1.0535x over previous
//
#include <hip/hip_runtime.h>
#include <hip/hip_bf16.h>

// B=4, S=2048, E=1024, H=16, HD=64. d_in/d_out are FLOAT32; compute in bf16 MFMA.
typedef unsigned short u16;
typedef __attribute__((ext_vector_type(8))) short short8;   // 8 bf16 (MFMA A/B frag)
typedef __attribute__((ext_vector_type(4))) float f32x4;    // MFMA C/D frag

__device__ __forceinline__ float b2f(u16 u){
    unsigned v = ((unsigned)u) << 16; float f; __builtin_memcpy(&f, &v, 4); return f;
}
__device__ __forceinline__ u16 f2b(float f){          // RNE
    unsigned v; __builtin_memcpy(&v, &f, 4);
    v += 0x7fffu + ((v >> 16) & 1u);
    return (u16)(v >> 16);
}
__device__ __forceinline__ u16 f2b_fast(float f){     // round-half-up (P path only)
    unsigned v; __builtin_memcpy(&v, &f, 4);
    return (u16)((v + 0x8000u) >> 16);
}

__device__ __forceinline__ void gload16(const void* g, void* l){
    __builtin_amdgcn_global_load_lds((const __attribute__((address_space(1))) unsigned int*)g,
                                     (__attribute__((address_space(3))) unsigned int*)l, 16, 0, 0);
}

// XOR bank swizzle for 64-u16-wide LDS rows (row stride 128B).
__device__ __forceinline__ int swz(int row, int col){
    return row * 64 + (col ^ ((row & 7) << 3));
}

// ---------------------------------------------------------------------------
// f32 -> bf16 converts
// ---------------------------------------------------------------------------
__global__ void cvt_k(const float* __restrict__ src, u16* __restrict__ dst)
{
    const int i = (blockIdx.x * 256 + threadIdx.x) * 4;
    float4 v = *(const float4*)&src[i];
    ushort4 o;
    o.x = f2b(v.x); o.y = f2b(v.y); o.z = f2b(v.z); o.w = f2b(v.w);
    *(ushort4*)&dst[i] = o;
}

__global__ void cvt4_k(const float* __restrict__ s0, const float* __restrict__ s1,
                       const float* __restrict__ s2, const float* __restrict__ s3,
                       u16* __restrict__ dst)   // 4 matrices contiguous
{
    const float* src = (blockIdx.y == 0) ? s0 : (blockIdx.y == 1) ? s1 :
                       (blockIdx.y == 2) ? s2 : s3;
    const int i = (blockIdx.x * 256 + threadIdx.x) * 4;
    float4 v = *(const float4*)&src[i];
    ushort4 o;
    o.x = f2b(v.x); o.y = f2b(v.y); o.z = f2b(v.z); o.w = f2b(v.w);
    *(ushort4*)&dst[(size_t)blockIdx.y * 1048576 + i] = o;
}

// ---------------------------------------------------------------------------
// Fused Q/K/V GEMM: C[m][n] = xb[m][k] @ W_mat[n][k]^T + bias_mat[n]
// grid (64, 24): blockIdx.y -> matrix (y>>3) and n0 ((y&7)*128).
// m97 structure: 128x128 tile, BK=32, 4 waves.
// ---------------------------------------------------------------------------
__global__ __launch_bounds__(256, 2)
void gemm3_k(const u16* __restrict__ A, const u16* __restrict__ Wb,
             const float* __restrict__ b0, const float* __restrict__ b1,
             const float* __restrict__ b2,
             u16* __restrict__ C0, u16* __restrict__ C1, u16* __restrict__ C2)
{
    __shared__ u16 As[128 * 32];
    __shared__ u16 Bs[128 * 32];
    const int K = 1024, N = 1024;
    const int mat = blockIdx.y >> 3;
    const int n0  = (blockIdx.y & 7) * 128;
    const u16* W = Wb + ((size_t)mat << 20);
    const float* bias = (mat == 0) ? b0 : (mat == 1) ? b1 : b2;
    u16* C = (mat == 0) ? C0 : (mat == 1) ? C1 : C2;

    const int tid  = threadIdx.x;
    const int wave = tid >> 6, lane = tid & 63;
    const int lg = lane >> 4, lr = lane & 15;
    const int m0 = blockIdx.x * 128;
    const int wm = (wave >> 1) * 64, wn = (wave & 1) * 64;

    const u16* aG = A + (size_t)(m0 + (tid >> 2)) * K + (tid & 3) * 8;
    const u16* bG = W + (size_t)(n0 + (tid >> 2)) * K + (tid & 3) * 8;
    char* asBase = (char*)As + wave * 1024;
    char* bsBase = (char*)Bs + wave * 1024;
    const size_t rstep = (size_t)64 * K;

    f32x4 acc[4][4] = {};

    for (int kt = 0; kt < K; kt += 32) {
        gload16(aG + kt,         asBase);
        gload16(aG + kt + rstep, asBase + 4096);
        gload16(bG + kt,         bsBase);
        gload16(bG + kt + rstep, bsBase + 4096);
        __syncthreads();

        short8 a[4], b[4];
#pragma unroll
        for (int i = 0; i < 4; ++i) a[i] = *(const short8*)&As[(wm + i*16 + lr)*32 + lg*8];
#pragma unroll
        for (int j = 0; j < 4; ++j) b[j] = *(const short8*)&Bs[(wn + j*16 + lr)*32 + lg*8];
        __builtin_amdgcn_s_setprio(1);
#pragma unroll
        for (int i = 0; i < 4; ++i)
#pragma unroll
            for (int j = 0; j < 4; ++j)
                acc[i][j] = __builtin_amdgcn_mfma_f32_16x16x32_bf16(a[i], b[j], acc[i][j], 0, 0, 0);
        __builtin_amdgcn_s_setprio(0);
        __syncthreads();
    }

#pragma unroll
    for (int j = 0; j < 4; ++j) {
        const int cn = n0 + wn + j*16 + lr;
        const float bv = bias[cn];
#pragma unroll
        for (int i = 0; i < 4; ++i) {
            const int cm = m0 + wm + i*16 + lg*4;
#pragma unroll
            for (int r = 0; r < 4; ++r)
                C[(size_t)(cm + r) * N + cn] = f2b(acc[i][j][r] + bv);
        }
    }
}

// ---------------------------------------------------------------------------
// Single-matrix GEMM (out-projection): bf16 in/out.
// ---------------------------------------------------------------------------
__global__ __launch_bounds__(256, 2)
void gemm_k(const u16* __restrict__ A, const u16* __restrict__ W,
            const float* __restrict__ bias, u16* __restrict__ C,
            int M, int N, int K)
{
    __shared__ u16 As[128 * 32];
    __shared__ u16 Bs[128 * 32];
    const int tid  = threadIdx.x;
    const int wave = tid >> 6, lane = tid & 63;
    const int lg = lane >> 4, lr = lane & 15;
    const int m0 = blockIdx.x * 128, n0 = blockIdx.y * 128;
    const int wm = (wave >> 1) * 64, wn = (wave & 1) * 64;

    const u16* aG = A + (size_t)(m0 + (tid >> 2)) * K + (tid & 3) * 8;
    const u16* bG = W + (size_t)(n0 + (tid >> 2)) * K + (tid & 3) * 8;
    char* asBase = (char*)As + wave * 1024;
    char* bsBase = (char*)Bs + wave * 1024;
    const size_t rstep = (size_t)64 * K;

    f32x4 acc[4][4] = {};

    for (int kt = 0; kt < K; kt += 32) {
        gload16(aG + kt,         asBase);
        gload16(aG + kt + rstep, asBase + 4096);
        gload16(bG + kt,         bsBase);
        gload16(bG + kt + rstep, bsBase + 4096);
        __syncthreads();

        short8 a[4], b[4];
#pragma unroll
        for (int i = 0; i < 4; ++i) a[i] = *(const short8*)&As[(wm + i*16 + lr)*32 + lg*8];
#pragma unroll
        for (int j = 0; j < 4; ++j) b[j] = *(const short8*)&Bs[(wn + j*16 + lr)*32 + lg*8];
        __builtin_amdgcn_s_setprio(1);
#pragma unroll
        for (int i = 0; i < 4; ++i)
#pragma unroll
            for (int j = 0; j < 4; ++j)
                acc[i][j] = __builtin_amdgcn_mfma_f32_16x16x32_bf16(a[i], b[j], acc[i][j], 0, 0, 0);
        __builtin_amdgcn_s_setprio(0);
        __syncthreads();
    }

#pragma unroll
    for (int j = 0; j < 4; ++j) {
        const int cn = n0 + wn + j*16 + lr;
        const float bv = bias[cn];
#pragma unroll
        for (int i = 0; i < 4; ++i) {
            const int cm = m0 + wm + i*16 + lg*4;
#pragma unroll
            for (int r = 0; r < 4; ++r)
                C[(size_t)(cm + r) * N + cn] = f2b(acc[i][j][r] + bv);
        }
    }
}

// ---------------------------------------------------------------------------
// Fused Q/K/V LayerNorm. grid (8192, 3): y=0 Q (bf16 in-place, pre-scaled),
// y=1 K (bf16 in-place), y=2 V (f32 head-layout scatter).
// ---------------------------------------------------------------------------
__global__ void ln3_k(u16* D0, u16* D1, const u16* __restrict__ Sv,
                      const float* __restrict__ g_q, const float* __restrict__ be_q,
                      const float* __restrict__ g_k, const float* __restrict__ be_k,
                      const float* __restrict__ g_v, const float* __restrict__ be_v,
                      float* __restrict__ Vf)
{
    __shared__ float red[8];
    const int which = blockIdx.y;
    const u16* src = (which == 0) ? D0 : (which == 1) ? D1 : Sv;
    const float* g  = (which == 0) ? g_q  : (which == 1) ? g_k  : g_v;
    const float* be = (which == 0) ? be_q : (which == 1) ? be_k : be_v;
    const float scale = (which == 0) ? 0.125f * 1.4426950408889634f : 1.0f;

    const int row = blockIdx.x;
    const int tid = threadIdx.x;
    const int lane = tid & 63, wave = tid >> 6;
    ushort4 v = *(const ushort4*)&src[(size_t)row * 1024 + tid * 4];
    float f[4] = { b2f(v.x), b2f(v.y), b2f(v.z), b2f(v.w) };
    float s  = f[0] + f[1] + f[2] + f[3];
    float ss = f[0]*f[0] + f[1]*f[1] + f[2]*f[2] + f[3]*f[3];
#pragma unroll
    for (int off = 32; off; off >>= 1) { s += __shfl_down(s, off); ss += __shfl_down(ss, off); }
    if (lane == 0) { red[wave] = s; red[4 + wave] = ss; }
    __syncthreads();
    s  = red[0] + red[1] + red[2] + red[3];
    ss = red[4] + red[5] + red[6] + red[7];
    const float mean = s * (1.0f / 1024.0f);
    const float var  = fmaxf(ss * (1.0f / 1024.0f) - mean * mean, 0.0f);
    const float rs   = rsqrtf(var + 1e-5f);
    float o[4];
#pragma unroll
    for (int k = 0; k < 4; ++k) {
        const int e = tid * 4 + k;
        o[k] = ((f[k] - mean) * rs * g[e] + be[e]) * scale;
    }
    if (which == 2) {
        const int b = row >> 11, sIdx = row & 2047;
        const int h = tid >> 4, hd = (tid * 4) & 63;
        float4 ov = { o[0], o[1], o[2], o[3] };
        *(float4*)&Vf[(((size_t)(b * 16 + h) * 2048 + sIdx) << 6) + hd] = ov;
    } else {
        u16* dst = (which == 0) ? D0 : D1;
        ushort4 ov; ov.x = f2b(o[0]); ov.y = f2b(o[1]); ov.z = f2b(o[2]); ov.w = f2b(o[3]);
        *(ushort4*)&dst[(size_t)row * 1024 + tid * 4] = ov;
    }
}

// ---------------------------------------------------------------------------
// Final LayerNorm: bf16 src -> f32 flat dst.
// ---------------------------------------------------------------------------
__global__ void lnf_k(const u16* __restrict__ src, const float* __restrict__ g,
                      const float* __restrict__ be, float* __restrict__ dst)
{
    __shared__ float red[8];
    const int row = blockIdx.x;
    const int tid = threadIdx.x;
    const int lane = tid & 63, wave = tid >> 6;
    ushort4 v = *(const ushort4*)&src[(size_t)row * 1024 + tid * 4];
    float f[4] = { b2f(v.x), b2f(v.y), b2f(v.z), b2f(v.w) };
    float s  = f[0] + f[1] + f[2] + f[3];
    float ss = f[0]*f[0] + f[1]*f[1] + f[2]*f[2] + f[3]*f[3];
#pragma unroll
    for (int off = 32; off; off >>= 1) { s += __shfl_down(s, off); ss += __shfl_down(ss, off); }
    if (lane == 0) { red[wave] = s; red[4 + wave] = ss; }
    __syncthreads();
    s  = red[0] + red[1] + red[2] + red[3];
    ss = red[4] + red[5] + red[6] + red[7];
    const float mean = s * (1.0f / 1024.0f);
    const float var  = fmaxf(ss * (1.0f / 1024.0f) - mean * mean, 0.0f);
    const float rs   = rsqrtf(var + 1e-5f);
    float4 ov;
    ov.x = (f[0] - mean) * rs * g[tid*4+0] + be[tid*4+0];
    ov.y = (f[1] - mean) * rs * g[tid*4+1] + be[tid*4+1];
    ov.z = (f[2] - mean) * rs * g[tid*4+2] + be[tid*4+2];
    ov.w = (f[3] - mean) * rs * g[tid*4+3] + be[tid*4+3];
    *(float4*)&dst[(size_t)row * 1024 + tid * 4] = ov;
}

// ---------------------------------------------------------------------------
// V transpose: Vf f32 [bh][s][64] -> Vt bf16 [bh][64(hd)][2048(s)].
// ---------------------------------------------------------------------------
__global__ void vtr_k(const float* __restrict__ Vf, u16* __restrict__ Vt)
{
    __shared__ float T[64 * 65];
    const int bh = blockIdx.x >> 5, st = blockIdx.x & 31;
    const int tid = threadIdx.x;
    const float* src = Vf + (size_t)bh * 2048 * 64 + (size_t)st * 64 * 64;
#pragma unroll
    for (int it = 0; it < 4; ++it) {
        const int fid = tid + it * 256;
        const int r = fid >> 4, c4 = fid & 15;
        float4 v = *(const float4*)&src[r * 64 + c4 * 4];
        T[r * 65 + c4*4 + 0] = v.x;
        T[r * 65 + c4*4 + 1] = v.y;
        T[r * 65 + c4*4 + 2] = v.z;
        T[r * 65 + c4*4 + 3] = v.w;
    }
    __syncthreads();
    u16* dst = Vt + (size_t)bh * 64 * 2048 + (size_t)st * 64;
#pragma unroll
    for (int it = 0; it < 2; ++it) {
        const int oid = tid + it * 256;
        const int hd = oid >> 3, ch = oid & 7;
        u16 tmp[8];
#pragma unroll
        for (int j = 0; j < 8; ++j) tmp[j] = f2b(T[(ch * 8 + j) * 65 + hd]);
        *(uint4*)&dst[(size_t)hd * 2048 + ch * 8] = *(uint4*)tmp;
    }
}

// ---------------------------------------------------------------------------
// Causal flash attention. QBLK=64 (4 waves x 16 rows), KVBLK=64 dbuf,
// paired q-tiles {x, 31-x} -> 33 kv-iters/block. grid (16,64) = 1024 blocks
// = 4/CU (LDS 40KB = 4/CU). Defer-max (THR=8, exp2 domain). Output in-place
// over Q. XCD remap groups the 16 blocks of one bh per XCD.
// ---------------------------------------------------------------------------
__global__ __launch_bounds__(256, 4)
void attn_k(const u16* __restrict__ Qf, const u16* __restrict__ Kf,
            const u16* __restrict__ Vt, u16* __restrict__ O)
{
    __shared__ u16 Ks [2][64 * 64];   // 16 KB
    __shared__ u16 Vts[2][64 * 64];   // 16 KB
    __shared__ u16 Ps [4][16 * 64];   // 8 KB
    const int lin = (int)blockIdx.x + (int)blockIdx.y * 16;
    const int xcd = lin & 7, idx = lin >> 3;
    const int bh  = xcd * 8 + (idx & 7);
    const int xb_ = idx >> 3;                 // 0..15
    const int b = bh >> 4, h = bh & 15;
    const int tid = threadIdx.x, wave = tid >> 6, lane = tid & 63;
    const int lg = lane >> 4, lr = lane & 15;
    const u16* Qbh = Qf + ((size_t)b * 2048) * 1024 + h * 64;
    const u16* Kbh = Kf + ((size_t)b * 2048) * 1024 + h * 64;
    const u16* Vbh = Vt + (size_t)bh * 64 * 2048;     // [hd][s]
    u16* Obh = O + ((size_t)b * 2048) * 1024 + h * 64;

    const short s1 = (short)0x3F80;
    const short8 ones = { s1,s1,s1,s1,s1,s1,s1,s1 };

    // preload Q frags for BOTH halves (output overwrites exactly these rows)
    const int qts[2] = { xb_, 31 - xb_ };
    short8 qfr[2][2];
#pragma unroll
    for (int hf = 0; hf < 2; ++hf) {
        const int qrow = qts[hf] * 64 + wave * 16 + lr;
        qfr[hf][0] = *(const short8*)&Qbh[(size_t)qrow * 1024 + lg * 8];
        qfr[hf][1] = *(const short8*)&Qbh[(size_t)qrow * 1024 + 32 + lg * 8];
    }

    for (int hf = 0; hf < 2; ++hf) {
        const int qt = qts[hf];
        const int myrow0 = qt * 64 + wave * 16 + lg * 4;
        const int nkv = qt + 1;

        f32x4 oacc[4] = {};
        f32x4 lacc = { 0.f, 0.f, 0.f, 0.f };
        float m_r[4] = { -1e30f, -1e30f, -1e30f, -1e30f };

        // prologue: stage kv tile 0 into buf 0 (2 issues x 4KB each for K and V)
#pragma unroll
        for (int it = 0; it < 2; ++it) {
            const int id = tid + it * 256;
            const int r = id >> 3, c = (id & 7) ^ (r & 7);
            gload16(Kbh + (size_t)r * 1024 + c * 8, (char*)Ks[0]  + it * 4096 + wave * 1024);
            gload16(Vbh + (size_t)r * 2048 + c * 8, (char*)Vts[0] + it * 4096 + wave * 1024);
        }
        __syncthreads();

        for (int kv = 0; kv < nkv; ++kv) {
            const int cur = kv & 1, nxt = cur ^ 1;
            const int kv0 = kv * 64;
            if (kv + 1 < nkv) {
                const int kvn = kv0 + 64;
#pragma unroll
                for (int it = 0; it < 2; ++it) {
                    const int id = tid + it * 256;
                    const int r = id >> 3, c = (id & 7) ^ (r & 7);
                    gload16(Kbh + (size_t)(kvn + r) * 1024 + c * 8, (char*)Ks[nxt]  + it * 4096 + wave * 1024);
                    gload16(Vbh + (size_t)r * 2048 + kvn + c * 8,   (char*)Vts[nxt] + it * 4096 + wave * 1024);
                }
            }

            // QK^T (16x64 per wave)
            f32x4 sacc[4];
#pragma unroll
            for (int c = 0; c < 4; ++c) {
                const int row = c * 16 + lr;
                const short8 k0 = *(const short8*)&Ks[cur][swz(row, lg * 8)];
                const short8 k1 = *(const short8*)&Ks[cur][swz(row, 32 + lg * 8)];
                f32x4 z = { 0.f, 0.f, 0.f, 0.f };
                __builtin_amdgcn_s_setprio(1);
                z = __builtin_amdgcn_mfma_f32_16x16x32_bf16(qfr[hf][0], k0, z, 0, 0, 0);
                z = __builtin_amdgcn_mfma_f32_16x16x32_bf16(qfr[hf][1], k1, z, 0, 0, 0);
                __builtin_amdgcn_s_setprio(0);
                sacc[c] = z;
            }

            // causal mask only on the diagonal tile (block-uniform test)
            if (kv == nkv - 1) {
#pragma unroll
                for (int r = 0; r < 4; ++r) {
                    const int rowg = myrow0 + r;
#pragma unroll
                    for (int c = 0; c < 4; ++c)
                        if (kv0 + c * 16 + lr > rowg) sacc[c][r] = -1e30f;
                }
            }

            // online softmax, exp2 domain, defer-max (THR=8)
#pragma unroll
            for (int r = 0; r < 4; ++r) {
                float mx = fmaxf(fmaxf(sacc[0][r], sacc[1][r]), fmaxf(sacc[2][r], sacc[3][r]));
#pragma unroll
                for (int d = 1; d < 16; d <<= 1) mx = fmaxf(mx, __shfl_xor(mx, d));
                const float df = mx - m_r[r];
                if (df > 8.0f) {                      // rescale only on real growth
                    const float al = exp2f(-df);
                    m_r[r] = mx;
                    lacc[r] *= al;
#pragma unroll
                    for (int c2 = 0; c2 < 4; ++c2) oacc[c2][r] *= al;
                }
#pragma unroll
                for (int c = 0; c < 4; ++c) sacc[c][r] = exp2f(sacc[c][r] - m_r[r]);
            }

            // P -> LDS (wave-private), PV + ones-MFMA row-sum
#pragma unroll
            for (int r = 0; r < 4; ++r)
#pragma unroll
                for (int c = 0; c < 4; ++c)
                    Ps[wave][swz(lg * 4 + r, c * 16 + lr)] = f2b_fast(sacc[c][r]);
#pragma unroll
            for (int s2 = 0; s2 < 2; ++s2) {
                const short8 pa = *(const short8*)&Ps[wave][swz(lr, s2 * 32 + lg * 8)];
                __builtin_amdgcn_s_setprio(1);
                lacc = __builtin_amdgcn_mfma_f32_16x16x32_bf16(pa, ones, lacc, 0, 0, 0);
#pragma unroll
                for (int c2 = 0; c2 < 4; ++c2) {
                    const short8 vb = *(const short8*)&Vts[cur][swz(c2 * 16 + lr, s2 * 32 + lg * 8)];
                    oacc[c2] = __builtin_amdgcn_mfma_f32_16x16x32_bf16(pa, vb, oacc[c2], 0, 0, 0);
                }
                __builtin_amdgcn_s_setprio(0);
            }
            __syncthreads();
        }

        // epilogue: rows == this block's preloaded Q rows -> safe in-place write
#pragma unroll
        for (int c2 = 0; c2 < 4; ++c2)
#pragma unroll
            for (int r = 0; r < 4; ++r) {
                const float ov = oacc[c2][r] / lacc[r];
                Obh[(size_t)(myrow0 + r) * 1024 + c2 * 16 + lr] = f2b(ov);
            }
    }
}

// ---------------------------------------------------------------------------
// Memory plan (f32 I/O):
//   d_out bytes: [0,16.78M) D0 = Q bf16 -> attnout bf16 (in-place)
//                [16.78,33.55M) D1 = K bf16
//                [33.55,50.33M) xb bf16 (dead before lnV writes Vf)
//                [33.55,67.1M)  Vf f32 final V output
//                [0,33.55M)     outF f32 final out (written last)
//   ws (25.2MB): S0 = preLN-V bf16 -> Vt bf16 -> gemmP-out bf16; weights after.
// ---------------------------------------------------------------------------
extern "C" void kernel_launch(void* const* d_in, const int* in_sizes, int n_in,
                              void* d_out, int out_size, void* d_ws, size_t ws_size,
                              hipStream_t stream)
{
    (void)in_sizes; (void)n_in; (void)out_size; (void)ws_size;
    const float* x   = (const float*)d_in[0];
    const float* wq  = (const float*)d_in[1];  const float* bq   = (const float*)d_in[2];
    const float* wk  = (const float*)d_in[3];  const float* bk   = (const float*)d_in[4];
    const float* wv  = (const float*)d_in[5];  const float* bv   = (const float*)d_in[6];
    const float* wp  = (const float*)d_in[7];  const float* bp   = (const float*)d_in[8];
    const float* g_q = (const float*)d_in[9];  const float* be_q = (const float*)d_in[10];
    const float* g_k = (const float*)d_in[11]; const float* be_k = (const float*)d_in[12];
    const float* g_v = (const float*)d_in[13]; const float* be_v = (const float*)d_in[14];
    const float* g_p = (const float*)d_in[15]; const float* be_p = (const float*)d_in[16];

    float* outF = (float*)d_out;
    float* Vf   = outF + 8388608;
    u16* D0 = (u16*)d_out;                  // Q bf16 -> attnout
    u16* D1 = (u16*)d_out + 8388608;        // K bf16
    u16* xb = (u16*)d_out + 16777216;       // x bf16 (dead before Vf written)
    char* ws = (char*)d_ws;
    u16* S0  = (u16*)ws;                    // preLN-V -> Vt -> gemmP out
    u16* wb  = (u16*)(ws + 16777216);       // 4 bf16 weight matrices contiguous
    u16* wpb = wb + 3145728;

    const dim3 bb(256);
    cvt4_k<<<dim3(1024, 4), bb, 0, stream>>>(wq, wk, wv, wp, wb);
    cvt_k<<<dim3(8192), bb, 0, stream>>>(x, xb);

    gemm3_k<<<dim3(64, 24), bb, 0, stream>>>(xb, wb, bq, bk, bv, D0, D1, S0);
    ln3_k<<<dim3(8192, 3), bb, 0, stream>>>(D0, D1, S0, g_q, be_q, g_k, be_k, g_v, be_v, Vf);
    vtr_k<<<dim3(2048), bb, 0, stream>>>(Vf, S0);                      // Vt over S0
    attn_k<<<dim3(16, 64), bb, 0, stream>>>(D0, D1, S0, D0);           // out over Q
    gemm_k<<<dim3(64, 8), bb, 0, stream>>>(D0, wpb, bp, S0, 8192, 1024, 1024);
    lnf_k<<<dim3(8192), bb, 0, stream>>>(S0, g_p, be_p, outF);
}

// Round 8
// 214.902 us; speedup vs baseline: 2.7314x; 1.1985x over previous
//
#include <hip/hip_runtime.h>
#include <hip/hip_bf16.h>

// B=4, S=2048, E=1024, H=16, HD=64. d_in/d_out are FLOAT32; compute in bf16 MFMA.
typedef unsigned short u16;
typedef __attribute__((ext_vector_type(8))) short short8;   // 8 bf16 (MFMA A/B frag)
typedef __attribute__((ext_vector_type(4))) float f32x4;    // MFMA C/D frag

__device__ __forceinline__ float b2f(u16 u){
    unsigned v = ((unsigned)u) << 16; float f; __builtin_memcpy(&f, &v, 4); return f;
}
__device__ __forceinline__ u16 f2b(float f){          // RNE
    unsigned v; __builtin_memcpy(&v, &f, 4);
    v += 0x7fffu + ((v >> 16) & 1u);
    return (u16)(v >> 16);
}
__device__ __forceinline__ u16 f2b_fast(float f){     // round-half-up (P path only)
    unsigned v; __builtin_memcpy(&v, &f, 4);
    return (u16)((v + 0x8000u) >> 16);
}

__device__ __forceinline__ void gload16(const void* g, void* l){
    __builtin_amdgcn_global_load_lds((const __attribute__((address_space(1))) unsigned int*)g,
                                     (__attribute__((address_space(3))) unsigned int*)l, 16, 0, 0);
}

// XOR bank swizzle for 64-u16-wide LDS rows (row stride 128B).
__device__ __forceinline__ int swz(int row, int col){
    return row * 64 + (col ^ ((row & 7) << 3));
}

// ---------------------------------------------------------------------------
// f32 -> bf16 converts
// ---------------------------------------------------------------------------
__global__ void cvt_k(const float* __restrict__ src, u16* __restrict__ dst)
{
    const int i = (blockIdx.x * 256 + threadIdx.x) * 4;
    float4 v = *(const float4*)&src[i];
    ushort4 o;
    o.x = f2b(v.x); o.y = f2b(v.y); o.z = f2b(v.z); o.w = f2b(v.w);
    *(ushort4*)&dst[i] = o;
}

__global__ void cvt4_k(const float* __restrict__ s0, const float* __restrict__ s1,
                       const float* __restrict__ s2, const float* __restrict__ s3,
                       u16* __restrict__ dst)   // 4 matrices contiguous
{
    const float* src = (blockIdx.y == 0) ? s0 : (blockIdx.y == 1) ? s1 :
                       (blockIdx.y == 2) ? s2 : s3;
    const int i = (blockIdx.x * 256 + threadIdx.x) * 4;
    float4 v = *(const float4*)&src[i];
    ushort4 o;
    o.x = f2b(v.x); o.y = f2b(v.y); o.z = f2b(v.z); o.w = f2b(v.w);
    *(ushort4*)&dst[(size_t)blockIdx.y * 1048576 + i] = o;
}

// ---------------------------------------------------------------------------
// Fused Q/K/V GEMM: C[m][n] = xb[m][k] @ W_mat[n][k]^T + bias_mat[n]
// ---------------------------------------------------------------------------
__global__ __launch_bounds__(256, 2)
void gemm3_k(const u16* __restrict__ A, const u16* __restrict__ Wb,
             const float* __restrict__ b0, const float* __restrict__ b1,
             const float* __restrict__ b2,
             u16* __restrict__ C0, u16* __restrict__ C1, u16* __restrict__ C2)
{
    __shared__ u16 As[128 * 32];
    __shared__ u16 Bs[128 * 32];
    const int K = 1024, N = 1024;
    const int mat = blockIdx.y >> 3;
    const int n0  = (blockIdx.y & 7) * 128;
    const u16* W = Wb + ((size_t)mat << 20);
    const float* bias = (mat == 0) ? b0 : (mat == 1) ? b1 : b2;
    u16* C = (mat == 0) ? C0 : (mat == 1) ? C1 : C2;

    const int tid  = threadIdx.x;
    const int wave = tid >> 6, lane = tid & 63;
    const int lg = lane >> 4, lr = lane & 15;
    const int m0 = blockIdx.x * 128;
    const int wm = (wave >> 1) * 64, wn = (wave & 1) * 64;

    const u16* aG = A + (size_t)(m0 + (tid >> 2)) * K + (tid & 3) * 8;
    const u16* bG = W + (size_t)(n0 + (tid >> 2)) * K + (tid & 3) * 8;
    char* asBase = (char*)As + wave * 1024;
    char* bsBase = (char*)Bs + wave * 1024;
    const size_t rstep = (size_t)64 * K;

    f32x4 acc[4][4] = {};

    for (int kt = 0; kt < K; kt += 32) {
        gload16(aG + kt,         asBase);
        gload16(aG + kt + rstep, asBase + 4096);
        gload16(bG + kt,         bsBase);
        gload16(bG + kt + rstep, bsBase + 4096);
        __syncthreads();

        short8 a[4], b[4];
#pragma unroll
        for (int i = 0; i < 4; ++i) a[i] = *(const short8*)&As[(wm + i*16 + lr)*32 + lg*8];
#pragma unroll
        for (int j = 0; j < 4; ++j) b[j] = *(const short8*)&Bs[(wn + j*16 + lr)*32 + lg*8];
        __builtin_amdgcn_s_setprio(1);
#pragma unroll
        for (int i = 0; i < 4; ++i)
#pragma unroll
            for (int j = 0; j < 4; ++j)
                acc[i][j] = __builtin_amdgcn_mfma_f32_16x16x32_bf16(a[i], b[j], acc[i][j], 0, 0, 0);
        __builtin_amdgcn_s_setprio(0);
        __syncthreads();
    }

#pragma unroll
    for (int j = 0; j < 4; ++j) {
        const int cn = n0 + wn + j*16 + lr;
        const float bv = bias[cn];
#pragma unroll
        for (int i = 0; i < 4; ++i) {
            const int cm = m0 + wm + i*16 + lg*4;
#pragma unroll
            for (int r = 0; r < 4; ++r)
                C[(size_t)(cm + r) * N + cn] = f2b(acc[i][j][r] + bv);
        }
    }
}

// ---------------------------------------------------------------------------
// Single-matrix GEMM (out-projection).
// ---------------------------------------------------------------------------
__global__ __launch_bounds__(256, 2)
void gemm_k(const u16* __restrict__ A, const u16* __restrict__ W,
            const float* __restrict__ bias, u16* __restrict__ C,
            int M, int N, int K)
{
    __shared__ u16 As[128 * 32];
    __shared__ u16 Bs[128 * 32];
    const int tid  = threadIdx.x;
    const int wave = tid >> 6, lane = tid & 63;
    const int lg = lane >> 4, lr = lane & 15;
    const int m0 = blockIdx.x * 128, n0 = blockIdx.y * 128;
    const int wm = (wave >> 1) * 64, wn = (wave & 1) * 64;

    const u16* aG = A + (size_t)(m0 + (tid >> 2)) * K + (tid & 3) * 8;
    const u16* bG = W + (size_t)(n0 + (tid >> 2)) * K + (tid & 3) * 8;
    char* asBase = (char*)As + wave * 1024;
    char* bsBase = (char*)Bs + wave * 1024;
    const size_t rstep = (size_t)64 * K;

    f32x4 acc[4][4] = {};

    for (int kt = 0; kt < K; kt += 32) {
        gload16(aG + kt,         asBase);
        gload16(aG + kt + rstep, asBase + 4096);
        gload16(bG + kt,         bsBase);
        gload16(bG + kt + rstep, bsBase + 4096);
        __syncthreads();

        short8 a[4], b[4];
#pragma unroll
        for (int i = 0; i < 4; ++i) a[i] = *(const short8*)&As[(wm + i*16 + lr)*32 + lg*8];
#pragma unroll
        for (int j = 0; j < 4; ++j) b[j] = *(const short8*)&Bs[(wn + j*16 + lr)*32 + lg*8];
        __builtin_amdgcn_s_setprio(1);
#pragma unroll
        for (int i = 0; i < 4; ++i)
#pragma unroll
            for (int j = 0; j < 4; ++j)
                acc[i][j] = __builtin_amdgcn_mfma_f32_16x16x32_bf16(a[i], b[j], acc[i][j], 0, 0, 0);
        __builtin_amdgcn_s_setprio(0);
        __syncthreads();
    }

#pragma unroll
    for (int j = 0; j < 4; ++j) {
        const int cn = n0 + wn + j*16 + lr;
        const float bv = bias[cn];
#pragma unroll
        for (int i = 0; i < 4; ++i) {
            const int cm = m0 + wm + i*16 + lg*4;
#pragma unroll
            for (int r = 0; r < 4; ++r)
                C[(size_t)(cm + r) * N + cn] = f2b(acc[i][j][r] + bv);
        }
    }
}

// ---------------------------------------------------------------------------
// Fused Q/K/V LayerNorm. grid (8192, 3).
// ---------------------------------------------------------------------------
__global__ void ln3_k(u16* D0, u16* D1, const u16* __restrict__ Sv,
                      const float* __restrict__ g_q, const float* __restrict__ be_q,
                      const float* __restrict__ g_k, const float* __restrict__ be_k,
                      const float* __restrict__ g_v, const float* __restrict__ be_v,
                      float* __restrict__ Vf)
{
    __shared__ float red[8];
    const int which = blockIdx.y;
    const u16* src = (which == 0) ? D0 : (which == 1) ? D1 : Sv;
    const float* g  = (which == 0) ? g_q  : (which == 1) ? g_k  : g_v;
    const float* be = (which == 0) ? be_q : (which == 1) ? be_k : be_v;
    const float scale = (which == 0) ? 0.125f * 1.4426950408889634f : 1.0f;

    const int row = blockIdx.x;
    const int tid = threadIdx.x;
    const int lane = tid & 63, wave = tid >> 6;
    ushort4 v = *(const ushort4*)&src[(size_t)row * 1024 + tid * 4];
    float f[4] = { b2f(v.x), b2f(v.y), b2f(v.z), b2f(v.w) };
    float s  = f[0] + f[1] + f[2] + f[3];
    float ss = f[0]*f[0] + f[1]*f[1] + f[2]*f[2] + f[3]*f[3];
#pragma unroll
    for (int off = 32; off; off >>= 1) { s += __shfl_down(s, off); ss += __shfl_down(ss, off); }
    if (lane == 0) { red[wave] = s; red[4 + wave] = ss; }
    __syncthreads();
    s  = red[0] + red[1] + red[2] + red[3];
    ss = red[4] + red[5] + red[6] + red[7];
    const float mean = s * (1.0f / 1024.0f);
    const float var  = fmaxf(ss * (1.0f / 1024.0f) - mean * mean, 0.0f);
    const float rs   = rsqrtf(var + 1e-5f);
    float o[4];
#pragma unroll
    for (int k = 0; k < 4; ++k) {
        const int e = tid * 4 + k;
        o[k] = ((f[k] - mean) * rs * g[e] + be[e]) * scale;
    }
    if (which == 2) {
        const int b = row >> 11, sIdx = row & 2047;
        const int h = tid >> 4, hd = (tid * 4) & 63;
        float4 ov = { o[0], o[1], o[2], o[3] };
        *(float4*)&Vf[(((size_t)(b * 16 + h) * 2048 + sIdx) << 6) + hd] = ov;
    } else {
        u16* dst = (which == 0) ? D0 : D1;
        ushort4 ov; ov.x = f2b(o[0]); ov.y = f2b(o[1]); ov.z = f2b(o[2]); ov.w = f2b(o[3]);
        *(ushort4*)&dst[(size_t)row * 1024 + tid * 4] = ov;
    }
}

// ---------------------------------------------------------------------------
// Final LayerNorm: bf16 src -> f32 flat dst.
// ---------------------------------------------------------------------------
__global__ void lnf_k(const u16* __restrict__ src, const float* __restrict__ g,
                      const float* __restrict__ be, float* __restrict__ dst)
{
    __shared__ float red[8];
    const int row = blockIdx.x;
    const int tid = threadIdx.x;
    const int lane = tid & 63, wave = tid >> 6;
    ushort4 v = *(const ushort4*)&src[(size_t)row * 1024 + tid * 4];
    float f[4] = { b2f(v.x), b2f(v.y), b2f(v.z), b2f(v.w) };
    float s  = f[0] + f[1] + f[2] + f[3];
    float ss = f[0]*f[0] + f[1]*f[1] + f[2]*f[2] + f[3]*f[3];
#pragma unroll
    for (int off = 32; off; off >>= 1) { s += __shfl_down(s, off); ss += __shfl_down(ss, off); }
    if (lane == 0) { red[wave] = s; red[4 + wave] = ss; }
    __syncthreads();
    s  = red[0] + red[1] + red[2] + red[3];
    ss = red[4] + red[5] + red[6] + red[7];
    const float mean = s * (1.0f / 1024.0f);
    const float var  = fmaxf(ss * (1.0f / 1024.0f) - mean * mean, 0.0f);
    const float rs   = rsqrtf(var + 1e-5f);
    float4 ov;
    ov.x = (f[0] - mean) * rs * g[tid*4+0] + be[tid*4+0];
    ov.y = (f[1] - mean) * rs * g[tid*4+1] + be[tid*4+1];
    ov.z = (f[2] - mean) * rs * g[tid*4+2] + be[tid*4+2];
    ov.w = (f[3] - mean) * rs * g[tid*4+3] + be[tid*4+3];
    *(float4*)&dst[(size_t)row * 1024 + tid * 4] = ov;
}

// ---------------------------------------------------------------------------
// V transpose + PV-slot permutation:
// Vf f32 [bh][s][64] -> Vt bf16 [bh][64(hd)][2048(s-permuted)].
// Within each 32-kv block, kv = 16a+4b+c is stored at slot 8b+4a+c so the
// attention kernel's in-register P (swapped-QK layout) matches the B-frag
// slot order with a plain b128 read. Bijective per 32-block.
// ---------------------------------------------------------------------------
__global__ void vtr_k(const float* __restrict__ Vf, u16* __restrict__ Vt)
{
    __shared__ float T[64 * 65];
    const int bh = blockIdx.x >> 5, st = blockIdx.x & 31;
    const int tid = threadIdx.x;
    const float* src = Vf + (size_t)bh * 2048 * 64 + (size_t)st * 64 * 64;
#pragma unroll
    for (int it = 0; it < 4; ++it) {
        const int fid = tid + it * 256;
        const int r = fid >> 4, c4 = fid & 15;
        float4 v = *(const float4*)&src[r * 64 + c4 * 4];
        T[r * 65 + c4*4 + 0] = v.x;
        T[r * 65 + c4*4 + 1] = v.y;
        T[r * 65 + c4*4 + 2] = v.z;
        T[r * 65 + c4*4 + 3] = v.w;
    }
    __syncthreads();
    u16* dst = Vt + (size_t)bh * 64 * 2048 + (size_t)st * 64;
#pragma unroll
    for (int it = 0; it < 2; ++it) {
        const int oid = tid + it * 256;
        const int hd = oid >> 3, ch = oid & 7;     // ch: source kv chunk of 8
        u16 tmp[8];
#pragma unroll
        for (int j = 0; j < 8; ++j) tmp[j] = f2b(T[(ch * 8 + j) * 65 + hd]);
        // permuted destinations (two ushort4 groups)
        const int base = 32 * (ch >> 2) + 4 * ((ch >> 1) & 1);
        const int p0 = base + 8 * ((2 * ch + 0) & 3);
        const int p1 = base + 8 * ((2 * ch + 1) & 3);
        ushort4 lo = { tmp[0], tmp[1], tmp[2], tmp[3] };
        ushort4 hi = { tmp[4], tmp[5], tmp[6], tmp[7] };
        *(ushort4*)&dst[(size_t)hd * 2048 + p0] = lo;
        *(ushort4*)&dst[(size_t)hd * 2048 + p1] = hi;
    }
}

// ---------------------------------------------------------------------------
// Causal flash attention, swapped-QK / in-register-P design.
// QBLK=128 (8 waves x 16 q-rows), KVBLK=64 double-buffered, grid (16,64)
// unpaired (1024 blocks), big q-tiles dispatched first. LDS 32 KB.
// sacc from mfma(K,Q): q = lane&15, kv = kv0 + c*16 + 4*(lane>>4) + r.
// Softmax per-lane (in-register tree + 2 shfl_xor); P stays in registers and
// feeds PV directly (V^T pre-permuted by vtr_k). Defer-max THR=8 (exp2 dom).
// ---------------------------------------------------------------------------
__global__ __launch_bounds__(512, 4)
void attn_k(const u16* __restrict__ Qf, const u16* __restrict__ Kf,
            const u16* __restrict__ Vt, u16* __restrict__ O)
{
    __shared__ u16 Ks [2][64 * 64];   // [buf][kv][hd] swizzled, 16 KB
    __shared__ u16 Vts[2][64 * 64];   // [buf][hd][kv-permuted] swizzled, 16 KB
    const int lin = (int)blockIdx.x + (int)blockIdx.y * 16;
    const int xcd = lin & 7, idx = lin >> 3;
    const int bh  = xcd * 8 + (idx & 7);
    const int qt  = 15 - (idx >> 3);          // big tiles dispatch first
    const int b = bh >> 4, h = bh & 15;
    const int tid = threadIdx.x, wave = tid >> 6, lane = tid & 63;
    const int lg = lane >> 4, lr = lane & 15;
    const u16* Qbh = Qf + ((size_t)b * 2048) * 1024 + h * 64;
    const u16* Kbh = Kf + ((size_t)b * 2048) * 1024 + h * 64;
    const u16* Vbh = Vt + (size_t)bh * 64 * 2048;     // [hd][s-perm]
    u16* Obh = O + ((size_t)b * 2048) * 1024 + h * 64;

    const int q0w  = qt * 128 + wave * 16;    // wave's first q row
    const int qrow = q0w + lr;                // this lane's q (softmax axis)
    // Q as B-operand frags (col=lane&15 -> q, k-slots = hd 8*lg..+7)
    const short8 qf0 = *(const short8*)&Qbh[(size_t)qrow * 1024 + lg * 8];
    const short8 qf1 = *(const short8*)&Qbh[(size_t)qrow * 1024 + 32 + lg * 8];

    const int nkv = 2 * qt + 2;
    const int sr = tid >> 3;
    const int sc = (tid & 7) ^ (sr & 7);      // pre-swizzled source chunk

    f32x4 oacc[4] = {};                       // col=lane&15=hd, row q = 4*lg+r
    float l_r = 0.f, m_r = -1e30f;            // per-lane (q = lr) softmax state

    // prologue: stage kv tile 0 into buf 0 (512 thr x 16B = full 8KB tile)
    gload16(Kbh + (size_t)sr * 1024 + sc * 8, (char*)Ks[0]  + wave * 1024);
    gload16(Vbh + (size_t)sr * 2048 + sc * 8, (char*)Vts[0] + wave * 1024);
    __syncthreads();

    for (int kv = 0; kv < nkv; ++kv) {
        const int cur = kv & 1, nxt = cur ^ 1;
        const int kv0 = kv * 64;
        if (kv + 1 < nkv) {
            const int kvn = kv0 + 64;
            gload16(Kbh + (size_t)(kvn + sr) * 1024 + sc * 8, (char*)Ks[nxt]  + wave * 1024);
            gload16(Vbh + (size_t)sr * 2048 + kvn + sc * 8,   (char*)Vts[nxt] + wave * 1024);
        }

        if (kv0 <= q0w + 15) {   // wave has unmasked rows in this tile
            // ---- S^T = K Q (A=K, B=Q): sacc[c][r]: q=lr, kv=kv0+c*16+4lg+r
            f32x4 sacc[4];
#pragma unroll
            for (int c = 0; c < 4; ++c) {
                const int row = c * 16 + lr;
                const short8 k0 = *(const short8*)&Ks[cur][swz(row, lg * 8)];
                const short8 k1 = *(const short8*)&Ks[cur][swz(row, 32 + lg * 8)];
                f32x4 z = { 0.f, 0.f, 0.f, 0.f };
                __builtin_amdgcn_s_setprio(1);
                z = __builtin_amdgcn_mfma_f32_16x16x32_bf16(k0, qf0, z, 0, 0, 0);
                z = __builtin_amdgcn_mfma_f32_16x16x32_bf16(k1, qf1, z, 0, 0, 0);
                __builtin_amdgcn_s_setprio(0);
                sacc[c] = z;
            }

            // ---- causal mask (diagonal-overlap tiles only; wave-uniform)
            if (kv0 + 63 > q0w) {
                const int kbase = kv0 + 4 * lg;
#pragma unroll
                for (int c = 0; c < 4; ++c)
#pragma unroll
                    for (int r = 0; r < 4; ++r)
                        if (kbase + c * 16 + r > qrow) sacc[c][r] = -1e30f;
            }

            // ---- per-lane softmax over 16 values + cross-g combine (2 shfl)
            float mx0 = fmaxf(fmaxf(sacc[0][0], sacc[0][1]), fmaxf(sacc[0][2], sacc[0][3]));
            float mx1 = fmaxf(fmaxf(sacc[1][0], sacc[1][1]), fmaxf(sacc[1][2], sacc[1][3]));
            float mx2 = fmaxf(fmaxf(sacc[2][0], sacc[2][1]), fmaxf(sacc[2][2], sacc[2][3]));
            float mx3 = fmaxf(fmaxf(sacc[3][0], sacc[3][1]), fmaxf(sacc[3][2], sacc[3][3]));
            float mx = fmaxf(fmaxf(mx0, mx1), fmaxf(mx2, mx3));
            mx = fmaxf(mx, __shfl_xor(mx, 16));
            mx = fmaxf(mx, __shfl_xor(mx, 32));

            const float df = mx - m_r;
            if (__any(df > 8.0f)) {           // defer-max: rescale only on growth
                const float mn = (df > 8.0f) ? mx : m_r;
                const float al = exp2f(m_r - mn);
                m_r = mn;
                l_r *= al;
#pragma unroll
                for (int r = 0; r < 4; ++r) {
                    const float alo = __shfl(al, 4 * lg + r);   // al at q=4lg+r
#pragma unroll
                    for (int c2 = 0; c2 < 4; ++c2) oacc[c2][r] *= alo;
                }
            }

            // ---- P = exp2(S - m), in-lane sum
            float ts = 0.f;
#pragma unroll
            for (int c = 0; c < 4; ++c)
#pragma unroll
                for (int r = 0; r < 4; ++r) {
                    const float pv = exp2f(sacc[c][r] - m_r);
                    sacc[c][r] = pv;
                    ts += pv;
                }
            ts += __shfl_xor(ts, 16);
            ts += __shfl_xor(ts, 32);
            l_r += ts;

            // ---- PV: in-register A-frag (k-slot permuted; V pre-permuted)
#pragma unroll
            for (int m2 = 0; m2 < 2; ++m2) {
                short8 pa;
#pragma unroll
                for (int r = 0; r < 4; ++r) {
                    pa[r]     = (short)f2b_fast(sacc[2 * m2][r]);
                    pa[4 + r] = (short)f2b_fast(sacc[2 * m2 + 1][r]);
                }
                __builtin_amdgcn_s_setprio(1);
#pragma unroll
                for (int c2 = 0; c2 < 4; ++c2) {
                    const short8 vb = *(const short8*)&Vts[cur][swz(c2 * 16 + lr, m2 * 32 + lg * 8)];
                    oacc[c2] = __builtin_amdgcn_mfma_f32_16x16x32_bf16(pa, vb, oacc[c2], 0, 0, 0);
                }
                __builtin_amdgcn_s_setprio(0);
            }
        }
        __syncthreads();
    }

    // ---- epilogue: l for q=4lg+r via shfl; O[q][hd] with hd=c2*16+lr
    float lo[4];
#pragma unroll
    for (int r = 0; r < 4; ++r) lo[r] = 1.0f / __shfl(l_r, 4 * lg + r);
#pragma unroll
    for (int c2 = 0; c2 < 4; ++c2)
#pragma unroll
        for (int r = 0; r < 4; ++r) {
            const float ov = oacc[c2][r] * lo[r];
            Obh[(size_t)(q0w + 4 * lg + r) * 1024 + c2 * 16 + lr] = f2b(ov);
        }
}

// ---------------------------------------------------------------------------
// Memory plan (f32 I/O):
//   d_out bytes: [0,16.78M) D0 = Q bf16 -> attnout bf16 (in-place)
//                [16.78,33.55M) D1 = K bf16
//                [33.55,50.33M) xb bf16 (dead before lnV writes Vf)
//                [33.55,67.1M)  Vf f32 final V output
//                [0,33.55M)     outF f32 final out (written last)
//   ws (25.2MB): S0 = preLN-V bf16 -> Vt bf16 -> gemmP-out bf16; weights after.
// ---------------------------------------------------------------------------
extern "C" void kernel_launch(void* const* d_in, const int* in_sizes, int n_in,
                              void* d_out, int out_size, void* d_ws, size_t ws_size,
                              hipStream_t stream)
{
    (void)in_sizes; (void)n_in; (void)out_size; (void)ws_size;
    const float* x   = (const float*)d_in[0];
    const float* wq  = (const float*)d_in[1];  const float* bq   = (const float*)d_in[2];
    const float* wk  = (const float*)d_in[3];  const float* bk   = (const float*)d_in[4];
    const float* wv  = (const float*)d_in[5];  const float* bv   = (const float*)d_in[6];
    const float* wp  = (const float*)d_in[7];  const float* bp   = (const float*)d_in[8];
    const float* g_q = (const float*)d_in[9];  const float* be_q = (const float*)d_in[10];
    const float* g_k = (const float*)d_in[11]; const float* be_k = (const float*)d_in[12];
    const float* g_v = (const float*)d_in[13]; const float* be_v = (const float*)d_in[14];
    const float* g_p = (const float*)d_in[15]; const float* be_p = (const float*)d_in[16];

    float* outF = (float*)d_out;
    float* Vf   = outF + 8388608;
    u16* D0 = (u16*)d_out;                  // Q bf16 -> attnout
    u16* D1 = (u16*)d_out + 8388608;        // K bf16
    u16* xb = (u16*)d_out + 16777216;       // x bf16 (dead before Vf written)
    char* ws = (char*)d_ws;
    u16* S0  = (u16*)ws;                    // preLN-V -> Vt -> gemmP out
    u16* wb  = (u16*)(ws + 16777216);       // 4 bf16 weight matrices contiguous
    u16* wpb = wb + 3145728;

    const dim3 bb(256);
    cvt4_k<<<dim3(1024, 4), bb, 0, stream>>>(wq, wk, wv, wp, wb);
    cvt_k<<<dim3(8192), bb, 0, stream>>>(x, xb);

    gemm3_k<<<dim3(64, 24), bb, 0, stream>>>(xb, wb, bq, bk, bv, D0, D1, S0);
    ln3_k<<<dim3(8192, 3), bb, 0, stream>>>(D0, D1, S0, g_q, be_q, g_k, be_k, g_v, be_v, Vf);
    vtr_k<<<dim3(2048), bb, 0, stream>>>(Vf, S0);                      // permuted Vt over S0
    attn_k<<<dim3(16, 64), dim3(512), 0, stream>>>(D0, D1, S0, D0);    // out over Q
    gemm_k<<<dim3(64, 8), bb, 0, stream>>>(D0, wpb, bp, S0, 8192, 1024, 1024);
    lnf_k<<<dim3(8192), bb, 0, stream>>>(S0, g_p, be_p, outF);
}

// Round 9
// 208.939 us; speedup vs baseline: 2.8094x; 1.0285x over previous
//
#include <hip/hip_runtime.h>
#include <hip/hip_bf16.h>

// B=4, S=2048, E=1024, H=16, HD=64. d_in/d_out are FLOAT32; compute in bf16 MFMA.
typedef unsigned short u16;
typedef __attribute__((ext_vector_type(8))) short short8;   // 8 bf16 (MFMA A/B frag)
typedef __attribute__((ext_vector_type(4))) float f32x4;    // MFMA C/D frag

__device__ __forceinline__ float b2f(u16 u){
    unsigned v = ((unsigned)u) << 16; float f; __builtin_memcpy(&f, &v, 4); return f;
}
__device__ __forceinline__ u16 f2b(float f){          // RNE
    unsigned v; __builtin_memcpy(&v, &f, 4);
    v += 0x7fffu + ((v >> 16) & 1u);
    return (u16)(v >> 16);
}
// pack two f32 -> one u32 of two bf16 (round-half-up), 3 VALU ops
__device__ __forceinline__ unsigned pk2(float lo, float hi){
    unsigned a, b; __builtin_memcpy(&a, &lo, 4); __builtin_memcpy(&b, &hi, 4);
    return __builtin_amdgcn_perm(b + 0x8000u, a + 0x8000u, 0x07060302u);
}

__device__ __forceinline__ void gload16(const void* g, void* l){
    __builtin_amdgcn_global_load_lds((const __attribute__((address_space(1))) unsigned int*)g,
                                     (__attribute__((address_space(3))) unsigned int*)l, 16, 0, 0);
}

// XOR bank swizzle for 64-u16-wide LDS rows (row stride 128B).
__device__ __forceinline__ int swz(int row, int col){
    return row * 64 + (col ^ ((row & 7) << 3));
}

// ---------------------------------------------------------------------------
// Fused f32->bf16 convert: x (8192 rows) + 4 weight matrices (4096 rows).
// grid 12288 x 256 threads, 1024 elems/block.
// ---------------------------------------------------------------------------
__global__ void cvtall_k(const float* __restrict__ x,
                         const float* __restrict__ wq, const float* __restrict__ wk,
                         const float* __restrict__ wv, const float* __restrict__ wp,
                         u16* __restrict__ xb, u16* __restrict__ wb)
{
    const int blk = blockIdx.x;
    const float* src; u16* dst;
    if (blk < 8192) {
        src = x + (size_t)blk * 1024; dst = xb + (size_t)blk * 1024;
    } else {
        const int m = (blk - 8192) >> 10, r = (blk - 8192) & 1023;
        const float* w = (m == 0) ? wq : (m == 1) ? wk : (m == 2) ? wv : wp;
        src = w + (size_t)r * 1024; dst = wb + ((size_t)m << 20) + (size_t)r * 1024;
    }
    const int i = threadIdx.x * 4;
    float4 v = *(const float4*)&src[i];
    ushort4 o;
    o.x = f2b(v.x); o.y = f2b(v.y); o.z = f2b(v.z); o.w = f2b(v.w);
    *(ushort4*)&dst[i] = o;
}

// ---------------------------------------------------------------------------
// Fused Q/K/V GEMM: C[m][n] = xb[m][k] @ W_mat[n][k]^T + bias_mat[n]
// ---------------------------------------------------------------------------
__global__ __launch_bounds__(256, 2)
void gemm3_k(const u16* __restrict__ A, const u16* __restrict__ Wb,
             const float* __restrict__ b0, const float* __restrict__ b1,
             const float* __restrict__ b2,
             u16* __restrict__ C0, u16* __restrict__ C1, u16* __restrict__ C2)
{
    __shared__ u16 As[128 * 32];
    __shared__ u16 Bs[128 * 32];
    const int K = 1024, N = 1024;
    const int mat = blockIdx.y >> 3;
    const int n0  = (blockIdx.y & 7) * 128;
    const u16* W = Wb + ((size_t)mat << 20);
    const float* bias = (mat == 0) ? b0 : (mat == 1) ? b1 : b2;
    u16* C = (mat == 0) ? C0 : (mat == 1) ? C1 : C2;

    const int tid  = threadIdx.x;
    const int wave = tid >> 6, lane = tid & 63;
    const int lg = lane >> 4, lr = lane & 15;
    const int m0 = blockIdx.x * 128;
    const int wm = (wave >> 1) * 64, wn = (wave & 1) * 64;

    const u16* aG = A + (size_t)(m0 + (tid >> 2)) * K + (tid & 3) * 8;
    const u16* bG = W + (size_t)(n0 + (tid >> 2)) * K + (tid & 3) * 8;
    char* asBase = (char*)As + wave * 1024;
    char* bsBase = (char*)Bs + wave * 1024;
    const size_t rstep = (size_t)64 * K;

    f32x4 acc[4][4] = {};

    for (int kt = 0; kt < K; kt += 32) {
        gload16(aG + kt,         asBase);
        gload16(aG + kt + rstep, asBase + 4096);
        gload16(bG + kt,         bsBase);
        gload16(bG + kt + rstep, bsBase + 4096);
        __syncthreads();

        short8 a[4], b[4];
#pragma unroll
        for (int i = 0; i < 4; ++i) a[i] = *(const short8*)&As[(wm + i*16 + lr)*32 + lg*8];
#pragma unroll
        for (int j = 0; j < 4; ++j) b[j] = *(const short8*)&Bs[(wn + j*16 + lr)*32 + lg*8];
        __builtin_amdgcn_s_setprio(1);
#pragma unroll
        for (int i = 0; i < 4; ++i)
#pragma unroll
            for (int j = 0; j < 4; ++j)
                acc[i][j] = __builtin_amdgcn_mfma_f32_16x16x32_bf16(a[i], b[j], acc[i][j], 0, 0, 0);
        __builtin_amdgcn_s_setprio(0);
        __syncthreads();
    }

#pragma unroll
    for (int j = 0; j < 4; ++j) {
        const int cn = n0 + wn + j*16 + lr;
        const float bv = bias[cn];
#pragma unroll
        for (int i = 0; i < 4; ++i) {
            const int cm = m0 + wm + i*16 + lg*4;
#pragma unroll
            for (int r = 0; r < 4; ++r)
                C[(size_t)(cm + r) * N + cn] = f2b(acc[i][j][r] + bv);
        }
    }
}

// ---------------------------------------------------------------------------
// Single-matrix GEMM (out-projection).
// ---------------------------------------------------------------------------
__global__ __launch_bounds__(256, 2)
void gemm_k(const u16* __restrict__ A, const u16* __restrict__ W,
            const float* __restrict__ bias, u16* __restrict__ C,
            int M, int N, int K)
{
    __shared__ u16 As[128 * 32];
    __shared__ u16 Bs[128 * 32];
    const int tid  = threadIdx.x;
    const int wave = tid >> 6, lane = tid & 63;
    const int lg = lane >> 4, lr = lane & 15;
    const int m0 = blockIdx.x * 128, n0 = blockIdx.y * 128;
    const int wm = (wave >> 1) * 64, wn = (wave & 1) * 64;

    const u16* aG = A + (size_t)(m0 + (tid >> 2)) * K + (tid & 3) * 8;
    const u16* bG = W + (size_t)(n0 + (tid >> 2)) * K + (tid & 3) * 8;
    char* asBase = (char*)As + wave * 1024;
    char* bsBase = (char*)Bs + wave * 1024;
    const size_t rstep = (size_t)64 * K;

    f32x4 acc[4][4] = {};

    for (int kt = 0; kt < K; kt += 32) {
        gload16(aG + kt,         asBase);
        gload16(aG + kt + rstep, asBase + 4096);
        gload16(bG + kt,         bsBase);
        gload16(bG + kt + rstep, bsBase + 4096);
        __syncthreads();

        short8 a[4], b[4];
#pragma unroll
        for (int i = 0; i < 4; ++i) a[i] = *(const short8*)&As[(wm + i*16 + lr)*32 + lg*8];
#pragma unroll
        for (int j = 0; j < 4; ++j) b[j] = *(const short8*)&Bs[(wn + j*16 + lr)*32 + lg*8];
        __builtin_amdgcn_s_setprio(1);
#pragma unroll
        for (int i = 0; i < 4; ++i)
#pragma unroll
            for (int j = 0; j < 4; ++j)
                acc[i][j] = __builtin_amdgcn_mfma_f32_16x16x32_bf16(a[i], b[j], acc[i][j], 0, 0, 0);
        __builtin_amdgcn_s_setprio(0);
        __syncthreads();
    }

#pragma unroll
    for (int j = 0; j < 4; ++j) {
        const int cn = n0 + wn + j*16 + lr;
        const float bv = bias[cn];
#pragma unroll
        for (int i = 0; i < 4; ++i) {
            const int cm = m0 + wm + i*16 + lg*4;
#pragma unroll
            for (int r = 0; r < 4; ++r)
                C[(size_t)(cm + r) * N + cn] = f2b(acc[i][j][r] + bv);
        }
    }
}

// ---------------------------------------------------------------------------
// Fused Q/K/V LayerNorm. grid (8192, 3).
// ---------------------------------------------------------------------------
__global__ void ln3_k(u16* D0, u16* D1, const u16* __restrict__ Sv,
                      const float* __restrict__ g_q, const float* __restrict__ be_q,
                      const float* __restrict__ g_k, const float* __restrict__ be_k,
                      const float* __restrict__ g_v, const float* __restrict__ be_v,
                      float* __restrict__ Vf)
{
    __shared__ float red[8];
    const int which = blockIdx.y;
    const u16* src = (which == 0) ? D0 : (which == 1) ? D1 : Sv;
    const float* g  = (which == 0) ? g_q  : (which == 1) ? g_k  : g_v;
    const float* be = (which == 0) ? be_q : (which == 1) ? be_k : be_v;
    const float scale = (which == 0) ? 0.125f * 1.4426950408889634f : 1.0f;

    const int row = blockIdx.x;
    const int tid = threadIdx.x;
    const int lane = tid & 63, wave = tid >> 6;
    ushort4 v = *(const ushort4*)&src[(size_t)row * 1024 + tid * 4];
    float f[4] = { b2f(v.x), b2f(v.y), b2f(v.z), b2f(v.w) };
    float s  = f[0] + f[1] + f[2] + f[3];
    float ss = f[0]*f[0] + f[1]*f[1] + f[2]*f[2] + f[3]*f[3];
#pragma unroll
    for (int off = 32; off; off >>= 1) { s += __shfl_down(s, off); ss += __shfl_down(ss, off); }
    if (lane == 0) { red[wave] = s; red[4 + wave] = ss; }
    __syncthreads();
    s  = red[0] + red[1] + red[2] + red[3];
    ss = red[4] + red[5] + red[6] + red[7];
    const float mean = s * (1.0f / 1024.0f);
    const float var  = fmaxf(ss * (1.0f / 1024.0f) - mean * mean, 0.0f);
    const float rs   = rsqrtf(var + 1e-5f);
    float o[4];
#pragma unroll
    for (int k = 0; k < 4; ++k) {
        const int e = tid * 4 + k;
        o[k] = ((f[k] - mean) * rs * g[e] + be[e]) * scale;
    }
    if (which == 2) {
        const int b = row >> 11, sIdx = row & 2047;
        const int h = tid >> 4, hd = (tid * 4) & 63;
        float4 ov = { o[0], o[1], o[2], o[3] };
        *(float4*)&Vf[(((size_t)(b * 16 + h) * 2048 + sIdx) << 6) + hd] = ov;
    } else {
        u16* dst = (which == 0) ? D0 : D1;
        ushort4 ov; ov.x = f2b(o[0]); ov.y = f2b(o[1]); ov.z = f2b(o[2]); ov.w = f2b(o[3]);
        *(ushort4*)&dst[(size_t)row * 1024 + tid * 4] = ov;
    }
}

// ---------------------------------------------------------------------------
// Final LayerNorm: bf16 src -> f32 flat dst.
// ---------------------------------------------------------------------------
__global__ void lnf_k(const u16* __restrict__ src, const float* __restrict__ g,
                      const float* __restrict__ be, float* __restrict__ dst)
{
    __shared__ float red[8];
    const int row = blockIdx.x;
    const int tid = threadIdx.x;
    const int lane = tid & 63, wave = tid >> 6;
    ushort4 v = *(const ushort4*)&src[(size_t)row * 1024 + tid * 4];
    float f[4] = { b2f(v.x), b2f(v.y), b2f(v.z), b2f(v.w) };
    float s  = f[0] + f[1] + f[2] + f[3];
    float ss = f[0]*f[0] + f[1]*f[1] + f[2]*f[2] + f[3]*f[3];
#pragma unroll
    for (int off = 32; off; off >>= 1) { s += __shfl_down(s, off); ss += __shfl_down(ss, off); }
    if (lane == 0) { red[wave] = s; red[4 + wave] = ss; }
    __syncthreads();
    s  = red[0] + red[1] + red[2] + red[3];
    ss = red[4] + red[5] + red[6] + red[7];
    const float mean = s * (1.0f / 1024.0f);
    const float var  = fmaxf(ss * (1.0f / 1024.0f) - mean * mean, 0.0f);
    const float rs   = rsqrtf(var + 1e-5f);
    float4 ov;
    ov.x = (f[0] - mean) * rs * g[tid*4+0] + be[tid*4+0];
    ov.y = (f[1] - mean) * rs * g[tid*4+1] + be[tid*4+1];
    ov.z = (f[2] - mean) * rs * g[tid*4+2] + be[tid*4+2];
    ov.w = (f[3] - mean) * rs * g[tid*4+3] + be[tid*4+3];
    *(float4*)&dst[(size_t)row * 1024 + tid * 4] = ov;
}

// ---------------------------------------------------------------------------
// V transpose + PV-slot permutation:
// Vf f32 [bh][s][64] -> Vt bf16 [bh][64(hd)][2048(s-permuted)].
// Within each 32-kv block, kv = 16a+4b+c stored at slot 8b+4a+c (matches the
// attention kernel's in-register P slot order). Bijective per 32-block.
// ---------------------------------------------------------------------------
__global__ void vtr_k(const float* __restrict__ Vf, u16* __restrict__ Vt)
{
    __shared__ float T[64 * 65];
    const int bh = blockIdx.x >> 5, st = blockIdx.x & 31;
    const int tid = threadIdx.x;
    const float* src = Vf + (size_t)bh * 2048 * 64 + (size_t)st * 64 * 64;
#pragma unroll
    for (int it = 0; it < 4; ++it) {
        const int fid = tid + it * 256;
        const int r = fid >> 4, c4 = fid & 15;
        float4 v = *(const float4*)&src[r * 64 + c4 * 4];
        T[r * 65 + c4*4 + 0] = v.x;
        T[r * 65 + c4*4 + 1] = v.y;
        T[r * 65 + c4*4 + 2] = v.z;
        T[r * 65 + c4*4 + 3] = v.w;
    }
    __syncthreads();
    u16* dst = Vt + (size_t)bh * 64 * 2048 + (size_t)st * 64;
#pragma unroll
    for (int it = 0; it < 2; ++it) {
        const int oid = tid + it * 256;
        const int hd = oid >> 3, ch = oid & 7;     // ch: source kv chunk of 8
        u16 tmp[8];
#pragma unroll
        for (int j = 0; j < 8; ++j) tmp[j] = f2b(T[(ch * 8 + j) * 65 + hd]);
        const int base = 32 * (ch >> 2) + 4 * ((ch >> 1) & 1);
        const int p0 = base + 8 * ((2 * ch + 0) & 3);
        const int p1 = base + 8 * ((2 * ch + 1) & 3);
        ushort4 lo = { tmp[0], tmp[1], tmp[2], tmp[3] };
        ushort4 hi = { tmp[4], tmp[5], tmp[6], tmp[7] };
        *(ushort4*)&dst[(size_t)hd * 2048 + p0] = lo;
        *(ushort4*)&dst[(size_t)hd * 2048 + p1] = hi;
    }
}

// ---------------------------------------------------------------------------
// Causal flash attention, swapped-QK / in-register-P, VALU-lean addressing.
// QBLK=128 (8 waves x 16 q-rows), KVBLK=64 double-buffered (32 KB LDS),
// grid (16,64) unpaired, big q-tiles first. All LDS read offsets hoisted
// (buffer toggle = 1 XOR); global staging pointers incremented; P packed via
// v_perm (3 ops/pair); max3-friendly reduction trees. Defer-max THR=8.
// ---------------------------------------------------------------------------
__global__ __launch_bounds__(512, 4)
void attn_k(const u16* __restrict__ Qf, const u16* __restrict__ Kf,
            const u16* __restrict__ Vt, u16* __restrict__ O)
{
    __shared__ u16 Lds[16384];        // [buf0: K 8KB | V 8KB][buf1: K | V]
    const int lin = (int)blockIdx.x + (int)blockIdx.y * 16;
    const int xcd = lin & 7, idx = lin >> 3;
    const int bh  = xcd * 8 + (idx & 7);
    const int qt  = 15 - (idx >> 3);          // big tiles dispatch first
    const int b = bh >> 4, h = bh & 15;
    const int tid = threadIdx.x, wave = tid >> 6, lane = tid & 63;
    const int lg = lane >> 4, lr = lane & 15;
    const u16* Qbh = Qf + ((size_t)b * 2048) * 1024 + h * 64;
    const u16* Kbh = Kf + ((size_t)b * 2048) * 1024 + h * 64;
    const u16* Vbh = Vt + (size_t)bh * 64 * 2048;     // [hd][s-perm]
    u16* Obh = O + ((size_t)b * 2048) * 1024 + h * 64;

    const int q0w  = qt * 128 + wave * 16;    // wave's first q row
    const int qrow = q0w + lr;                // this lane's q (softmax axis)
    const short8 qf0 = *(const short8*)&Qbh[(size_t)qrow * 1024 + lg * 8];
    const short8 qf1 = *(const short8*)&Qbh[(size_t)qrow * 1024 + 32 + lg * 8];

    const int nkv    = 2 * qt + 2;
    const int diagkv = q0w >> 6;              // this wave's diagonal tile

    // hoisted per-lane LDS byte offsets (K at +0, V at +8192 within a buffer)
    const int kro0 = swz(lr, lg * 8) * 2;
    const int kro1 = swz(lr, 32 + lg * 8) * 2;
    const int vro0 = 8192 + kro0;
    const int vro1 = 8192 + kro1;
    const char* ldsB = (const char*)Lds;

    // staging: thread -> row tid>>3, pre-swizzled 16B chunk; incremented ptrs
    const int sr = tid >> 3;
    const int sc8 = ((tid & 7) ^ (sr & 7)) * 8;
    const u16* kg = Kbh + (size_t)sr * 1024 + sc8;
    const u16* vg = Vbh + (size_t)sr * 2048 + sc8;
    const int stKo = wave * 1024;             // wave-uniform LDS dest offset

    f32x4 oacc[4] = {};                       // col=lr=hd-frag, row q=4*lg+r
    float l_r = 0.f, m_r = -1e30f;

    // prologue: stage kv tile 0 into buf 0
    gload16(kg, (char*)Lds + stKo);
    gload16(vg, (char*)Lds + 8192 + stKo);
    kg += 65536; vg += 64;
    __syncthreads();

    int rbuf = 0, sbuf = 16384;               // read buf 0, stage buf 1
    for (int kv = 0; kv < nkv; ++kv) {
        if (kv + 1 < nkv) {
            gload16(kg, (char*)Lds + sbuf + stKo);
            gload16(vg, (char*)Lds + sbuf + 8192 + stKo);
            kg += 65536; vg += 64;
        }

        if (kv <= diagkv) {
            const char* kp0 = ldsB + (rbuf + kro0);
            const char* kp1 = ldsB + (rbuf + kro1);

            // ---- S^T = K Q: sacc[c][r]: q=lr, kv=kv*64 + c*16 + 4*lg + r
            f32x4 sacc[4];
#pragma unroll
            for (int c = 0; c < 4; ++c) {
                const short8 k0 = *(const short8*)(kp0 + c * 2048);
                const short8 k1 = *(const short8*)(kp1 + c * 2048);
                f32x4 z = { 0.f, 0.f, 0.f, 0.f };
                __builtin_amdgcn_s_setprio(1);
                z = __builtin_amdgcn_mfma_f32_16x16x32_bf16(k0, qf0, z, 0, 0, 0);
                z = __builtin_amdgcn_mfma_f32_16x16x32_bf16(k1, qf1, z, 0, 0, 0);
                __builtin_amdgcn_s_setprio(0);
                sacc[c] = z;
            }

            // ---- causal mask on the wave's diagonal tile only
            if (kv == diagkv) {
                const int kbase = kv * 64 + 4 * lg;
#pragma unroll
                for (int c = 0; c < 4; ++c)
#pragma unroll
                    for (int r = 0; r < 4; ++r)
                        if (kbase + c * 16 + r > qrow) sacc[c][r] = -1e30f;
            }

            // ---- per-lane max (max3 trees) + cross-half combine
            float t0 = fmaxf(fmaxf(sacc[0][0], sacc[0][1]), sacc[0][2]);
            float t1 = fmaxf(fmaxf(sacc[0][3], sacc[1][0]), sacc[1][1]);
            float t2 = fmaxf(fmaxf(sacc[1][2], sacc[1][3]), sacc[2][0]);
            float t3 = fmaxf(fmaxf(sacc[2][1], sacc[2][2]), sacc[2][3]);
            float t4 = fmaxf(fmaxf(sacc[3][0], sacc[3][1]), sacc[3][2]);
            float mx = fmaxf(fmaxf(fmaxf(t0, t1), fmaxf(t2, t3)),
                             fmaxf(t4, sacc[3][3]));
            mx = fmaxf(mx, __shfl_xor(mx, 16));
            mx = fmaxf(mx, __shfl_xor(mx, 32));

            const float df = mx - m_r;
            if (__any(df > 8.0f)) {           // defer-max rescale
                const float mn = (df > 8.0f) ? mx : m_r;
                const float al = exp2f(m_r - mn);
                m_r = mn;
                l_r *= al;
#pragma unroll
                for (int r = 0; r < 4; ++r) {
                    const float alo = __shfl(al, 4 * lg + r);
#pragma unroll
                    for (int c2 = 0; c2 < 4; ++c2) oacc[c2][r] *= alo;
                }
            }

            // ---- P = exp2(S - m); pairwise sum tree
#pragma unroll
            for (int c = 0; c < 4; ++c)
#pragma unroll
                for (int r = 0; r < 4; ++r) sacc[c][r] = exp2f(sacc[c][r] - m_r);
            {
                float s0 = (sacc[0][0] + sacc[0][1]) + (sacc[0][2] + sacc[0][3]);
                float s1 = (sacc[1][0] + sacc[1][1]) + (sacc[1][2] + sacc[1][3]);
                float s2 = (sacc[2][0] + sacc[2][1]) + (sacc[2][2] + sacc[2][3]);
                float s3 = (sacc[3][0] + sacc[3][1]) + (sacc[3][2] + sacc[3][3]);
                float ts = (s0 + s1) + (s2 + s3);
                ts += __shfl_xor(ts, 16);
                ts += __shfl_xor(ts, 32);
                l_r += ts;
            }

            // ---- PV: pack P via v_perm, in-register A-frags
            const char* vp0 = ldsB + (rbuf + vro0);
            const char* vp1 = ldsB + (rbuf + vro1);
#pragma unroll
            for (int m2 = 0; m2 < 2; ++m2) {
                union { unsigned w[4]; short8 v; } pa;
                pa.w[0] = pk2(sacc[2*m2][0],   sacc[2*m2][1]);
                pa.w[1] = pk2(sacc[2*m2][2],   sacc[2*m2][3]);
                pa.w[2] = pk2(sacc[2*m2+1][0], sacc[2*m2+1][1]);
                pa.w[3] = pk2(sacc[2*m2+1][2], sacc[2*m2+1][3]);
                const char* vp = m2 ? vp1 : vp0;
                __builtin_amdgcn_s_setprio(1);
#pragma unroll
                for (int c2 = 0; c2 < 4; ++c2) {
                    const short8 vb = *(const short8*)(vp + c2 * 2048);
                    oacc[c2] = __builtin_amdgcn_mfma_f32_16x16x32_bf16(pa.v, vb, oacc[c2], 0, 0, 0);
                }
                __builtin_amdgcn_s_setprio(0);
            }
        }
        rbuf ^= 16384; sbuf ^= 16384;
        __syncthreads();
    }

    // ---- epilogue
    float lo[4];
#pragma unroll
    for (int r = 0; r < 4; ++r) lo[r] = 1.0f / __shfl(l_r, 4 * lg + r);
#pragma unroll
    for (int c2 = 0; c2 < 4; ++c2)
#pragma unroll
        for (int r = 0; r < 4; ++r) {
            const float ov = oacc[c2][r] * lo[r];
            Obh[(size_t)(q0w + 4 * lg + r) * 1024 + c2 * 16 + lr] = f2b(ov);
        }
}

// ---------------------------------------------------------------------------
// Memory plan (f32 I/O):
//   d_out bytes: [0,16.78M) D0 = Q bf16 -> attnout bf16 (in-place)
//                [16.78,33.55M) D1 = K bf16
//                [33.55,50.33M) xb bf16 (dead before lnV writes Vf)
//                [33.55,67.1M)  Vf f32 final V output
//                [0,33.55M)     outF f32 final out (written last)
//   ws (25.2MB): S0 = preLN-V bf16 -> Vt bf16 -> gemmP-out bf16; weights after.
// ---------------------------------------------------------------------------
extern "C" void kernel_launch(void* const* d_in, const int* in_sizes, int n_in,
                              void* d_out, int out_size, void* d_ws, size_t ws_size,
                              hipStream_t stream)
{
    (void)in_sizes; (void)n_in; (void)out_size; (void)ws_size;
    const float* x   = (const float*)d_in[0];
    const float* wq  = (const float*)d_in[1];  const float* bq   = (const float*)d_in[2];
    const float* wk  = (const float*)d_in[3];  const float* bk   = (const float*)d_in[4];
    const float* wv  = (const float*)d_in[5];  const float* bv   = (const float*)d_in[6];
    const float* wp  = (const float*)d_in[7];  const float* bp   = (const float*)d_in[8];
    const float* g_q = (const float*)d_in[9];  const float* be_q = (const float*)d_in[10];
    const float* g_k = (const float*)d_in[11]; const float* be_k = (const float*)d_in[12];
    const float* g_v = (const float*)d_in[13]; const float* be_v = (const float*)d_in[14];
    const float* g_p = (const float*)d_in[15]; const float* be_p = (const float*)d_in[16];

    float* outF = (float*)d_out;
    float* Vf   = outF + 8388608;
    u16* D0 = (u16*)d_out;                  // Q bf16 -> attnout
    u16* D1 = (u16*)d_out + 8388608;        // K bf16
    u16* xb = (u16*)d_out + 16777216;       // x bf16 (dead before Vf written)
    char* ws = (char*)d_ws;
    u16* S0  = (u16*)ws;                    // preLN-V -> Vt -> gemmP out
    u16* wb  = (u16*)(ws + 16777216);       // 4 bf16 weight matrices contiguous
    u16* wpb = wb + 3145728;

    const dim3 bb(256);
    cvtall_k<<<dim3(12288), bb, 0, stream>>>(x, wq, wk, wv, wp, xb, wb);

    gemm3_k<<<dim3(64, 24), bb, 0, stream>>>(xb, wb, bq, bk, bv, D0, D1, S0);
    ln3_k<<<dim3(8192, 3), bb, 0, stream>>>(D0, D1, S0, g_q, be_q, g_k, be_k, g_v, be_v, Vf);
    vtr_k<<<dim3(2048), bb, 0, stream>>>(Vf, S0);                      // permuted Vt over S0
    attn_k<<<dim3(16, 64), dim3(512), 0, stream>>>(D0, D1, S0, D0);    // out over Q
    gemm_k<<<dim3(64, 8), bb, 0, stream>>>(D0, wpb, bp, S0, 8192, 1024, 1024);
    lnf_k<<<dim3(8192), bb, 0, stream>>>(S0, g_p, be_p, outF);
}

// Round 10
// 194.106 us; speedup vs baseline: 3.0241x; 1.0764x over previous
//
#include <hip/hip_runtime.h>
#include <hip/hip_bf16.h>

// B=4, S=2048, E=1024, H=16, HD=64. d_in/d_out are FLOAT32; compute in bf16 MFMA.
typedef unsigned short u16;
typedef __attribute__((ext_vector_type(8))) short short8;   // 8 bf16 (MFMA A/B frag)
typedef __attribute__((ext_vector_type(4))) float f32x4;    // MFMA C/D frag

#define VMCNT2 asm volatile("s_waitcnt vmcnt(2)" ::: "memory")
#define VMCNT0 asm volatile("s_waitcnt vmcnt(0)" ::: "memory")

__device__ __forceinline__ float b2f(u16 u){
    unsigned v = ((unsigned)u) << 16; float f; __builtin_memcpy(&f, &v, 4); return f;
}
__device__ __forceinline__ u16 f2b(float f){          // RNE
    unsigned v; __builtin_memcpy(&v, &f, 4);
    v += 0x7fffu + ((v >> 16) & 1u);
    return (u16)(v >> 16);
}
// pack two f32 -> one u32 of two bf16 (round-half-up), 3 VALU ops
__device__ __forceinline__ unsigned pk2(float lo, float hi){
    unsigned a, b; __builtin_memcpy(&a, &lo, 4); __builtin_memcpy(&b, &hi, 4);
    return __builtin_amdgcn_perm(b + 0x8000u, a + 0x8000u, 0x07060302u);
}

__device__ __forceinline__ void gload16(const void* g, void* l){
    __builtin_amdgcn_global_load_lds((const __attribute__((address_space(1))) unsigned int*)g,
                                     (__attribute__((address_space(3))) unsigned int*)l, 16, 0, 0);
}

// XOR bank swizzle for 64-u16-wide LDS rows (row stride 128B).
__device__ __forceinline__ int swz(int row, int col){
    return row * 64 + (col ^ ((row & 7) << 3));
}

// ---------------------------------------------------------------------------
// Fused f32->bf16 convert: x (8192 rows) + 4 weight matrices (4096 rows).
// ---------------------------------------------------------------------------
__global__ void cvtall_k(const float* __restrict__ x,
                         const float* __restrict__ wq, const float* __restrict__ wk,
                         const float* __restrict__ wv, const float* __restrict__ wp,
                         u16* __restrict__ xb, u16* __restrict__ wb)
{
    const int blk = blockIdx.x;
    const float* src; u16* dst;
    if (blk < 8192) {
        src = x + (size_t)blk * 1024; dst = xb + (size_t)blk * 1024;
    } else {
        const int m = (blk - 8192) >> 10, r = (blk - 8192) & 1023;
        const float* w = (m == 0) ? wq : (m == 1) ? wk : (m == 2) ? wv : wp;
        src = w + (size_t)r * 1024; dst = wb + ((size_t)m << 20) + (size_t)r * 1024;
    }
    const int i = threadIdx.x * 4;
    float4 v = *(const float4*)&src[i];
    ushort4 o;
    o.x = f2b(v.x); o.y = f2b(v.y); o.z = f2b(v.z); o.w = f2b(v.w);
    *(ushort4*)&dst[i] = o;
}

// ---------------------------------------------------------------------------
// Fused Q/K/V GEMM, BK=64 (16 K-steps, half the barriers of BK=32).
// LDS tiles [128][64] bf16 XOR-swizzled; staged via global_load_lds with
// pre-swizzled source chunks (rule: linear dest + inv-swizzled src + swz read).
// ---------------------------------------------------------------------------
__global__ __launch_bounds__(256, 2)
void gemm3_k(const u16* __restrict__ A, const u16* __restrict__ Wb,
             const float* __restrict__ b0, const float* __restrict__ b1,
             const float* __restrict__ b2,
             u16* __restrict__ C0, u16* __restrict__ C1, u16* __restrict__ C2)
{
    __shared__ u16 As[128 * 64];   // 16 KB
    __shared__ u16 Bs[128 * 64];   // 16 KB
    const int K = 1024, N = 1024;
    const int mat = blockIdx.y >> 3;
    const int n0  = (blockIdx.y & 7) * 128;
    const u16* W = Wb + ((size_t)mat << 20);
    const float* bias = (mat == 0) ? b0 : (mat == 1) ? b1 : b2;
    u16* C = (mat == 0) ? C0 : (mat == 1) ? C1 : C2;

    const int tid  = threadIdx.x;
    const int wave = tid >> 6, lane = tid & 63;
    const int lg = lane >> 4, lr = lane & 15;
    const int m0 = blockIdx.x * 128;
    const int wm = (wave >> 1) * 64, wn = (wave & 1) * 64;

    const int srow = tid >> 3;                       // 0..31
    const int sc8  = ((tid & 7) ^ (srow & 7)) * 8;   // pre-swizzled 16B chunk
    const u16* aG = A + (size_t)(m0 + srow) * K + sc8;
    const u16* bG = W + (size_t)(n0 + srow) * K + sc8;
    char* asBase = (char*)As + wave * 1024;
    char* bsBase = (char*)Bs + wave * 1024;
    const size_t rstep = (size_t)32 * K;             // 32 rows per issue

    f32x4 acc[4][4] = {};

    for (int kt = 0; kt < K; kt += 64) {
#pragma unroll
        for (int i = 0; i < 4; ++i) {
            gload16(aG + kt + i * rstep, asBase + i * 4096);
            gload16(bG + kt + i * rstep, bsBase + i * 4096);
        }
        __syncthreads();

#pragma unroll
        for (int s = 0; s < 2; ++s) {
            short8 a[4], b[4];
#pragma unroll
            for (int i = 0; i < 4; ++i) a[i] = *(const short8*)&As[swz(wm + i*16 + lr, s*32 + lg*8)];
#pragma unroll
            for (int j = 0; j < 4; ++j) b[j] = *(const short8*)&Bs[swz(wn + j*16 + lr, s*32 + lg*8)];
            __builtin_amdgcn_s_setprio(1);
#pragma unroll
            for (int i = 0; i < 4; ++i)
#pragma unroll
                for (int j = 0; j < 4; ++j)
                    acc[i][j] = __builtin_amdgcn_mfma_f32_16x16x32_bf16(a[i], b[j], acc[i][j], 0, 0, 0);
            __builtin_amdgcn_s_setprio(0);
        }
        __syncthreads();
    }

#pragma unroll
    for (int j = 0; j < 4; ++j) {
        const int cn = n0 + wn + j*16 + lr;
        const float bv = bias[cn];
#pragma unroll
        for (int i = 0; i < 4; ++i) {
            const int cm = m0 + wm + i*16 + lg*4;
#pragma unroll
            for (int r = 0; r < 4; ++r)
                C[(size_t)(cm + r) * N + cn] = f2b(acc[i][j][r] + bv);
        }
    }
}

// ---------------------------------------------------------------------------
// Single-matrix GEMM (out-projection), BK=64, same structure.
// ---------------------------------------------------------------------------
__global__ __launch_bounds__(256, 2)
void gemm_k(const u16* __restrict__ A, const u16* __restrict__ W,
            const float* __restrict__ bias, u16* __restrict__ C,
            int M, int N, int K)
{
    __shared__ u16 As[128 * 64];
    __shared__ u16 Bs[128 * 64];
    const int tid  = threadIdx.x;
    const int wave = tid >> 6, lane = tid & 63;
    const int lg = lane >> 4, lr = lane & 15;
    const int m0 = blockIdx.x * 128, n0 = blockIdx.y * 128;
    const int wm = (wave >> 1) * 64, wn = (wave & 1) * 64;

    const int srow = tid >> 3;
    const int sc8  = ((tid & 7) ^ (srow & 7)) * 8;
    const u16* aG = A + (size_t)(m0 + srow) * K + sc8;
    const u16* bG = W + (size_t)(n0 + srow) * K + sc8;
    char* asBase = (char*)As + wave * 1024;
    char* bsBase = (char*)Bs + wave * 1024;
    const size_t rstep = (size_t)32 * K;

    f32x4 acc[4][4] = {};

    for (int kt = 0; kt < K; kt += 64) {
#pragma unroll
        for (int i = 0; i < 4; ++i) {
            gload16(aG + kt + i * rstep, asBase + i * 4096);
            gload16(bG + kt + i * rstep, bsBase + i * 4096);
        }
        __syncthreads();

#pragma unroll
        for (int s = 0; s < 2; ++s) {
            short8 a[4], b[4];
#pragma unroll
            for (int i = 0; i < 4; ++i) a[i] = *(const short8*)&As[swz(wm + i*16 + lr, s*32 + lg*8)];
#pragma unroll
            for (int j = 0; j < 4; ++j) b[j] = *(const short8*)&Bs[swz(wn + j*16 + lr, s*32 + lg*8)];
            __builtin_amdgcn_s_setprio(1);
#pragma unroll
            for (int i = 0; i < 4; ++i)
#pragma unroll
                for (int j = 0; j < 4; ++j)
                    acc[i][j] = __builtin_amdgcn_mfma_f32_16x16x32_bf16(a[i], b[j], acc[i][j], 0, 0, 0);
            __builtin_amdgcn_s_setprio(0);
        }
        __syncthreads();
    }

#pragma unroll
    for (int j = 0; j < 4; ++j) {
        const int cn = n0 + wn + j*16 + lr;
        const float bv = bias[cn];
#pragma unroll
        for (int i = 0; i < 4; ++i) {
            const int cm = m0 + wm + i*16 + lg*4;
#pragma unroll
            for (int r = 0; r < 4; ++r)
                C[(size_t)(cm + r) * N + cn] = f2b(acc[i][j][r] + bv);
        }
    }
}

// ---------------------------------------------------------------------------
// Fused Q/K/V LayerNorm. grid (8192, 3).
// ---------------------------------------------------------------------------
__global__ void ln3_k(u16* D0, u16* D1, const u16* __restrict__ Sv,
                      const float* __restrict__ g_q, const float* __restrict__ be_q,
                      const float* __restrict__ g_k, const float* __restrict__ be_k,
                      const float* __restrict__ g_v, const float* __restrict__ be_v,
                      float* __restrict__ Vf)
{
    __shared__ float red[8];
    const int which = blockIdx.y;
    const u16* src = (which == 0) ? D0 : (which == 1) ? D1 : Sv;
    const float* g  = (which == 0) ? g_q  : (which == 1) ? g_k  : g_v;
    const float* be = (which == 0) ? be_q : (which == 1) ? be_k : be_v;
    const float scale = (which == 0) ? 0.125f * 1.4426950408889634f : 1.0f;

    const int row = blockIdx.x;
    const int tid = threadIdx.x;
    const int lane = tid & 63, wave = tid >> 6;
    ushort4 v = *(const ushort4*)&src[(size_t)row * 1024 + tid * 4];
    float f[4] = { b2f(v.x), b2f(v.y), b2f(v.z), b2f(v.w) };
    float s  = f[0] + f[1] + f[2] + f[3];
    float ss = f[0]*f[0] + f[1]*f[1] + f[2]*f[2] + f[3]*f[3];
#pragma unroll
    for (int off = 32; off; off >>= 1) { s += __shfl_down(s, off); ss += __shfl_down(ss, off); }
    if (lane == 0) { red[wave] = s; red[4 + wave] = ss; }
    __syncthreads();
    s  = red[0] + red[1] + red[2] + red[3];
    ss = red[4] + red[5] + red[6] + red[7];
    const float mean = s * (1.0f / 1024.0f);
    const float var  = fmaxf(ss * (1.0f / 1024.0f) - mean * mean, 0.0f);
    const float rs   = rsqrtf(var + 1e-5f);
    float o[4];
#pragma unroll
    for (int k = 0; k < 4; ++k) {
        const int e = tid * 4 + k;
        o[k] = ((f[k] - mean) * rs * g[e] + be[e]) * scale;
    }
    if (which == 2) {
        const int b = row >> 11, sIdx = row & 2047;
        const int h = tid >> 4, hd = (tid * 4) & 63;
        float4 ov = { o[0], o[1], o[2], o[3] };
        *(float4*)&Vf[(((size_t)(b * 16 + h) * 2048 + sIdx) << 6) + hd] = ov;
    } else {
        u16* dst = (which == 0) ? D0 : D1;
        ushort4 ov; ov.x = f2b(o[0]); ov.y = f2b(o[1]); ov.z = f2b(o[2]); ov.w = f2b(o[3]);
        *(ushort4*)&dst[(size_t)row * 1024 + tid * 4] = ov;
    }
}

// ---------------------------------------------------------------------------
// Final LayerNorm: bf16 src -> f32 flat dst.
// ---------------------------------------------------------------------------
__global__ void lnf_k(const u16* __restrict__ src, const float* __restrict__ g,
                      const float* __restrict__ be, float* __restrict__ dst)
{
    __shared__ float red[8];
    const int row = blockIdx.x;
    const int tid = threadIdx.x;
    const int lane = tid & 63, wave = tid >> 6;
    ushort4 v = *(const ushort4*)&src[(size_t)row * 1024 + tid * 4];
    float f[4] = { b2f(v.x), b2f(v.y), b2f(v.z), b2f(v.w) };
    float s  = f[0] + f[1] + f[2] + f[3];
    float ss = f[0]*f[0] + f[1]*f[1] + f[2]*f[2] + f[3]*f[3];
#pragma unroll
    for (int off = 32; off; off >>= 1) { s += __shfl_down(s, off); ss += __shfl_down(ss, off); }
    if (lane == 0) { red[wave] = s; red[4 + wave] = ss; }
    __syncthreads();
    s  = red[0] + red[1] + red[2] + red[3];
    ss = red[4] + red[5] + red[6] + red[7];
    const float mean = s * (1.0f / 1024.0f);
    const float var  = fmaxf(ss * (1.0f / 1024.0f) - mean * mean, 0.0f);
    const float rs   = rsqrtf(var + 1e-5f);
    float4 ov;
    ov.x = (f[0] - mean) * rs * g[tid*4+0] + be[tid*4+0];
    ov.y = (f[1] - mean) * rs * g[tid*4+1] + be[tid*4+1];
    ov.z = (f[2] - mean) * rs * g[tid*4+2] + be[tid*4+2];
    ov.w = (f[3] - mean) * rs * g[tid*4+3] + be[tid*4+3];
    *(float4*)&dst[(size_t)row * 1024 + tid * 4] = ov;
}

// ---------------------------------------------------------------------------
// V transpose + PV-slot permutation:
// Vf f32 [bh][s][64] -> Vt bf16 [bh][64(hd)][2048(s-permuted)].
// Within each 32-kv block, kv = 16a+4b+c stored at slot 8b+4a+c.
// ---------------------------------------------------------------------------
__global__ void vtr_k(const float* __restrict__ Vf, u16* __restrict__ Vt)
{
    __shared__ float T[64 * 65];
    const int bh = blockIdx.x >> 5, st = blockIdx.x & 31;
    const int tid = threadIdx.x;
    const float* src = Vf + (size_t)bh * 2048 * 64 + (size_t)st * 64 * 64;
#pragma unroll
    for (int it = 0; it < 4; ++it) {
        const int fid = tid + it * 256;
        const int r = fid >> 4, c4 = fid & 15;
        float4 v = *(const float4*)&src[r * 64 + c4 * 4];
        T[r * 65 + c4*4 + 0] = v.x;
        T[r * 65 + c4*4 + 1] = v.y;
        T[r * 65 + c4*4 + 2] = v.z;
        T[r * 65 + c4*4 + 3] = v.w;
    }
    __syncthreads();
    u16* dst = Vt + (size_t)bh * 64 * 2048 + (size_t)st * 64;
#pragma unroll
    for (int it = 0; it < 2; ++it) {
        const int oid = tid + it * 256;
        const int hd = oid >> 3, ch = oid & 7;     // ch: source kv chunk of 8
        u16 tmp[8];
#pragma unroll
        for (int j = 0; j < 8; ++j) tmp[j] = f2b(T[(ch * 8 + j) * 65 + hd]);
        const int base = 32 * (ch >> 2) + 4 * ((ch >> 1) & 1);
        const int p0 = base + 8 * ((2 * ch + 0) & 3);
        const int p1 = base + 8 * ((2 * ch + 1) & 3);
        ushort4 lo = { tmp[0], tmp[1], tmp[2], tmp[3] };
        ushort4 hi = { tmp[4], tmp[5], tmp[6], tmp[7] };
        *(ushort4*)&dst[(size_t)hd * 2048 + p0] = lo;
        *(ushort4*)&dst[(size_t)hd * 2048 + p1] = hi;
    }
}

// ---------------------------------------------------------------------------
// Causal flash attention, swapped-QK / in-register-P, 3-buffer depth-2
// pipeline with counted vmcnt (T3/T4): stage tile kv+2 at top of iter kv,
// raw s_barrier + vmcnt(2) at iter end (vmcnt(0) only in the 2 drain iters).
// QBLK=128 (8 waves x 16 q-rows), KVBLK=64, LDS 48 KB -> 3 blocks/CU.
// ---------------------------------------------------------------------------
__global__ __launch_bounds__(512, 4)
void attn_k(const u16* __restrict__ Qf, const u16* __restrict__ Kf,
            const u16* __restrict__ Vt, u16* __restrict__ O)
{
    __shared__ u16 Lds[24576];        // 3 bufs x (K 8KB | V 8KB) = 48 KB
    const int lin = (int)blockIdx.x + (int)blockIdx.y * 16;
    const int xcd = lin & 7, idx = lin >> 3;
    const int bh  = xcd * 8 + (idx & 7);
    const int qt  = 15 - (idx >> 3);          // big tiles dispatch first
    const int b = bh >> 4, h = bh & 15;
    const int tid = threadIdx.x, wave = tid >> 6, lane = tid & 63;
    const int lg = lane >> 4, lr = lane & 15;
    const u16* Qbh = Qf + ((size_t)b * 2048) * 1024 + h * 64;
    const u16* Kbh = Kf + ((size_t)b * 2048) * 1024 + h * 64;
    const u16* Vbh = Vt + (size_t)bh * 64 * 2048;     // [hd][s-perm]
    u16* Obh = O + ((size_t)b * 2048) * 1024 + h * 64;

    const int q0w  = qt * 128 + wave * 16;
    const int qrow = q0w + lr;
    const short8 qf0 = *(const short8*)&Qbh[(size_t)qrow * 1024 + lg * 8];
    const short8 qf1 = *(const short8*)&Qbh[(size_t)qrow * 1024 + 32 + lg * 8];

    const int nkv    = 2 * qt + 2;            // always >= 2
    const int diagkv = q0w >> 6;

    // hoisted per-lane LDS byte offsets (K at +0, V at +8192 within a buffer)
    const int kro0 = swz(lr, lg * 8) * 2;
    const int kro1 = swz(lr, 32 + lg * 8) * 2;
    const int vro0 = 8192 + kro0;
    const int vro1 = 8192 + kro1;
    const char* ldsB = (const char*)Lds;

    const int sr = tid >> 3;
    const int sc8 = ((tid & 7) ^ (sr & 7)) * 8;
    const u16* kg = Kbh + (size_t)sr * 1024 + sc8;
    const u16* vg = Vbh + (size_t)sr * 2048 + sc8;
    const int stKo = wave * 1024;

    f32x4 oacc[4] = {};
    float l_r = 0.f, m_r = -1e30f;

    // ---- prologue: stage tiles 0 and 1 into bufs 0,1 (4 loads in flight) ----
    gload16(kg,          (char*)Lds + stKo);
    gload16(vg,          (char*)Lds + 8192 + stKo);
    gload16(kg + 65536,  (char*)Lds + 16384 + stKo);
    gload16(vg + 64,     (char*)Lds + 16384 + 8192 + stKo);
    kg += 131072; vg += 128;
    VMCNT2;                                   // tile 0 landed; tile 1 in flight
    __builtin_amdgcn_s_barrier();

    int ro = 0;                               // read-buffer byte offset
    for (int kv = 0; kv < nkv; ++kv) {
        const bool doStage = (kv + 2 < nkv);
        if (doStage) {
            int so = ro + 32768; if (so >= 49152) so -= 49152;
            gload16(kg, (char*)Lds + so + stKo);
            gload16(vg, (char*)Lds + so + 8192 + stKo);
            kg += 65536; vg += 64;
        }

        if (kv <= diagkv) {
            const char* kp0 = ldsB + (ro + kro0);
            const char* kp1 = ldsB + (ro + kro1);

            // S^T = K Q: sacc[c][r]: q=lr, kv = kv*64 + c*16 + 4*lg + r
            f32x4 sacc[4];
            __builtin_amdgcn_s_setprio(1);
#pragma unroll
            for (int c = 0; c < 4; ++c) {
                const short8 k0 = *(const short8*)(kp0 + c * 2048);
                const short8 k1 = *(const short8*)(kp1 + c * 2048);
                f32x4 z = { 0.f, 0.f, 0.f, 0.f };
                z = __builtin_amdgcn_mfma_f32_16x16x32_bf16(k0, qf0, z, 0, 0, 0);
                z = __builtin_amdgcn_mfma_f32_16x16x32_bf16(k1, qf1, z, 0, 0, 0);
                sacc[c] = z;
            }
            __builtin_amdgcn_s_setprio(0);

            if (kv == diagkv) {               // causal mask, diagonal tile only
                const int kbase = kv * 64 + 4 * lg;
#pragma unroll
                for (int c = 0; c < 4; ++c)
#pragma unroll
                    for (int r = 0; r < 4; ++r)
                        if (kbase + c * 16 + r > qrow) sacc[c][r] = -1e30f;
            }

            // per-lane max (max3 trees) + cross-half combine
            float t0 = fmaxf(fmaxf(sacc[0][0], sacc[0][1]), sacc[0][2]);
            float t1 = fmaxf(fmaxf(sacc[0][3], sacc[1][0]), sacc[1][1]);
            float t2 = fmaxf(fmaxf(sacc[1][2], sacc[1][3]), sacc[2][0]);
            float t3 = fmaxf(fmaxf(sacc[2][1], sacc[2][2]), sacc[2][3]);
            float t4 = fmaxf(fmaxf(sacc[3][0], sacc[3][1]), sacc[3][2]);
            float mx = fmaxf(fmaxf(fmaxf(t0, t1), fmaxf(t2, t3)),
                             fmaxf(t4, sacc[3][3]));
            mx = fmaxf(mx, __shfl_xor(mx, 16));
            mx = fmaxf(mx, __shfl_xor(mx, 32));

            const float df = mx - m_r;
            if (__any(df > 8.0f)) {           // defer-max rescale
                const float mn = (df > 8.0f) ? mx : m_r;
                const float al = exp2f(m_r - mn);
                m_r = mn;
                l_r *= al;
#pragma unroll
                for (int r = 0; r < 4; ++r) {
                    const float alo = __shfl(al, 4 * lg + r);
#pragma unroll
                    for (int c2 = 0; c2 < 4; ++c2) oacc[c2][r] *= alo;
                }
            }

            // P = exp2(S - m); pairwise sum tree
#pragma unroll
            for (int c = 0; c < 4; ++c)
#pragma unroll
                for (int r = 0; r < 4; ++r) sacc[c][r] = exp2f(sacc[c][r] - m_r);
            {
                float s0 = (sacc[0][0] + sacc[0][1]) + (sacc[0][2] + sacc[0][3]);
                float s1 = (sacc[1][0] + sacc[1][1]) + (sacc[1][2] + sacc[1][3]);
                float s2 = (sacc[2][0] + sacc[2][1]) + (sacc[2][2] + sacc[2][3]);
                float s3 = (sacc[3][0] + sacc[3][1]) + (sacc[3][2] + sacc[3][3]);
                float ts = (s0 + s1) + (s2 + s3);
                ts += __shfl_xor(ts, 16);
                ts += __shfl_xor(ts, 32);
                l_r += ts;
            }

            // PV: pack P via v_perm, in-register A-frags (V pre-permuted)
            const char* vp0 = ldsB + (ro + vro0);
            const char* vp1 = ldsB + (ro + vro1);
#pragma unroll
            for (int m2 = 0; m2 < 2; ++m2) {
                union { unsigned w[4]; short8 v; } pa;
                pa.w[0] = pk2(sacc[2*m2][0],   sacc[2*m2][1]);
                pa.w[1] = pk2(sacc[2*m2][2],   sacc[2*m2][3]);
                pa.w[2] = pk2(sacc[2*m2+1][0], sacc[2*m2+1][1]);
                pa.w[3] = pk2(sacc[2*m2+1][2], sacc[2*m2+1][3]);
                const char* vp = m2 ? vp1 : vp0;
                __builtin_amdgcn_s_setprio(1);
#pragma unroll
                for (int c2 = 0; c2 < 4; ++c2) {
                    const short8 vb = *(const short8*)(vp + c2 * 2048);
                    oacc[c2] = __builtin_amdgcn_mfma_f32_16x16x32_bf16(pa.v, vb, oacc[c2], 0, 0, 0);
                }
                __builtin_amdgcn_s_setprio(0);
            }
        }

        if (kv + 1 < nkv) {
            if (doStage) { VMCNT2; }          // steady state: keep 2 in flight
            else        { VMCNT0; }           // drain iterations
            __builtin_amdgcn_s_barrier();
        }
        ro += 16384; if (ro == 49152) ro = 0;
    }

    // ---- epilogue ----
    float lo[4];
#pragma unroll
    for (int r = 0; r < 4; ++r) lo[r] = 1.0f / __shfl(l_r, 4 * lg + r);
#pragma unroll
    for (int c2 = 0; c2 < 4; ++c2)
#pragma unroll
        for (int r = 0; r < 4; ++r) {
            const float ov = oacc[c2][r] * lo[r];
            Obh[(size_t)(q0w + 4 * lg + r) * 1024 + c2 * 16 + lr] = f2b(ov);
        }
}

// ---------------------------------------------------------------------------
// Memory plan (f32 I/O):
//   d_out bytes: [0,16.78M) D0 = Q bf16 -> attnout bf16 (in-place)
//                [16.78,33.55M) D1 = K bf16
//                [33.55,50.33M) xb bf16 (dead before lnV writes Vf)
//                [33.55,67.1M)  Vf f32 final V output
//                [0,33.55M)     outF f32 final out (written last)
//   ws (25.2MB): S0 = preLN-V bf16 -> Vt bf16 -> gemmP-out bf16; weights after.
// ---------------------------------------------------------------------------
extern "C" void kernel_launch(void* const* d_in, const int* in_sizes, int n_in,
                              void* d_out, int out_size, void* d_ws, size_t ws_size,
                              hipStream_t stream)
{
    (void)in_sizes; (void)n_in; (void)out_size; (void)ws_size;
    const float* x   = (const float*)d_in[0];
    const float* wq  = (const float*)d_in[1];  const float* bq   = (const float*)d_in[2];
    const float* wk  = (const float*)d_in[3];  const float* bk   = (const float*)d_in[4];
    const float* wv  = (const float*)d_in[5];  const float* bv   = (const float*)d_in[6];
    const float* wp  = (const float*)d_in[7];  const float* bp   = (const float*)d_in[8];
    const float* g_q = (const float*)d_in[9];  const float* be_q = (const float*)d_in[10];
    const float* g_k = (const float*)d_in[11]; const float* be_k = (const float*)d_in[12];
    const float* g_v = (const float*)d_in[13]; const float* be_v = (const float*)d_in[14];
    const float* g_p = (const float*)d_in[15]; const float* be_p = (const float*)d_in[16];

    float* outF = (float*)d_out;
    float* Vf   = outF + 8388608;
    u16* D0 = (u16*)d_out;                  // Q bf16 -> attnout
    u16* D1 = (u16*)d_out + 8388608;        // K bf16
    u16* xb = (u16*)d_out + 16777216;       // x bf16 (dead before Vf written)
    char* ws = (char*)d_ws;
    u16* S0  = (u16*)ws;                    // preLN-V -> Vt -> gemmP out
    u16* wb  = (u16*)(ws + 16777216);       // 4 bf16 weight matrices contiguous
    u16* wpb = wb + 3145728;

    const dim3 bb(256);
    cvtall_k<<<dim3(12288), bb, 0, stream>>>(x, wq, wk, wv, wp, xb, wb);

    gemm3_k<<<dim3(64, 24), bb, 0, stream>>>(xb, wb, bq, bk, bv, D0, D1, S0);
    ln3_k<<<dim3(8192, 3), bb, 0, stream>>>(D0, D1, S0, g_q, be_q, g_k, be_k, g_v, be_v, Vf);
    vtr_k<<<dim3(2048), bb, 0, stream>>>(Vf, S0);                      // permuted Vt over S0
    attn_k<<<dim3(16, 64), dim3(512), 0, stream>>>(D0, D1, S0, D0);    // out over Q
    gemm_k<<<dim3(64, 8), bb, 0, stream>>>(D0, wpb, bp, S0, 8192, 1024, 1024);
    lnf_k<<<dim3(8192), bb, 0, stream>>>(S0, g_p, be_p, outF);
}

// Round 11
// 181.369 us; speedup vs baseline: 3.2365x; 1.0702x over previous
//
#include <hip/hip_runtime.h>
#include <hip/hip_bf16.h>

// B=4, S=2048, E=1024, H=16, HD=64. d_in/d_out are FLOAT32; compute in bf16 MFMA.
typedef unsigned short u16;
typedef __attribute__((ext_vector_type(8))) short short8;   // 8 bf16 (MFMA A/B frag)
typedef __attribute__((ext_vector_type(4))) float f32x4;    // MFMA C/D frag

#define VMCNT2 asm volatile("s_waitcnt vmcnt(2)" ::: "memory")
#define VMCNT0 asm volatile("s_waitcnt vmcnt(0)" ::: "memory")

__device__ __forceinline__ float b2f(u16 u){
    unsigned v = ((unsigned)u) << 16; float f; __builtin_memcpy(&f, &v, 4); return f;
}
__device__ __forceinline__ u16 f2b(float f){          // RNE
    unsigned v; __builtin_memcpy(&v, &f, 4);
    v += 0x7fffu + ((v >> 16) & 1u);
    return (u16)(v >> 16);
}
// pack two f32 -> one u32 of two bf16 (round-half-up), 3 VALU ops
__device__ __forceinline__ unsigned pk2(float lo, float hi){
    unsigned a, b; __builtin_memcpy(&a, &lo, 4); __builtin_memcpy(&b, &hi, 4);
    return __builtin_amdgcn_perm(b + 0x8000u, a + 0x8000u, 0x07060302u);
}
// raw 2^x (args <= 0 here; masked -1e30 -> 0). libm exp2f adds ~10 insts of
// edge handling we don't need -- this was ~1/3 of attn's VALU.
__device__ __forceinline__ float ex2(float x){
    float r; asm("v_exp_f32 %0, %1" : "=v"(r) : "v"(x)); return r;
}
__device__ __forceinline__ float rcp(float x){
    float r; asm("v_rcp_f32 %0, %1" : "=v"(r) : "v"(x)); return r;
}

__device__ __forceinline__ void gload16(const void* g, void* l){
    __builtin_amdgcn_global_load_lds((const __attribute__((address_space(1))) unsigned int*)g,
                                     (__attribute__((address_space(3))) unsigned int*)l, 16, 0, 0);
}

// XOR bank swizzle for 64-u16-wide LDS rows (row stride 128B).
__device__ __forceinline__ int swz(int row, int col){
    return row * 64 + (col ^ ((row & 7) << 3));
}

// ---------------------------------------------------------------------------
// Fused f32->bf16 convert: x (8192 rows) + 4 weight matrices (4096 rows).
// ---------------------------------------------------------------------------
__global__ void cvtall_k(const float* __restrict__ x,
                         const float* __restrict__ wq, const float* __restrict__ wk,
                         const float* __restrict__ wv, const float* __restrict__ wp,
                         u16* __restrict__ xb, u16* __restrict__ wb)
{
    const int blk = blockIdx.x;
    const float* src; u16* dst;
    if (blk < 8192) {
        src = x + (size_t)blk * 1024; dst = xb + (size_t)blk * 1024;
    } else {
        const int m = (blk - 8192) >> 10, r = (blk - 8192) & 1023;
        const float* w = (m == 0) ? wq : (m == 1) ? wk : (m == 2) ? wv : wp;
        src = w + (size_t)r * 1024; dst = wb + ((size_t)m << 20) + (size_t)r * 1024;
    }
    const int i = threadIdx.x * 4;
    float4 v = *(const float4*)&src[i];
    ushort4 o;
    o.x = f2b(v.x); o.y = f2b(v.y); o.z = f2b(v.z); o.w = f2b(v.w);
    *(ushort4*)&dst[i] = o;
}

// ---------------------------------------------------------------------------
// Fused Q/K/V GEMM, BK=64, XOR-swizzled LDS, pre-swizzled-source staging.
// ---------------------------------------------------------------------------
__global__ __launch_bounds__(256, 2)
void gemm3_k(const u16* __restrict__ A, const u16* __restrict__ Wb,
             const float* __restrict__ b0, const float* __restrict__ b1,
             const float* __restrict__ b2,
             u16* __restrict__ C0, u16* __restrict__ C1, u16* __restrict__ C2)
{
    __shared__ u16 As[128 * 64];   // 16 KB
    __shared__ u16 Bs[128 * 64];   // 16 KB
    const int K = 1024, N = 1024;
    const int mat = blockIdx.y >> 3;
    const int n0  = (blockIdx.y & 7) * 128;
    const u16* W = Wb + ((size_t)mat << 20);
    const float* bias = (mat == 0) ? b0 : (mat == 1) ? b1 : b2;
    u16* C = (mat == 0) ? C0 : (mat == 1) ? C1 : C2;

    const int tid  = threadIdx.x;
    const int wave = tid >> 6, lane = tid & 63;
    const int lg = lane >> 4, lr = lane & 15;
    const int m0 = blockIdx.x * 128;
    const int wm = (wave >> 1) * 64, wn = (wave & 1) * 64;

    const int srow = tid >> 3;
    const int sc8  = ((tid & 7) ^ (srow & 7)) * 8;
    const u16* aG = A + (size_t)(m0 + srow) * K + sc8;
    const u16* bG = W + (size_t)(n0 + srow) * K + sc8;
    char* asBase = (char*)As + wave * 1024;
    char* bsBase = (char*)Bs + wave * 1024;
    const size_t rstep = (size_t)32 * K;

    f32x4 acc[4][4] = {};

    for (int kt = 0; kt < K; kt += 64) {
#pragma unroll
        for (int i = 0; i < 4; ++i) {
            gload16(aG + kt + i * rstep, asBase + i * 4096);
            gload16(bG + kt + i * rstep, bsBase + i * 4096);
        }
        __syncthreads();

#pragma unroll
        for (int s = 0; s < 2; ++s) {
            short8 a[4], b[4];
#pragma unroll
            for (int i = 0; i < 4; ++i) a[i] = *(const short8*)&As[swz(wm + i*16 + lr, s*32 + lg*8)];
#pragma unroll
            for (int j = 0; j < 4; ++j) b[j] = *(const short8*)&Bs[swz(wn + j*16 + lr, s*32 + lg*8)];
            __builtin_amdgcn_s_setprio(1);
#pragma unroll
            for (int i = 0; i < 4; ++i)
#pragma unroll
                for (int j = 0; j < 4; ++j)
                    acc[i][j] = __builtin_amdgcn_mfma_f32_16x16x32_bf16(a[i], b[j], acc[i][j], 0, 0, 0);
            __builtin_amdgcn_s_setprio(0);
        }
        __syncthreads();
    }

#pragma unroll
    for (int j = 0; j < 4; ++j) {
        const int cn = n0 + wn + j*16 + lr;
        const float bv = bias[cn];
#pragma unroll
        for (int i = 0; i < 4; ++i) {
            const int cm = m0 + wm + i*16 + lg*4;
#pragma unroll
            for (int r = 0; r < 4; ++r)
                C[(size_t)(cm + r) * N + cn] = f2b(acc[i][j][r] + bv);
        }
    }
}

// ---------------------------------------------------------------------------
// Single-matrix GEMM (out-projection), BK=64.
// ---------------------------------------------------------------------------
__global__ __launch_bounds__(256, 2)
void gemm_k(const u16* __restrict__ A, const u16* __restrict__ W,
            const float* __restrict__ bias, u16* __restrict__ C,
            int M, int N, int K)
{
    __shared__ u16 As[128 * 64];
    __shared__ u16 Bs[128 * 64];
    const int tid  = threadIdx.x;
    const int wave = tid >> 6, lane = tid & 63;
    const int lg = lane >> 4, lr = lane & 15;
    const int m0 = blockIdx.x * 128, n0 = blockIdx.y * 128;
    const int wm = (wave >> 1) * 64, wn = (wave & 1) * 64;

    const int srow = tid >> 3;
    const int sc8  = ((tid & 7) ^ (srow & 7)) * 8;
    const u16* aG = A + (size_t)(m0 + srow) * K + sc8;
    const u16* bG = W + (size_t)(n0 + srow) * K + sc8;
    char* asBase = (char*)As + wave * 1024;
    char* bsBase = (char*)Bs + wave * 1024;
    const size_t rstep = (size_t)32 * K;

    f32x4 acc[4][4] = {};

    for (int kt = 0; kt < K; kt += 64) {
#pragma unroll
        for (int i = 0; i < 4; ++i) {
            gload16(aG + kt + i * rstep, asBase + i * 4096);
            gload16(bG + kt + i * rstep, bsBase + i * 4096);
        }
        __syncthreads();

#pragma unroll
        for (int s = 0; s < 2; ++s) {
            short8 a[4], b[4];
#pragma unroll
            for (int i = 0; i < 4; ++i) a[i] = *(const short8*)&As[swz(wm + i*16 + lr, s*32 + lg*8)];
#pragma unroll
            for (int j = 0; j < 4; ++j) b[j] = *(const short8*)&Bs[swz(wn + j*16 + lr, s*32 + lg*8)];
            __builtin_amdgcn_s_setprio(1);
#pragma unroll
            for (int i = 0; i < 4; ++i)
#pragma unroll
                for (int j = 0; j < 4; ++j)
                    acc[i][j] = __builtin_amdgcn_mfma_f32_16x16x32_bf16(a[i], b[j], acc[i][j], 0, 0, 0);
            __builtin_amdgcn_s_setprio(0);
        }
        __syncthreads();
    }

#pragma unroll
    for (int j = 0; j < 4; ++j) {
        const int cn = n0 + wn + j*16 + lr;
        const float bv = bias[cn];
#pragma unroll
        for (int i = 0; i < 4; ++i) {
            const int cm = m0 + wm + i*16 + lg*4;
#pragma unroll
            for (int r = 0; r < 4; ++r)
                C[(size_t)(cm + r) * N + cn] = f2b(acc[i][j][r] + bv);
        }
    }
}

// ---------------------------------------------------------------------------
// Fused Q/K/V LayerNorm. grid (8192, 3).
// ---------------------------------------------------------------------------
__global__ void ln3_k(u16* D0, u16* D1, const u16* __restrict__ Sv,
                      const float* __restrict__ g_q, const float* __restrict__ be_q,
                      const float* __restrict__ g_k, const float* __restrict__ be_k,
                      const float* __restrict__ g_v, const float* __restrict__ be_v,
                      float* __restrict__ Vf)
{
    __shared__ float red[8];
    const int which = blockIdx.y;
    const u16* src = (which == 0) ? D0 : (which == 1) ? D1 : Sv;
    const float* g  = (which == 0) ? g_q  : (which == 1) ? g_k  : g_v;
    const float* be = (which == 0) ? be_q : (which == 1) ? be_k : be_v;
    const float scale = (which == 0) ? 0.125f * 1.4426950408889634f : 1.0f;

    const int row = blockIdx.x;
    const int tid = threadIdx.x;
    const int lane = tid & 63, wave = tid >> 6;
    ushort4 v = *(const ushort4*)&src[(size_t)row * 1024 + tid * 4];
    float f[4] = { b2f(v.x), b2f(v.y), b2f(v.z), b2f(v.w) };
    float s  = f[0] + f[1] + f[2] + f[3];
    float ss = f[0]*f[0] + f[1]*f[1] + f[2]*f[2] + f[3]*f[3];
#pragma unroll
    for (int off = 32; off; off >>= 1) { s += __shfl_down(s, off); ss += __shfl_down(ss, off); }
    if (lane == 0) { red[wave] = s; red[4 + wave] = ss; }
    __syncthreads();
    s  = red[0] + red[1] + red[2] + red[3];
    ss = red[4] + red[5] + red[6] + red[7];
    const float mean = s * (1.0f / 1024.0f);
    const float var  = fmaxf(ss * (1.0f / 1024.0f) - mean * mean, 0.0f);
    const float rs   = rsqrtf(var + 1e-5f);
    float o[4];
#pragma unroll
    for (int k = 0; k < 4; ++k) {
        const int e = tid * 4 + k;
        o[k] = ((f[k] - mean) * rs * g[e] + be[e]) * scale;
    }
    if (which == 2) {
        const int b = row >> 11, sIdx = row & 2047;
        const int h = tid >> 4, hd = (tid * 4) & 63;
        float4 ov = { o[0], o[1], o[2], o[3] };
        *(float4*)&Vf[(((size_t)(b * 16 + h) * 2048 + sIdx) << 6) + hd] = ov;
    } else {
        u16* dst = (which == 0) ? D0 : D1;
        ushort4 ov; ov.x = f2b(o[0]); ov.y = f2b(o[1]); ov.z = f2b(o[2]); ov.w = f2b(o[3]);
        *(ushort4*)&dst[(size_t)row * 1024 + tid * 4] = ov;
    }
}

// ---------------------------------------------------------------------------
// Final LayerNorm: bf16 src -> f32 flat dst.
// ---------------------------------------------------------------------------
__global__ void lnf_k(const u16* __restrict__ src, const float* __restrict__ g,
                      const float* __restrict__ be, float* __restrict__ dst)
{
    __shared__ float red[8];
    const int row = blockIdx.x;
    const int tid = threadIdx.x;
    const int lane = tid & 63, wave = tid >> 6;
    ushort4 v = *(const ushort4*)&src[(size_t)row * 1024 + tid * 4];
    float f[4] = { b2f(v.x), b2f(v.y), b2f(v.z), b2f(v.w) };
    float s  = f[0] + f[1] + f[2] + f[3];
    float ss = f[0]*f[0] + f[1]*f[1] + f[2]*f[2] + f[3]*f[3];
#pragma unroll
    for (int off = 32; off; off >>= 1) { s += __shfl_down(s, off); ss += __shfl_down(ss, off); }
    if (lane == 0) { red[wave] = s; red[4 + wave] = ss; }
    __syncthreads();
    s  = red[0] + red[1] + red[2] + red[3];
    ss = red[4] + red[5] + red[6] + red[7];
    const float mean = s * (1.0f / 1024.0f);
    const float var  = fmaxf(ss * (1.0f / 1024.0f) - mean * mean, 0.0f);
    const float rs   = rsqrtf(var + 1e-5f);
    float4 ov;
    ov.x = (f[0] - mean) * rs * g[tid*4+0] + be[tid*4+0];
    ov.y = (f[1] - mean) * rs * g[tid*4+1] + be[tid*4+1];
    ov.z = (f[2] - mean) * rs * g[tid*4+2] + be[tid*4+2];
    ov.w = (f[3] - mean) * rs * g[tid*4+3] + be[tid*4+3];
    *(float4*)&dst[(size_t)row * 1024 + tid * 4] = ov;
}

// ---------------------------------------------------------------------------
// V transpose + PV-slot permutation:
// Vf f32 [bh][s][64] -> Vt bf16 [bh][64(hd)][2048(s-permuted)].
// Within each 32-kv block, kv = 16a+4b+c stored at slot 8b+4a+c.
// ---------------------------------------------------------------------------
__global__ void vtr_k(const float* __restrict__ Vf, u16* __restrict__ Vt)
{
    __shared__ float T[64 * 65];
    const int bh = blockIdx.x >> 5, st = blockIdx.x & 31;
    const int tid = threadIdx.x;
    const float* src = Vf + (size_t)bh * 2048 * 64 + (size_t)st * 64 * 64;
#pragma unroll
    for (int it = 0; it < 4; ++it) {
        const int fid = tid + it * 256;
        const int r = fid >> 4, c4 = fid & 15;
        float4 v = *(const float4*)&src[r * 64 + c4 * 4];
        T[r * 65 + c4*4 + 0] = v.x;
        T[r * 65 + c4*4 + 1] = v.y;
        T[r * 65 + c4*4 + 2] = v.z;
        T[r * 65 + c4*4 + 3] = v.w;
    }
    __syncthreads();
    u16* dst = Vt + (size_t)bh * 64 * 2048 + (size_t)st * 64;
#pragma unroll
    for (int it = 0; it < 2; ++it) {
        const int oid = tid + it * 256;
        const int hd = oid >> 3, ch = oid & 7;     // ch: source kv chunk of 8
        u16 tmp[8];
#pragma unroll
        for (int j = 0; j < 8; ++j) tmp[j] = f2b(T[(ch * 8 + j) * 65 + hd]);
        const int base = 32 * (ch >> 2) + 4 * ((ch >> 1) & 1);
        const int p0 = base + 8 * ((2 * ch + 0) & 3);
        const int p1 = base + 8 * ((2 * ch + 1) & 3);
        ushort4 lo = { tmp[0], tmp[1], tmp[2], tmp[3] };
        ushort4 hi = { tmp[4], tmp[5], tmp[6], tmp[7] };
        *(ushort4*)&dst[(size_t)hd * 2048 + p0] = lo;
        *(ushort4*)&dst[(size_t)hd * 2048 + p1] = hi;
    }
}

// ---------------------------------------------------------------------------
// Causal flash attention, swapped-QK / in-register-P, 3-buffer depth-2
// pipeline with counted vmcnt. VALU-lean: raw v_exp_f32 (no libm), row-sum l
// via ones-MFMA on the idle matrix pipe (lacc[r] lands in oacc's row domain,
// no epilogue shfl), v_rcp epilogue. QBLK=128, KVBLK=64, LDS 48 KB.
// ---------------------------------------------------------------------------
__global__ __launch_bounds__(512, 4)
void attn_k(const u16* __restrict__ Qf, const u16* __restrict__ Kf,
            const u16* __restrict__ Vt, u16* __restrict__ O)
{
    __shared__ u16 Lds[24576];        // 3 bufs x (K 8KB | V 8KB) = 48 KB
    const int lin = (int)blockIdx.x + (int)blockIdx.y * 16;
    const int xcd = lin & 7, idx = lin >> 3;
    const int bh  = xcd * 8 + (idx & 7);
    const int qt  = 15 - (idx >> 3);          // big tiles dispatch first
    const int b = bh >> 4, h = bh & 15;
    const int tid = threadIdx.x, wave = tid >> 6, lane = tid & 63;
    const int lg = lane >> 4, lr = lane & 15;
    const u16* Qbh = Qf + ((size_t)b * 2048) * 1024 + h * 64;
    const u16* Kbh = Kf + ((size_t)b * 2048) * 1024 + h * 64;
    const u16* Vbh = Vt + (size_t)bh * 64 * 2048;     // [hd][s-perm]
    u16* Obh = O + ((size_t)b * 2048) * 1024 + h * 64;

    const int q0w  = qt * 128 + wave * 16;
    const int qrow = q0w + lr;
    const short8 qf0 = *(const short8*)&Qbh[(size_t)qrow * 1024 + lg * 8];
    const short8 qf1 = *(const short8*)&Qbh[(size_t)qrow * 1024 + 32 + lg * 8];

    const int nkv    = 2 * qt + 2;
    const int diagkv = q0w >> 6;

    const int kro0 = swz(lr, lg * 8) * 2;
    const int kro1 = swz(lr, 32 + lg * 8) * 2;
    const int vro0 = 8192 + kro0;
    const int vro1 = 8192 + kro1;
    const char* ldsB = (const char*)Lds;

    const int sr = tid >> 3;
    const int sc8 = ((tid & 7) ^ (sr & 7)) * 8;
    const u16* kg = Kbh + (size_t)sr * 1024 + sc8;
    const u16* vg = Vbh + (size_t)sr * 2048 + sc8;
    const int stKo = wave * 1024;

    const short s1 = (short)0x3F80;
    const short8 ones = { s1,s1,s1,s1,s1,s1,s1,s1 };

    f32x4 oacc[4] = {};                       // col=lr=hd-frag, row q=4*lg+r
    f32x4 lacc = { 0.f, 0.f, 0.f, 0.f };      // row sums (all cols equal)
    float m_r = -1e30f;                       // per-lane (q=lr) running max

    // ---- prologue: stage tiles 0 and 1 into bufs 0,1 ----
    gload16(kg,          (char*)Lds + stKo);
    gload16(vg,          (char*)Lds + 8192 + stKo);
    gload16(kg + 65536,  (char*)Lds + 16384 + stKo);
    gload16(vg + 64,     (char*)Lds + 16384 + 8192 + stKo);
    kg += 131072; vg += 128;
    VMCNT2;
    __builtin_amdgcn_s_barrier();

    int ro = 0;
    for (int kv = 0; kv < nkv; ++kv) {
        const bool doStage = (kv + 2 < nkv);
        if (doStage) {
            int so = ro + 32768; if (so >= 49152) so -= 49152;
            gload16(kg, (char*)Lds + so + stKo);
            gload16(vg, (char*)Lds + so + 8192 + stKo);
            kg += 65536; vg += 64;
        }

        if (kv <= diagkv) {
            const char* kp0 = ldsB + (ro + kro0);
            const char* kp1 = ldsB + (ro + kro1);

            // S^T = K Q: sacc[c][r]: q=lr, kv = kv*64 + c*16 + 4*lg + r
            f32x4 sacc[4];
            __builtin_amdgcn_s_setprio(1);
#pragma unroll
            for (int c = 0; c < 4; ++c) {
                const short8 k0 = *(const short8*)(kp0 + c * 2048);
                const short8 k1 = *(const short8*)(kp1 + c * 2048);
                f32x4 z = { 0.f, 0.f, 0.f, 0.f };
                z = __builtin_amdgcn_mfma_f32_16x16x32_bf16(k0, qf0, z, 0, 0, 0);
                z = __builtin_amdgcn_mfma_f32_16x16x32_bf16(k1, qf1, z, 0, 0, 0);
                sacc[c] = z;
            }
            __builtin_amdgcn_s_setprio(0);

            if (kv == diagkv) {               // causal mask, diagonal tile only
                const int kbase = kv * 64 + 4 * lg;
#pragma unroll
                for (int c = 0; c < 4; ++c)
#pragma unroll
                    for (int r = 0; r < 4; ++r)
                        if (kbase + c * 16 + r > qrow) sacc[c][r] = -1e30f;
            }

            // per-lane max (max3 trees) + cross-half combine
            float t0 = fmaxf(fmaxf(sacc[0][0], sacc[0][1]), sacc[0][2]);
            float t1 = fmaxf(fmaxf(sacc[0][3], sacc[1][0]), sacc[1][1]);
            float t2 = fmaxf(fmaxf(sacc[1][2], sacc[1][3]), sacc[2][0]);
            float t3 = fmaxf(fmaxf(sacc[2][1], sacc[2][2]), sacc[2][3]);
            float t4 = fmaxf(fmaxf(sacc[3][0], sacc[3][1]), sacc[3][2]);
            float mx = fmaxf(fmaxf(fmaxf(t0, t1), fmaxf(t2, t3)),
                             fmaxf(t4, sacc[3][3]));
            mx = fmaxf(mx, __shfl_xor(mx, 16));
            mx = fmaxf(mx, __shfl_xor(mx, 32));

            const float df = mx - m_r;
            if (__any(df > 8.0f)) {           // defer-max rescale
                const float mn = (df > 8.0f) ? mx : m_r;
                const float al = ex2(m_r - mn);
                m_r = mn;
#pragma unroll
                for (int r = 0; r < 4; ++r) {
                    const float alo = __shfl(al, 4 * lg + r);
                    lacc[r] *= alo;
#pragma unroll
                    for (int c2 = 0; c2 < 4; ++c2) oacc[c2][r] *= alo;
                }
            }

            // P = exp2(S - m) via raw v_exp_f32
#pragma unroll
            for (int c = 0; c < 4; ++c)
#pragma unroll
                for (int r = 0; r < 4; ++r) sacc[c][r] = ex2(sacc[c][r] - m_r);

            // PV + ones-MFMA row sum (l on the matrix pipe; no sum tree)
            const char* vp0 = ldsB + (ro + vro0);
            const char* vp1 = ldsB + (ro + vro1);
#pragma unroll
            for (int m2 = 0; m2 < 2; ++m2) {
                union { unsigned w[4]; short8 v; } pa;
                pa.w[0] = pk2(sacc[2*m2][0],   sacc[2*m2][1]);
                pa.w[1] = pk2(sacc[2*m2][2],   sacc[2*m2][3]);
                pa.w[2] = pk2(sacc[2*m2+1][0], sacc[2*m2+1][1]);
                pa.w[3] = pk2(sacc[2*m2+1][2], sacc[2*m2+1][3]);
                const char* vp = m2 ? vp1 : vp0;
                __builtin_amdgcn_s_setprio(1);
                lacc = __builtin_amdgcn_mfma_f32_16x16x32_bf16(pa.v, ones, lacc, 0, 0, 0);
#pragma unroll
                for (int c2 = 0; c2 < 4; ++c2) {
                    const short8 vb = *(const short8*)(vp + c2 * 2048);
                    oacc[c2] = __builtin_amdgcn_mfma_f32_16x16x32_bf16(pa.v, vb, oacc[c2], 0, 0, 0);
                }
                __builtin_amdgcn_s_setprio(0);
            }
        }

        if (kv + 1 < nkv) {
            if (doStage) { VMCNT2; }          // steady state: keep 2 in flight
            else        { VMCNT0; }           // drain iterations
            __builtin_amdgcn_s_barrier();
        }
        ro += 16384; if (ro == 49152) ro = 0;
    }

    // ---- epilogue: lacc[r] is already this lane's row-q sum ----
    float lo[4];
#pragma unroll
    for (int r = 0; r < 4; ++r) lo[r] = rcp(lacc[r]);
#pragma unroll
    for (int c2 = 0; c2 < 4; ++c2)
#pragma unroll
        for (int r = 0; r < 4; ++r) {
            const float ov = oacc[c2][r] * lo[r];
            Obh[(size_t)(q0w + 4 * lg + r) * 1024 + c2 * 16 + lr] = f2b(ov);
        }
}

// ---------------------------------------------------------------------------
// Memory plan (f32 I/O):
//   d_out bytes: [0,16.78M) D0 = Q bf16 -> attnout bf16 (in-place)
//                [16.78,33.55M) D1 = K bf16
//                [33.55,50.33M) xb bf16 (dead before lnV writes Vf)
//                [33.55,67.1M)  Vf f32 final V output
//                [0,33.55M)     outF f32 final out (written last)
//   ws (25.2MB): S0 = preLN-V bf16 -> Vt bf16 -> gemmP-out bf16; weights after.
// ---------------------------------------------------------------------------
extern "C" void kernel_launch(void* const* d_in, const int* in_sizes, int n_in,
                              void* d_out, int out_size, void* d_ws, size_t ws_size,
                              hipStream_t stream)
{
    (void)in_sizes; (void)n_in; (void)out_size; (void)ws_size;
    const float* x   = (const float*)d_in[0];
    const float* wq  = (const float*)d_in[1];  const float* bq   = (const float*)d_in[2];
    const float* wk  = (const float*)d_in[3];  const float* bk   = (const float*)d_in[4];
    const float* wv  = (const float*)d_in[5];  const float* bv   = (const float*)d_in[6];
    const float* wp  = (const float*)d_in[7];  const float* bp   = (const float*)d_in[8];
    const float* g_q = (const float*)d_in[9];  const float* be_q = (const float*)d_in[10];
    const float* g_k = (const float*)d_in[11]; const float* be_k = (const float*)d_in[12];
    const float* g_v = (const float*)d_in[13]; const float* be_v = (const float*)d_in[14];
    const float* g_p = (const float*)d_in[15]; const float* be_p = (const float*)d_in[16];

    float* outF = (float*)d_out;
    float* Vf   = outF + 8388608;
    u16* D0 = (u16*)d_out;                  // Q bf16 -> attnout
    u16* D1 = (u16*)d_out + 8388608;        // K bf16
    u16* xb = (u16*)d_out + 16777216;       // x bf16 (dead before Vf written)
    char* ws = (char*)d_ws;
    u16* S0  = (u16*)ws;                    // preLN-V -> Vt -> gemmP out
    u16* wb  = (u16*)(ws + 16777216);       // 4 bf16 weight matrices contiguous
    u16* wpb = wb + 3145728;

    const dim3 bb(256);
    cvtall_k<<<dim3(12288), bb, 0, stream>>>(x, wq, wk, wv, wp, xb, wb);

    gemm3_k<<<dim3(64, 24), bb, 0, stream>>>(xb, wb, bq, bk, bv, D0, D1, S0);
    ln3_k<<<dim3(8192, 3), bb, 0, stream>>>(D0, D1, S0, g_q, be_q, g_k, be_k, g_v, be_v, Vf);
    vtr_k<<<dim3(2048), bb, 0, stream>>>(Vf, S0);                      // permuted Vt over S0
    attn_k<<<dim3(16, 64), dim3(512), 0, stream>>>(D0, D1, S0, D0);    // out over Q
    gemm_k<<<dim3(64, 8), bb, 0, stream>>>(D0, wpb, bp, S0, 8192, 1024, 1024);
    lnf_k<<<dim3(8192), bb, 0, stream>>>(S0, g_p, be_p, outF);
}